// Round 4
// baseline (3842.107 us; speedup 1.0000x reference)
//
#include <hip/hip_runtime.h>

#define N_USERC 100000
#define N_ITEMC 50000
#define N_TOTALC 150000
#define DC 64
#define NNZ_AC 2000000
#define NNZ_SC 1000000
#define N_TAILC 10000
#define N_HEADC 4000
#define TOPKC 10
#define BATCHC 4096
#define N_NEGC 4
#define CONVF 40.0f
#define CHUNK_ROWS 2500

#define RPB 128                                  // rows per bucket
#define NB_A ((N_TOTALC + RPB - 1) / RPB)        // 1172
#define NB_S ((N_USERC + RPB - 1) / RPB)         // 782
#define IPB 12288                                // items per partition block
#define PBLK_A ((NNZ_AC + IPB - 1) / IPB)        // 163
#define PBLK_S ((NNZ_SC + IPB - 1) / IPB)        // 82

// ---------------- bucket histogram: LDS pre-aggregation, then flush ----------------
__global__ __launch_bounds__(256) void hist_bucket(const int* __restrict__ a_rows, const int* __restrict__ s_rows,
                                                   int* __restrict__ aCnt, int* __restrict__ sCnt) {
    __shared__ int h[NB_A];
    int blk = blockIdx.x;
    const int* rows; int n; int nb; int* gout; int base;
    if (blk < PBLK_A) { rows = a_rows; n = NNZ_AC; nb = NB_A; gout = aCnt; base = blk * IPB; }
    else { rows = s_rows; n = NNZ_SC; nb = NB_S; gout = sCnt; base = (blk - PBLK_A) * IPB; }
    for (int i = threadIdx.x; i < nb; i += 256) h[i] = 0;
    __syncthreads();
    for (int k = 0; k < IPB; k += 256) {
        int idx = base + k + threadIdx.x;
        if (idx < n) atomicAdd(&h[rows[idx] >> 7], 1);
    }
    __syncthreads();
    for (int i = threadIdx.x; i < nb; i += 256) {
        int c = h[i];
        if (c) atomicAdd(&gout[i], c);
    }
}

// ---------------- exclusive scan of bucket counts -> cursor bases (2 blocks) ----------------
__global__ __launch_bounds__(256) void scan_buckets(const int* __restrict__ aCnt, const int* __restrict__ sCnt,
                                                    int* __restrict__ aCur, int* __restrict__ sCur) {
    __shared__ int lds[256];
    const int* cnt; int* cur; int nb;
    if (blockIdx.x == 0) { cnt = aCnt; cur = aCur; nb = NB_A; }
    else { cnt = sCnt; cur = sCur; nb = NB_S; }
    int tid = threadIdx.x;
    int v[5]; int s = 0;
#pragma unroll
    for (int k = 0; k < 5; ++k) {
        int i = tid * 5 + k;
        v[k] = s;
        s += (i < nb) ? cnt[i] : 0;
    }
    lds[tid] = s;
    __syncthreads();
    for (int off = 1; off < 256; off <<= 1) {
        int t = (tid >= off) ? lds[tid - off] : 0;
        __syncthreads();
        lds[tid] += t;
        __syncthreads();
    }
    int base = (tid > 0) ? lds[tid - 1] : 0;
#pragma unroll
    for (int k = 0; k < 5; ++k) {
        int i = tid * 5 + k;
        if (i < nb) cur[i] = base + v[k];
    }
}

// ---------------- partition: block-local counting sort into bucket regions ----------------
// pack.y = col | (row_in_bucket << 18)   (col < 262144, rl < 128)
__global__ __launch_bounds__(256) void partition_fused(
    const float* __restrict__ a_vals, const int* __restrict__ a_rows, const int* __restrict__ a_cols,
    const float* __restrict__ s_vals, const int* __restrict__ s_rows, const int* __restrict__ s_cols,
    int* __restrict__ aCur, int* __restrict__ sCur,
    int2* __restrict__ aPack, int2* __restrict__ sPack) {
    __shared__ int h[NB_A];
    __shared__ int cur[NB_A];
    int blk = blockIdx.x;
    const float* vals; const int* rows; const int* cols; int n; int nb; int* gcur; int2* pack; int base;
    if (blk < PBLK_A) { vals = a_vals; rows = a_rows; cols = a_cols; n = NNZ_AC; nb = NB_A; gcur = aCur; pack = aPack; base = blk * IPB; }
    else { vals = s_vals; rows = s_rows; cols = s_cols; n = NNZ_SC; nb = NB_S; gcur = sCur; pack = sPack; base = (blk - PBLK_A) * IPB; }
    int tid = threadIdx.x;
    for (int i = tid; i < nb; i += 256) h[i] = 0;
    __syncthreads();
    for (int k = 0; k < IPB; k += 256) {
        int idx = base + k + tid;
        if (idx < n) atomicAdd(&h[rows[idx] >> 7], 1);
    }
    __syncthreads();
    for (int i = tid; i < nb; i += 256) {
        int c = h[i];
        cur[i] = c ? atomicAdd(&gcur[i], c) : 0;
    }
    __syncthreads();
    for (int k = 0; k < IPB; k += 256) {
        int idx = base + k + tid;
        if (idx < n) {
            int r = rows[idx];
            int b = r >> 7;
            int pos = atomicAdd(&cur[b], 1);
            pack[pos] = make_int2(__float_as_int(vals[idx]), cols[idx] | ((r & 127) << 18));
        }
    }
}

// ---------------- bucket SpMM: one block per 128-row bucket, LDS accumulator ----------------
// after partition_fused, gcur[b] == end offset of bucket b (bases were bumped by exactly count)
__global__ __launch_bounds__(256) void spmm_bucket(const int* __restrict__ bends,
                                                   const int2* __restrict__ pack,
                                                   const float* __restrict__ x,
                                                   float* __restrict__ y, int nrows) {
    __shared__ float acc[RPB * 64];
    int b = blockIdx.x;
    int s = (b == 0) ? 0 : bends[b - 1];
    int e = bends[b];
    int tid = threadIdx.x;
    for (int i = tid; i < RPB * 64; i += 256) acc[i] = 0.f;
    __syncthreads();
    int wv = tid >> 6, lane = tid & 63;
    int cnt = e - s;
    int per = (cnt + 3) >> 2;
    int ws = s + wv * per;
    int we = ws + per; if (we > e) we = e;
    int j = ws;
    for (; j + 4 <= we; j += 4) {
        int2 e0 = pack[j], e1 = pack[j + 1], e2 = pack[j + 2], e3 = pack[j + 3];
        float g0 = x[(size_t)(e0.y & 0x3FFFF) * 64 + lane];
        float g1 = x[(size_t)(e1.y & 0x3FFFF) * 64 + lane];
        float g2 = x[(size_t)(e2.y & 0x3FFFF) * 64 + lane];
        float g3 = x[(size_t)(e3.y & 0x3FFFF) * 64 + lane];
        atomicAdd(&acc[((e0.y >> 18) << 6) + lane], __int_as_float(e0.x) * g0);
        atomicAdd(&acc[((e1.y >> 18) << 6) + lane], __int_as_float(e1.x) * g1);
        atomicAdd(&acc[((e2.y >> 18) << 6) + lane], __int_as_float(e2.x) * g2);
        atomicAdd(&acc[((e3.y >> 18) << 6) + lane], __int_as_float(e3.x) * g3);
    }
    for (; j < we; ++j) {
        int2 e0 = pack[j];
        float g0 = x[(size_t)(e0.y & 0x3FFFF) * 64 + lane];
        atomicAdd(&acc[((e0.y >> 18) << 6) + lane], __int_as_float(e0.x) * g0);
    }
    __syncthreads();
    int row0 = b << 7;
    for (int i = tid; i < RPB * 64; i += 256) {
        int r = row0 + (i >> 6);
        if (r < nrows) y[(size_t)r * 64 + (i & 63)] = acc[i];
    }
}

// first A-layer variant: reads virtual concat [user_emb; item_emb]
__global__ __launch_bounds__(256) void spmm_bucket_concat(const int* __restrict__ bends,
                                                          const int2* __restrict__ pack,
                                                          const float* __restrict__ xu,
                                                          const float* __restrict__ xi,
                                                          float* __restrict__ y, int nrows) {
    __shared__ float acc[RPB * 64];
    int b = blockIdx.x;
    int s = (b == 0) ? 0 : bends[b - 1];
    int e = bends[b];
    int tid = threadIdx.x;
    for (int i = tid; i < RPB * 64; i += 256) acc[i] = 0.f;
    __syncthreads();
    int wv = tid >> 6, lane = tid & 63;
    int cnt = e - s;
    int per = (cnt + 3) >> 2;
    int ws = s + wv * per;
    int we = ws + per; if (we > e) we = e;
#define GATHER(c) ((c) < N_USERC ? xu[(size_t)(c) * 64 + lane] : xi[(size_t)((c) - N_USERC) * 64 + lane])
    int j = ws;
    for (; j + 4 <= we; j += 4) {
        int2 e0 = pack[j], e1 = pack[j + 1], e2 = pack[j + 2], e3 = pack[j + 3];
        float g0 = GATHER(e0.y & 0x3FFFF);
        float g1 = GATHER(e1.y & 0x3FFFF);
        float g2 = GATHER(e2.y & 0x3FFFF);
        float g3 = GATHER(e3.y & 0x3FFFF);
        atomicAdd(&acc[((e0.y >> 18) << 6) + lane], __int_as_float(e0.x) * g0);
        atomicAdd(&acc[((e1.y >> 18) << 6) + lane], __int_as_float(e1.x) * g1);
        atomicAdd(&acc[((e2.y >> 18) << 6) + lane], __int_as_float(e2.x) * g2);
        atomicAdd(&acc[((e3.y >> 18) << 6) + lane], __int_as_float(e3.x) * g3);
    }
    for (; j < we; ++j) {
        int2 e0 = pack[j];
        float g0 = GATHER(e0.y & 0x3FFFF);
        atomicAdd(&acc[((e0.y >> 18) << 6) + lane], __int_as_float(e0.x) * g0);
    }
#undef GATHER
    __syncthreads();
    int row0 = b << 7;
    for (int i = tid; i < RPB * 64; i += 256) {
        int r = row0 + (i >> 6);
        if (r < nrows) y[(size_t)r * 64 + (i & 63)] = acc[i];
    }
}

// ---------------- collapsed encoder ----------------
__global__ __launch_bounds__(256) void mc_kernel(const float* __restrict__ w0, const float* __restrict__ b0,
                                                 const float* __restrict__ w2, const float* __restrict__ b2,
                                                 float* __restrict__ Mrm, float* __restrict__ cvec) {
    int idx = blockIdx.x * 256 + threadIdx.x;
    if (idx < 4096) {
        int j = idx >> 6, d = idx & 63;
        float acc = 0.f;
        for (int k = 0; k < 256; ++k) acc += w2[j * 256 + k] * w0[k * 64 + d];
        Mrm[idx] = acc;
    } else if (idx < 4160) {
        int i = idx - 4096;
        float acc = b2[i];
        for (int k = 0; k < 256; ++k) acc += w2[i * 256 + k] * b0[k];
        cvec[i] = acc;
    }
}

// enc(f) = f @ Mrm^T + cvec ; one wave per row; fused tail+head
__global__ __launch_bounds__(256) void enc2_fused(const float* __restrict__ emb,
                                                  const int* __restrict__ tail_idx, const int* __restrict__ head_idx,
                                                  const float* __restrict__ Mrm, const float* __restrict__ cvec,
                                                  float* __restrict__ tail_e, float* __restrict__ top_e) {
    __shared__ float fsh[4][64];
    int wv = threadIdx.x >> 6, lane = threadIdx.x & 63;
    int r = blockIdx.x * 4 + wv;
    int item;
    float* outp;
    if (r < N_TAILC) { item = tail_idx[r]; outp = tail_e + (size_t)r * 64; }
    else if (r < N_TAILC + N_HEADC) { item = head_idx[r - N_TAILC]; outp = top_e + (size_t)(r - N_TAILC) * 64; }
    else { item = -1; outp = nullptr; }
    if (item >= 0) fsh[wv][lane] = emb[(size_t)item * 64 + lane];
    __syncthreads();
    if (item < 0) return;
    float acc = cvec[lane];
#pragma unroll
    for (int d4 = 0; d4 < 64; d4 += 4) {
        float4 m4 = *(const float4*)&Mrm[lane * 64 + d4];
        float4 f4 = *(const float4*)&fsh[wv][d4];
        acc += m4.x * f4.x + m4.y * f4.y + m4.z * f4.z + m4.w * f4.w;
    }
    outp[lane] = acc;
}

// ---------------- score GEMM: C[m x 4000] = A[m x 64] @ B[4000 x 64]^T ----------------
__global__ __launch_bounds__(256) void score_gemm(const float* __restrict__ A,
                                                  const float* __restrict__ B,
                                                  float* __restrict__ C, int M) {
    __shared__ float As[32][132];
    __shared__ float Bs[32][132];
    int tid = threadIdx.x;
    int tx = tid & 15, ty = tid >> 4;
    int rowbase = blockIdx.y * 128;
    int colbase = blockIdx.x * 128;
    float acc[8][8];
#pragma unroll
    for (int i = 0; i < 8; ++i)
#pragma unroll
        for (int j = 0; j < 8; ++j) acc[i][j] = 0.f;

    for (int k0 = 0; k0 < 64; k0 += 32) {
        __syncthreads();
#pragma unroll
        for (int i = 0; i < 4; ++i) {
            int f = tid + i * 256;
            int r = f >> 3;
            int kq = (f & 7) << 2;
            int grow = rowbase + r;
            float4 av = (grow < M) ? *(const float4*)&A[(size_t)grow * 64 + k0 + kq]
                                   : make_float4(0.f, 0.f, 0.f, 0.f);
            As[kq + 0][r] = av.x; As[kq + 1][r] = av.y; As[kq + 2][r] = av.z; As[kq + 3][r] = av.w;
            int gcol = colbase + r;
            float4 bv = (gcol < N_HEADC) ? *(const float4*)&B[(size_t)gcol * 64 + k0 + kq]
                                         : make_float4(0.f, 0.f, 0.f, 0.f);
            Bs[kq + 0][r] = bv.x; Bs[kq + 1][r] = bv.y; Bs[kq + 2][r] = bv.z; Bs[kq + 3][r] = bv.w;
        }
        __syncthreads();
#pragma unroll
        for (int k = 0; k < 32; ++k) {
            float a[8], b[8];
#pragma unroll
            for (int i = 0; i < 8; ++i) a[i] = As[k][ty + 16 * i];
#pragma unroll
            for (int j = 0; j < 8; ++j) b[j] = Bs[k][tx + 16 * j];
#pragma unroll
            for (int i = 0; i < 8; ++i)
#pragma unroll
                for (int j = 0; j < 8; ++j) acc[i][j] += a[i] * b[j];
        }
    }
#pragma unroll
    for (int i = 0; i < 8; ++i) {
        int r = rowbase + ty + 16 * i;
        if (r < M) {
#pragma unroll
            for (int j = 0; j < 8; ++j) {
                int c = colbase + tx + 16 * j;
                if (c < N_HEADC) C[(size_t)r * N_HEADC + c] = acc[i][j];
            }
        }
    }
}

// ---------------- per-row top-k on materialized scores ----------------
__global__ __launch_bounds__(256) void topk_rows(const float* __restrict__ scores, int nrows, int row0,
                                                 const int* __restrict__ head_idx,
                                                 int* __restrict__ ig_cols, float* __restrict__ ig_vals) {
    int w = (blockIdx.x * blockDim.x + threadIdx.x) >> 6;
    int lane = threadIdx.x & 63;
    if (w >= nrows) return;
    const float* srow = scores + (size_t)w * N_HEADC;
    float v[TOPKC];
    int id[TOPKC];
#pragma unroll
    for (int k = 0; k < TOPKC; ++k) { v[k] = -1e30f; id[k] = -1; }
    for (int it = 0; it < 16; ++it) {
        int f4 = lane + it * 64;
        if (f4 < 1000) {
            float4 s4 = ((const float4*)srow)[f4];
            int cb = f4 * 4;
            float vv[4] = { s4.x, s4.y, s4.z, s4.w };
#pragma unroll
            for (int q = 0; q < 4; ++q) {
                float sc = vv[q];
                if (sc > v[TOPKC - 1]) {
                    float cv = sc; int ci = cb + q;
#pragma unroll
                    for (int k = 0; k < TOPKC; ++k) {
                        if (cv > v[k]) { float t = v[k]; int ti = id[k]; v[k] = cv; id[k] = ci; cv = t; ci = ti; }
                    }
                }
            }
        }
    }
    int ptr = 0;
    float ssum = 0.f;
    float outv = 0.f;
    int outid = -1;
#pragma unroll
    for (int r = 0; r < TOPKC; ++r) {
        float cv = (ptr < TOPKC) ? v[ptr] : -1e30f;
        int ci = (ptr < TOPKC) ? id[ptr] : -1;
        int wl = lane;
#pragma unroll
        for (int m = 1; m < 64; m <<= 1) {
            float ov = __shfl_xor(cv, m, 64);
            int oi = __shfl_xor(ci, m, 64);
            int ol = __shfl_xor(wl, m, 64);
            if (ov > cv || (ov == cv && ol < wl)) { cv = ov; ci = oi; wl = ol; }
        }
        if (wl == lane) ptr++;
        ssum += 1.f / (1.f + expf(-cv));
        if (lane == r) { outv = cv; outid = ci; }
    }
    if (lane < TOPKC) {
        float s = 1.f / (1.f + expf(-outv));
        float wgt = s / (ssum + 1.f);
        int grow = row0 + w;
        ig_vals[grow * TOPKC + lane] = wgt;
        ig_cols[grow * TOPKC + lane] = head_idx[outid];
    }
}

// ---------------- item_enh accumulation ----------------
__global__ __launch_bounds__(256) void ig_spmm_kernel(const int* __restrict__ tail_idx,
                                                      const int* __restrict__ ig_cols,
                                                      const float* __restrict__ ig_vals,
                                                      const float* __restrict__ items,
                                                      float* __restrict__ enh) {
    int e = (blockIdx.x * blockDim.x + threadIdx.x) >> 6;
    int lane = threadIdx.x & 63;
    if (e >= N_TAILC * TOPKC) return;
    int row = tail_idx[e / TOPKC];
    int col = ig_cols[e];
    float w = ig_vals[e];
    atomicAdd(&enh[(size_t)row * 64 + lane], w * items[(size_t)col * 64 + lane]);
}

// ---------------- final loss ----------------
__global__ __launch_bounds__(256) void loss_kernel(const float* __restrict__ u0, const float* __restrict__ u1,
                                                   const float* __restrict__ u2, const float* __restrict__ items,
                                                   const float* __restrict__ enh, const float* __restrict__ deg,
                                                   const float* __restrict__ user_emb, const float* __restrict__ item_emb,
                                                   const int* __restrict__ bu, const int* __restrict__ bp,
                                                   const int* __restrict__ bn, float* __restrict__ out) {
    int w = (blockIdx.x * blockDim.x + threadIdx.x) >> 6;
    int lane = threadIdx.x & 63;
    if (w >= BATCHC) return;
    int uu = bu[w], pp = bp[w];
    float ue = (u0[uu * 64 + lane] + u1[uu * 64 + lane] + u2[uu * 64 + lane]) * (1.f / 3.f);
    float swp = CONVF / (CONVF + expf(deg[pp] * (1.f / CONVF)));
    float pe = items[pp * 64 + lane] + swp * enh[pp * 64 + lane];
    float ps = ue * pe;
    float ns = 0.f;
    float u0e = user_emb[uu * 64 + lane];
    float p0e = item_emb[pp * 64 + lane];
    float reg = u0e * u0e + p0e * p0e;
#pragma unroll
    for (int k = 0; k < N_NEGC; ++k) {
        int nn = bn[w * N_NEGC + k];
        float swn = CONVF / (CONVF + expf(deg[nn] * (1.f / CONVF)));
        float nv = items[nn * 64 + lane] + swn * enh[nn * 64 + lane];
        ns += ue * nv;
        float n0 = item_emb[nn * 64 + lane];
        reg += n0 * n0;
    }
#pragma unroll
    for (int m = 32; m >= 1; m >>= 1) {
        ps += __shfl_xor(ps, m, 64);
        ns += __shfl_xor(ns, m, 64);
        reg += __shfl_xor(reg, m, 64);
    }
    if (lane == 0) {
        float x = ns * (1.f / N_NEGC) - ps;
        float sp = (x > 0.f) ? (x + log1pf(expf(-x))) : log1pf(expf(x));
        atomicAdd(&out[0], sp * (1.f / BATCHC));
        atomicAdd(&out[1], 0.5f * reg * (1.f / BATCHC));
    }
}

extern "C" void kernel_launch(void* const* d_in, const int* in_sizes, int n_in,
                              void* d_out, int out_size, void* d_ws, size_t ws_size,
                              hipStream_t stream) {
    const float* user_emb = (const float*)d_in[0];
    const float* item_emb = (const float*)d_in[1];
    const float* w0 = (const float*)d_in[2];
    const float* b0 = (const float*)d_in[3];
    const float* w2 = (const float*)d_in[4];
    const float* b2 = (const float*)d_in[5];
    const float* a_vals = (const float*)d_in[6];
    const float* s_vals = (const float*)d_in[7];
    const float* item_degree = (const float*)d_in[8];
    const int* a_rows = (const int*)d_in[9];
    const int* a_cols = (const int*)d_in[10];
    const int* s_rows = (const int*)d_in[11];
    const int* s_cols = (const int*)d_in[12];
    const int* tail_idx = (const int*)d_in[13];
    const int* head_idx = (const int*)d_in[14];
    const int* batch_user = (const int*)d_in[15];
    const int* batch_pos = (const int*)d_in[16];
    const int* batch_neg = (const int*)d_in[17];
    float* out = (float*)d_out;

    // ---- workspace carve ----
    char* p = (char*)d_ws;
    auto carve = [&](size_t bytes) -> void* {
        void* r = (void*)p;
        p += (bytes + 255) & ~size_t(255);
        return r;
    };
    float* embA = (float*)carve((size_t)N_TOTALC * 64 * 4);
    float* embB = (float*)carve((size_t)N_TOTALC * 64 * 4);
    float* u1 = (float*)carve((size_t)N_USERC * 64 * 4);
    float* u2 = (float*)carve((size_t)N_USERC * 64 * 4);
    float* enh = (float*)carve((size_t)N_ITEMC * 64 * 4);
    float* tail_e = (float*)carve((size_t)N_TAILC * 64 * 4);
    float* top_e = (float*)carve((size_t)N_HEADC * 64 * 4);
    int2* aPack = (int2*)carve((size_t)NNZ_AC * 8);
    int2* sPack = (int2*)carve((size_t)NNZ_SC * 8);
    int* aCnt = (int*)carve((size_t)NB_A * 4);
    int* sCnt = (int*)carve((size_t)NB_S * 4);
    int* aCur = (int*)carve((size_t)NB_A * 4);
    int* sCur = (int*)carve((size_t)NB_S * 4);
    int* ig_cols_buf = (int*)carve((size_t)N_TAILC * TOPKC * 4);
    float* ig_vals_buf = (float*)carve((size_t)N_TAILC * TOPKC * 4);
    float* Mrm = (float*)carve(64 * 64 * 4);
    float* cvec = (float*)carve(64 * 4);
    float* scores = (float*)carve((size_t)CHUNK_ROWS * N_HEADC * 4);

    // ---- bucketed CSR-lite build (A + S) ----
    hipMemsetAsync(aCnt, 0, (size_t)NB_A * 4, stream);
    hipMemsetAsync(sCnt, 0, (size_t)NB_S * 4, stream);
    hist_bucket<<<PBLK_A + PBLK_S, 256, 0, stream>>>(a_rows, s_rows, aCnt, sCnt);
    scan_buckets<<<2, 256, 0, stream>>>(aCnt, sCnt, aCur, sCur);
    partition_fused<<<PBLK_A + PBLK_S, 256, 0, stream>>>(a_vals, a_rows, a_cols,
                                                         s_vals, s_rows, s_cols,
                                                         aCur, sCur, aPack, sPack);
    // after partition, aCur[b] / sCur[b] hold bucket END offsets

    // ---- collapsed encoder (tail + head fused) ----
    mc_kernel<<<17, 256, 0, stream>>>(w0, b0, w2, b2, Mrm, cvec);
    enc2_fused<<<(N_TAILC + N_HEADC + 3) / 4, 256, 0, stream>>>(item_emb, tail_idx, head_idx, Mrm, cvec, tail_e, top_e);

    // ---- chunked scores GEMM + top-k ----
    for (int row0 = 0; row0 < N_TAILC; row0 += CHUNK_ROWS) {
        int m = N_TAILC - row0;
        if (m > CHUNK_ROWS) m = CHUNK_ROWS;
        int rb = (m + 127) / 128;
        score_gemm<<<dim3((N_HEADC + 127) / 128, rb), 256, 0, stream>>>(tail_e + (size_t)row0 * 64, top_e, scores, m);
        topk_rows<<<(m + 3) / 4, 256, 0, stream>>>(scores, m, row0, head_idx, ig_cols_buf, ig_vals_buf);
    }

    // ---- 3 A-layers (first reads inputs directly, then ping-pong) ----
    spmm_bucket_concat<<<NB_A, 256, 0, stream>>>(aCur, aPack, user_emb, item_emb, embB, N_TOTALC);
    spmm_bucket<<<NB_A, 256, 0, stream>>>(aCur, aPack, embB, embA, N_TOTALC);
    spmm_bucket<<<NB_A, 256, 0, stream>>>(aCur, aPack, embA, embB, N_TOTALC);
    const float* u0 = embB;
    const float* items = embB + (size_t)N_USERC * 64;

    // ---- 2 S-layers on users ----
    spmm_bucket<<<NB_S, 256, 0, stream>>>(sCur, sPack, u0, u1, N_USERC);
    spmm_bucket<<<NB_S, 256, 0, stream>>>(sCur, sPack, u1, u2, N_USERC);

    // ---- item enhancement ----
    hipMemsetAsync(enh, 0, (size_t)N_ITEMC * 64 * 4, stream);
    ig_spmm_kernel<<<(N_TAILC * TOPKC) / 4, 256, 0, stream>>>(tail_idx, ig_cols_buf, ig_vals_buf, items, enh);

    // ---- loss + reg ----
    hipMemsetAsync(out, 0, 2 * sizeof(float), stream);
    loss_kernel<<<BATCHC / 4, 256, 0, stream>>>(u0, u1, u2, items, enh, item_degree,
                                                user_emb, item_emb, batch_user, batch_pos, batch_neg, out);
}

// Round 5
// 1246.677 us; speedup vs baseline: 3.0819x; 3.0819x over previous
//
#include <hip/hip_runtime.h>

#define N_USERC 100000
#define N_ITEMC 50000
#define N_TOTALC 150000
#define DC 64
#define NNZ_AC 2000000
#define NNZ_SC 1000000
#define N_TAILC 10000
#define N_HEADC 4000
#define TOPKC 10
#define BATCHC 4096
#define N_NEGC 4
#define CONVF 40.0f
#define CHUNK_ROWS 2500

#define RPB 128                                  // rows per bucket
#define NB_A ((N_TOTALC + RPB - 1) / RPB)        // 1172
#define NB_S ((N_USERC + RPB - 1) / RPB)         // 782
#define IPB 12288                                // items per partition block
#define PBLK_A ((NNZ_AC + IPB - 1) / IPB)        // 163
#define PBLK_S ((NNZ_SC + IPB - 1) / IPB)        // 82

// ---------------- bucket histogram: LDS pre-aggregation, then flush ----------------
__global__ __launch_bounds__(256) void hist_bucket(const int* __restrict__ a_rows, const int* __restrict__ s_rows,
                                                   int* __restrict__ aCnt, int* __restrict__ sCnt) {
    __shared__ int h[NB_A];
    int blk = blockIdx.x;
    const int* rows; int n; int nb; int* gout; int base;
    if (blk < PBLK_A) { rows = a_rows; n = NNZ_AC; nb = NB_A; gout = aCnt; base = blk * IPB; }
    else { rows = s_rows; n = NNZ_SC; nb = NB_S; gout = sCnt; base = (blk - PBLK_A) * IPB; }
    for (int i = threadIdx.x; i < nb; i += 256) h[i] = 0;
    __syncthreads();
    for (int k = 0; k < IPB; k += 256) {
        int idx = base + k + threadIdx.x;
        if (idx < n) atomicAdd(&h[rows[idx] >> 7], 1);
    }
    __syncthreads();
    for (int i = threadIdx.x; i < nb; i += 256) {
        int c = h[i];
        if (c) atomicAdd(&gout[i], c);
    }
}

// ---------------- exclusive scan of bucket counts -> cursor bases (2 blocks) ----------------
__global__ __launch_bounds__(256) void scan_buckets(const int* __restrict__ aCnt, const int* __restrict__ sCnt,
                                                    int* __restrict__ aCur, int* __restrict__ sCur) {
    __shared__ int lds[256];
    const int* cnt; int* cur; int nb;
    if (blockIdx.x == 0) { cnt = aCnt; cur = aCur; nb = NB_A; }
    else { cnt = sCnt; cur = sCur; nb = NB_S; }
    int tid = threadIdx.x;
    int v[5]; int s = 0;
#pragma unroll
    for (int k = 0; k < 5; ++k) {
        int i = tid * 5 + k;
        v[k] = s;
        s += (i < nb) ? cnt[i] : 0;
    }
    lds[tid] = s;
    __syncthreads();
    for (int off = 1; off < 256; off <<= 1) {
        int t = (tid >= off) ? lds[tid - off] : 0;
        __syncthreads();
        lds[tid] += t;
        __syncthreads();
    }
    int base = (tid > 0) ? lds[tid - 1] : 0;
#pragma unroll
    for (int k = 0; k < 5; ++k) {
        int i = tid * 5 + k;
        if (i < nb) cur[i] = base + v[k];
    }
}

// ---------------- partition: block-local counting sort into bucket regions ----------------
// pack.y = col | (row_in_bucket << 18)   (col < 262144, rl < 128)
__global__ __launch_bounds__(256) void partition_fused(
    const float* __restrict__ a_vals, const int* __restrict__ a_rows, const int* __restrict__ a_cols,
    const float* __restrict__ s_vals, const int* __restrict__ s_rows, const int* __restrict__ s_cols,
    int* __restrict__ aCur, int* __restrict__ sCur,
    int2* __restrict__ aPack, int2* __restrict__ sPack) {
    __shared__ int h[NB_A];
    __shared__ int cur[NB_A];
    int blk = blockIdx.x;
    const float* vals; const int* rows; const int* cols; int n; int nb; int* gcur; int2* pack; int base;
    if (blk < PBLK_A) { vals = a_vals; rows = a_rows; cols = a_cols; n = NNZ_AC; nb = NB_A; gcur = aCur; pack = aPack; base = blk * IPB; }
    else { vals = s_vals; rows = s_rows; cols = s_cols; n = NNZ_SC; nb = NB_S; gcur = sCur; pack = sPack; base = (blk - PBLK_A) * IPB; }
    int tid = threadIdx.x;
    for (int i = tid; i < nb; i += 256) h[i] = 0;
    __syncthreads();
    for (int k = 0; k < IPB; k += 256) {
        int idx = base + k + tid;
        if (idx < n) atomicAdd(&h[rows[idx] >> 7], 1);
    }
    __syncthreads();
    for (int i = tid; i < nb; i += 256) {
        int c = h[i];
        cur[i] = c ? atomicAdd(&gcur[i], c) : 0;
    }
    __syncthreads();
    for (int k = 0; k < IPB; k += 256) {
        int idx = base + k + tid;
        if (idx < n) {
            int r = rows[idx];
            int b = r >> 7;
            int pos = atomicAdd(&cur[b], 1);
            pack[pos] = make_int2(__float_as_int(vals[idx]), cols[idx] | ((r & 127) << 18));
        }
    }
}

// ---------------- finalize: per-bucket counting sort -> row-grouped entries + rowptr ----------------
// one block per bucket; bucket span [s,e) is owned exclusively by this block -> local line assembly
__global__ __launch_bounds__(256) void csr_finalize(const int* __restrict__ aEnd, const int* __restrict__ sEnd,
                                                    const int2* __restrict__ aRaw, const int2* __restrict__ sRaw,
                                                    int2* __restrict__ aOut, int2* __restrict__ sOut,
                                                    int* __restrict__ aRp, int* __restrict__ sRp) {
    __shared__ int cnt_[RPB];
    __shared__ int scn[RPB];
    __shared__ int cursor[RPB];
    int blk = blockIdx.x;
    const int* ends; const int2* raw; int2* outp; int* rp; int nb; int nrows; int b;
    if (blk < NB_A) { ends = aEnd; raw = aRaw; outp = aOut; rp = aRp; nb = NB_A; nrows = N_TOTALC; b = blk; }
    else { ends = sEnd; raw = sRaw; outp = sOut; rp = sRp; nb = NB_S; nrows = N_USERC; b = blk - NB_A; }
    int s = b ? ends[b - 1] : 0;
    int e = ends[b];
    int n = e - s;
    int tid = threadIdx.x;
    if (tid < RPB) cnt_[tid] = 0;
    __syncthreads();
    for (int i = tid; i < n; i += 256)
        atomicAdd(&cnt_[(raw[s + i].y >> 18) & 127], 1);
    __syncthreads();
    if (tid < RPB) scn[tid] = cnt_[tid];
    __syncthreads();
    for (int off = 1; off < RPB; off <<= 1) {
        int t = (tid < RPB && tid >= off) ? scn[tid - off] : 0;
        __syncthreads();
        if (tid < RPB) scn[tid] += t;
        __syncthreads();
    }
    if (tid < RPB) {
        int ex = scn[tid] - cnt_[tid];      // exclusive
        cursor[tid] = ex;
        int row = (b << 7) + tid;
        if (row < nrows) rp[row] = s + ex;
    }
    if (b == nb - 1 && tid == 0) rp[nrows] = e;
    __syncthreads();
    for (int i = tid; i < n; i += 256) {
        int2 en = raw[s + i];
        int r = (en.y >> 18) & 127;
        int pos = atomicAdd(&cursor[r], 1);
        outp[s + pos] = make_int2(en.x, en.y & 0x3FFFF);
    }
}

// ---------------- CSR SpMM (packed): one wave per row, lane = feature dim ----------------
__global__ __launch_bounds__(256) void spmm_csr(const int* __restrict__ rowptr,
                                                const int2* __restrict__ pack,
                                                const float* __restrict__ x,
                                                float* __restrict__ y, int nrows) {
    int w = (blockIdx.x * blockDim.x + threadIdx.x) >> 6;
    int lane = threadIdx.x & 63;
    if (w >= nrows) return;
    int s = rowptr[w], e = rowptr[w + 1];
    float a0 = 0.f, a1 = 0.f, a2 = 0.f, a3 = 0.f;
    int j = s;
    for (; j + 4 <= e; j += 4) {
        int2 e0 = pack[j], e1 = pack[j + 1], e2 = pack[j + 2], e3 = pack[j + 3];
        a0 += __int_as_float(e0.x) * x[(size_t)e0.y * 64 + lane];
        a1 += __int_as_float(e1.x) * x[(size_t)e1.y * 64 + lane];
        a2 += __int_as_float(e2.x) * x[(size_t)e2.y * 64 + lane];
        a3 += __int_as_float(e3.x) * x[(size_t)e3.y * 64 + lane];
    }
    for (; j < e; ++j) {
        int2 e0 = pack[j];
        a0 += __int_as_float(e0.x) * x[(size_t)e0.y * 64 + lane];
    }
    y[(size_t)w * 64 + lane] = a0 + a1 + a2 + a3;
}

// first A-layer: reads the virtual concat [user_emb; item_emb] directly
__global__ __launch_bounds__(256) void spmm_csr_concat(const int* __restrict__ rowptr,
                                                       const int2* __restrict__ pack,
                                                       const float* __restrict__ xu,
                                                       const float* __restrict__ xi,
                                                       float* __restrict__ y, int nrows) {
    int w = (blockIdx.x * blockDim.x + threadIdx.x) >> 6;
    int lane = threadIdx.x & 63;
    if (w >= nrows) return;
    int s = rowptr[w], e = rowptr[w + 1];
    float a0 = 0.f, a1 = 0.f, a2 = 0.f, a3 = 0.f;
    int j = s;
#define GATHER(c) ((c) < N_USERC ? xu[(size_t)(c) * 64 + lane] : xi[(size_t)((c) - N_USERC) * 64 + lane])
    for (; j + 4 <= e; j += 4) {
        int2 e0 = pack[j], e1 = pack[j + 1], e2 = pack[j + 2], e3 = pack[j + 3];
        a0 += __int_as_float(e0.x) * GATHER(e0.y);
        a1 += __int_as_float(e1.x) * GATHER(e1.y);
        a2 += __int_as_float(e2.x) * GATHER(e2.y);
        a3 += __int_as_float(e3.x) * GATHER(e3.y);
    }
    for (; j < e; ++j) {
        int2 e0 = pack[j];
        a0 += __int_as_float(e0.x) * GATHER(e0.y);
    }
#undef GATHER
    y[(size_t)w * 64 + lane] = a0 + a1 + a2 + a3;
}

// ---------------- collapsed encoder ----------------
__global__ __launch_bounds__(256) void mc_kernel(const float* __restrict__ w0, const float* __restrict__ b0,
                                                 const float* __restrict__ w2, const float* __restrict__ b2,
                                                 float* __restrict__ Mrm, float* __restrict__ cvec) {
    int idx = blockIdx.x * 256 + threadIdx.x;
    if (idx < 4096) {
        int j = idx >> 6, d = idx & 63;
        float acc = 0.f;
        for (int k = 0; k < 256; ++k) acc += w2[j * 256 + k] * w0[k * 64 + d];
        Mrm[idx] = acc;
    } else if (idx < 4160) {
        int i = idx - 4096;
        float acc = b2[i];
        for (int k = 0; k < 256; ++k) acc += w2[i * 256 + k] * b0[k];
        cvec[i] = acc;
    }
}

// enc(f) = f @ Mrm^T + cvec ; one wave per row; fused tail+head
__global__ __launch_bounds__(256) void enc2_fused(const float* __restrict__ emb,
                                                  const int* __restrict__ tail_idx, const int* __restrict__ head_idx,
                                                  const float* __restrict__ Mrm, const float* __restrict__ cvec,
                                                  float* __restrict__ tail_e, float* __restrict__ top_e) {
    __shared__ float fsh[4][64];
    int wv = threadIdx.x >> 6, lane = threadIdx.x & 63;
    int r = blockIdx.x * 4 + wv;
    int item;
    float* outp;
    if (r < N_TAILC) { item = tail_idx[r]; outp = tail_e + (size_t)r * 64; }
    else if (r < N_TAILC + N_HEADC) { item = head_idx[r - N_TAILC]; outp = top_e + (size_t)(r - N_TAILC) * 64; }
    else { item = -1; outp = nullptr; }
    if (item >= 0) fsh[wv][lane] = emb[(size_t)item * 64 + lane];
    __syncthreads();
    if (item < 0) return;
    float acc = cvec[lane];
#pragma unroll
    for (int d4 = 0; d4 < 64; d4 += 4) {
        float4 m4 = *(const float4*)&Mrm[lane * 64 + d4];
        float4 f4 = *(const float4*)&fsh[wv][d4];
        acc += m4.x * f4.x + m4.y * f4.y + m4.z * f4.z + m4.w * f4.w;
    }
    outp[lane] = acc;
}

// ---------------- score GEMM: C[m x 4000] = A[m x 64] @ B[4000 x 64]^T ----------------
__global__ __launch_bounds__(256) void score_gemm(const float* __restrict__ A,
                                                  const float* __restrict__ B,
                                                  float* __restrict__ C, int M) {
    __shared__ float As[32][132];
    __shared__ float Bs[32][132];
    int tid = threadIdx.x;
    int tx = tid & 15, ty = tid >> 4;
    int rowbase = blockIdx.y * 128;
    int colbase = blockIdx.x * 128;
    float acc[8][8];
#pragma unroll
    for (int i = 0; i < 8; ++i)
#pragma unroll
        for (int j = 0; j < 8; ++j) acc[i][j] = 0.f;

    for (int k0 = 0; k0 < 64; k0 += 32) {
        __syncthreads();
#pragma unroll
        for (int i = 0; i < 4; ++i) {
            int f = tid + i * 256;
            int r = f >> 3;
            int kq = (f & 7) << 2;
            int grow = rowbase + r;
            float4 av = (grow < M) ? *(const float4*)&A[(size_t)grow * 64 + k0 + kq]
                                   : make_float4(0.f, 0.f, 0.f, 0.f);
            As[kq + 0][r] = av.x; As[kq + 1][r] = av.y; As[kq + 2][r] = av.z; As[kq + 3][r] = av.w;
            int gcol = colbase + r;
            float4 bv = (gcol < N_HEADC) ? *(const float4*)&B[(size_t)gcol * 64 + k0 + kq]
                                         : make_float4(0.f, 0.f, 0.f, 0.f);
            Bs[kq + 0][r] = bv.x; Bs[kq + 1][r] = bv.y; Bs[kq + 2][r] = bv.z; Bs[kq + 3][r] = bv.w;
        }
        __syncthreads();
#pragma unroll
        for (int k = 0; k < 32; ++k) {
            float a[8], b[8];
#pragma unroll
            for (int i = 0; i < 8; ++i) a[i] = As[k][ty + 16 * i];
#pragma unroll
            for (int j = 0; j < 8; ++j) b[j] = Bs[k][tx + 16 * j];
#pragma unroll
            for (int i = 0; i < 8; ++i)
#pragma unroll
                for (int j = 0; j < 8; ++j) acc[i][j] += a[i] * b[j];
        }
    }
#pragma unroll
    for (int i = 0; i < 8; ++i) {
        int r = rowbase + ty + 16 * i;
        if (r < M) {
#pragma unroll
            for (int j = 0; j < 8; ++j) {
                int c = colbase + tx + 16 * j;
                if (c < N_HEADC) C[(size_t)r * N_HEADC + c] = acc[i][j];
            }
        }
    }
}

// ---------------- per-row top-k on materialized scores ----------------
__global__ __launch_bounds__(256) void topk_rows(const float* __restrict__ scores, int nrows, int row0,
                                                 const int* __restrict__ head_idx,
                                                 int* __restrict__ ig_cols, float* __restrict__ ig_vals) {
    int w = (blockIdx.x * blockDim.x + threadIdx.x) >> 6;
    int lane = threadIdx.x & 63;
    if (w >= nrows) return;
    const float* srow = scores + (size_t)w * N_HEADC;
    float v[TOPKC];
    int id[TOPKC];
#pragma unroll
    for (int k = 0; k < TOPKC; ++k) { v[k] = -1e30f; id[k] = -1; }
    for (int it = 0; it < 16; ++it) {
        int f4 = lane + it * 64;
        if (f4 < 1000) {
            float4 s4 = ((const float4*)srow)[f4];
            int cb = f4 * 4;
            float vv[4] = { s4.x, s4.y, s4.z, s4.w };
#pragma unroll
            for (int q = 0; q < 4; ++q) {
                float sc = vv[q];
                if (sc > v[TOPKC - 1]) {
                    float cv = sc; int ci = cb + q;
#pragma unroll
                    for (int k = 0; k < TOPKC; ++k) {
                        if (cv > v[k]) { float t = v[k]; int ti = id[k]; v[k] = cv; id[k] = ci; cv = t; ci = ti; }
                    }
                }
            }
        }
    }
    int ptr = 0;
    float ssum = 0.f;
    float outv = 0.f;
    int outid = -1;
#pragma unroll
    for (int r = 0; r < TOPKC; ++r) {
        float cv = (ptr < TOPKC) ? v[ptr] : -1e30f;
        int ci = (ptr < TOPKC) ? id[ptr] : -1;
        int wl = lane;
#pragma unroll
        for (int m = 1; m < 64; m <<= 1) {
            float ov = __shfl_xor(cv, m, 64);
            int oi = __shfl_xor(ci, m, 64);
            int ol = __shfl_xor(wl, m, 64);
            if (ov > cv || (ov == cv && ol < wl)) { cv = ov; ci = oi; wl = ol; }
        }
        if (wl == lane) ptr++;
        ssum += 1.f / (1.f + expf(-cv));
        if (lane == r) { outv = cv; outid = ci; }
    }
    if (lane < TOPKC) {
        float s = 1.f / (1.f + expf(-outv));
        float wgt = s / (ssum + 1.f);
        int grow = row0 + w;
        ig_vals[grow * TOPKC + lane] = wgt;
        ig_cols[grow * TOPKC + lane] = head_idx[outid];
    }
}

// ---------------- item_enh accumulation ----------------
__global__ __launch_bounds__(256) void ig_spmm_kernel(const int* __restrict__ tail_idx,
                                                      const int* __restrict__ ig_cols,
                                                      const float* __restrict__ ig_vals,
                                                      const float* __restrict__ items,
                                                      float* __restrict__ enh) {
    int e = (blockIdx.x * blockDim.x + threadIdx.x) >> 6;
    int lane = threadIdx.x & 63;
    if (e >= N_TAILC * TOPKC) return;
    int row = tail_idx[e / TOPKC];
    int col = ig_cols[e];
    float w = ig_vals[e];
    atomicAdd(&enh[(size_t)row * 64 + lane], w * items[(size_t)col * 64 + lane]);
}

// ---------------- final loss ----------------
__global__ __launch_bounds__(256) void loss_kernel(const float* __restrict__ u0, const float* __restrict__ u1,
                                                   const float* __restrict__ u2, const float* __restrict__ items,
                                                   const float* __restrict__ enh, const float* __restrict__ deg,
                                                   const float* __restrict__ user_emb, const float* __restrict__ item_emb,
                                                   const int* __restrict__ bu, const int* __restrict__ bp,
                                                   const int* __restrict__ bn, float* __restrict__ out) {
    int w = (blockIdx.x * blockDim.x + threadIdx.x) >> 6;
    int lane = threadIdx.x & 63;
    if (w >= BATCHC) return;
    int uu = bu[w], pp = bp[w];
    float ue = (u0[uu * 64 + lane] + u1[uu * 64 + lane] + u2[uu * 64 + lane]) * (1.f / 3.f);
    float swp = CONVF / (CONVF + expf(deg[pp] * (1.f / CONVF)));
    float pe = items[pp * 64 + lane] + swp * enh[pp * 64 + lane];
    float ps = ue * pe;
    float ns = 0.f;
    float u0e = user_emb[uu * 64 + lane];
    float p0e = item_emb[pp * 64 + lane];
    float reg = u0e * u0e + p0e * p0e;
#pragma unroll
    for (int k = 0; k < N_NEGC; ++k) {
        int nn = bn[w * N_NEGC + k];
        float swn = CONVF / (CONVF + expf(deg[nn] * (1.f / CONVF)));
        float nv = items[nn * 64 + lane] + swn * enh[nn * 64 + lane];
        ns += ue * nv;
        float n0 = item_emb[nn * 64 + lane];
        reg += n0 * n0;
    }
#pragma unroll
    for (int m = 32; m >= 1; m >>= 1) {
        ps += __shfl_xor(ps, m, 64);
        ns += __shfl_xor(ns, m, 64);
        reg += __shfl_xor(reg, m, 64);
    }
    if (lane == 0) {
        float x = ns * (1.f / N_NEGC) - ps;
        float sp = (x > 0.f) ? (x + log1pf(expf(-x))) : log1pf(expf(x));
        atomicAdd(&out[0], sp * (1.f / BATCHC));
        atomicAdd(&out[1], 0.5f * reg * (1.f / BATCHC));
    }
}

extern "C" void kernel_launch(void* const* d_in, const int* in_sizes, int n_in,
                              void* d_out, int out_size, void* d_ws, size_t ws_size,
                              hipStream_t stream) {
    const float* user_emb = (const float*)d_in[0];
    const float* item_emb = (const float*)d_in[1];
    const float* w0 = (const float*)d_in[2];
    const float* b0 = (const float*)d_in[3];
    const float* w2 = (const float*)d_in[4];
    const float* b2 = (const float*)d_in[5];
    const float* a_vals = (const float*)d_in[6];
    const float* s_vals = (const float*)d_in[7];
    const float* item_degree = (const float*)d_in[8];
    const int* a_rows = (const int*)d_in[9];
    const int* a_cols = (const int*)d_in[10];
    const int* s_rows = (const int*)d_in[11];
    const int* s_cols = (const int*)d_in[12];
    const int* tail_idx = (const int*)d_in[13];
    const int* head_idx = (const int*)d_in[14];
    const int* batch_user = (const int*)d_in[15];
    const int* batch_pos = (const int*)d_in[16];
    const int* batch_neg = (const int*)d_in[17];
    float* out = (float*)d_out;

    // ---- workspace carve ----
    char* p = (char*)d_ws;
    auto carve = [&](size_t bytes) -> void* {
        void* r = (void*)p;
        p += (bytes + 255) & ~size_t(255);
        return r;
    };
    float* embA = (float*)carve((size_t)N_TOTALC * 64 * 4);
    float* embB = (float*)carve((size_t)N_TOTALC * 64 * 4);
    float* u1 = (float*)carve((size_t)N_USERC * 64 * 4);
    float* u2 = (float*)carve((size_t)N_USERC * 64 * 4);
    float* enh = (float*)carve((size_t)N_ITEMC * 64 * 4);
    float* tail_e = (float*)carve((size_t)N_TAILC * 64 * 4);
    float* top_e = (float*)carve((size_t)N_HEADC * 64 * 4);
    int2* aSort = (int2*)carve((size_t)NNZ_AC * 8);       // final row-grouped entries
    int2* sSort = (int2*)carve((size_t)NNZ_SC * 8);
    int* a_rowptr = (int*)carve((size_t)(N_TOTALC + 1) * 4);
    int* s_rowptr = (int*)carve((size_t)(N_USERC + 1) * 4);
    int* aCnt = (int*)carve((size_t)NB_A * 4);
    int* sCnt = (int*)carve((size_t)NB_S * 4);
    int* aCur = (int*)carve((size_t)NB_A * 4);
    int* sCur = (int*)carve((size_t)NB_S * 4);
    int* ig_cols_buf = (int*)carve((size_t)N_TAILC * TOPKC * 4);
    float* ig_vals_buf = (float*)carve((size_t)N_TAILC * TOPKC * 4);
    float* Mrm = (float*)carve(64 * 64 * 4);
    float* cvec = (float*)carve(64 * 4);
    float* scores = (float*)carve((size_t)CHUNK_ROWS * N_HEADC * 4);   // 40MB
    // raw (bucket-ordered) pack buffers alias the scores region: dead before score phase
    int2* aPackRaw = (int2*)scores;
    int2* sPackRaw = aPackRaw + NNZ_AC;   // 16MB + 8MB = 24MB < 40MB

    // ---- bucketed CSR build (A + S) ----
    hipMemsetAsync(aCnt, 0, (size_t)NB_A * 4, stream);
    hipMemsetAsync(sCnt, 0, (size_t)NB_S * 4, stream);
    hist_bucket<<<PBLK_A + PBLK_S, 256, 0, stream>>>(a_rows, s_rows, aCnt, sCnt);
    scan_buckets<<<2, 256, 0, stream>>>(aCnt, sCnt, aCur, sCur);
    partition_fused<<<PBLK_A + PBLK_S, 256, 0, stream>>>(a_vals, a_rows, a_cols,
                                                         s_vals, s_rows, s_cols,
                                                         aCur, sCur, aPackRaw, sPackRaw);
    // aCur/sCur now hold bucket END offsets
    csr_finalize<<<NB_A + NB_S, 256, 0, stream>>>(aCur, sCur, aPackRaw, sPackRaw,
                                                  aSort, sSort, a_rowptr, s_rowptr);

    // ---- collapsed encoder (tail + head fused) ----
    mc_kernel<<<17, 256, 0, stream>>>(w0, b0, w2, b2, Mrm, cvec);
    enc2_fused<<<(N_TAILC + N_HEADC + 3) / 4, 256, 0, stream>>>(item_emb, tail_idx, head_idx, Mrm, cvec, tail_e, top_e);

    // ---- chunked scores GEMM + top-k (aPackRaw dead from here) ----
    for (int row0 = 0; row0 < N_TAILC; row0 += CHUNK_ROWS) {
        int m = N_TAILC - row0;
        if (m > CHUNK_ROWS) m = CHUNK_ROWS;
        int rb = (m + 127) / 128;
        score_gemm<<<dim3((N_HEADC + 127) / 128, rb), 256, 0, stream>>>(tail_e + (size_t)row0 * 64, top_e, scores, m);
        topk_rows<<<(m + 3) / 4, 256, 0, stream>>>(scores, m, row0, head_idx, ig_cols_buf, ig_vals_buf);
    }

    // ---- 3 A-layers (first reads inputs directly, then ping-pong) ----
    {
        int blocks = (N_TOTALC + 3) / 4;
        spmm_csr_concat<<<blocks, 256, 0, stream>>>(a_rowptr, aSort, user_emb, item_emb, embB, N_TOTALC);
        spmm_csr<<<blocks, 256, 0, stream>>>(a_rowptr, aSort, embB, embA, N_TOTALC);
        spmm_csr<<<blocks, 256, 0, stream>>>(a_rowptr, aSort, embA, embB, N_TOTALC);
    }
    const float* u0 = embB;
    const float* items = embB + (size_t)N_USERC * 64;

    // ---- 2 S-layers on users ----
    {
        int blocks = (N_USERC + 3) / 4;
        spmm_csr<<<blocks, 256, 0, stream>>>(s_rowptr, sSort, u0, u1, N_USERC);
        spmm_csr<<<blocks, 256, 0, stream>>>(s_rowptr, sSort, u1, u2, N_USERC);
    }

    // ---- item enhancement ----
    hipMemsetAsync(enh, 0, (size_t)N_ITEMC * 64 * 4, stream);
    ig_spmm_kernel<<<(N_TAILC * TOPKC) / 4, 256, 0, stream>>>(tail_idx, ig_cols_buf, ig_vals_buf, items, enh);

    // ---- loss + reg ----
    hipMemsetAsync(out, 0, 2 * sizeof(float), stream);
    loss_kernel<<<BATCHC / 4, 256, 0, stream>>>(u0, u1, u2, items, enh, item_degree,
                                                user_emb, item_emb, batch_user, batch_pos, batch_neg, out);
}

// Round 6
// 1147.365 us; speedup vs baseline: 3.3486x; 1.0866x over previous
//
#include <hip/hip_runtime.h>

#define N_USERC 100000
#define N_ITEMC 50000
#define N_TOTALC 150000
#define DC 64
#define NNZ_AC 2000000
#define NNZ_SC 1000000
#define N_TAILC 10000
#define N_HEADC 4000
#define TOPKC 10
#define BATCHC 4096
#define N_NEGC 4
#define CONVF 40.0f
#define CHUNK_ROWS 2500

#define RPB 128                                  // rows per bucket
#define NB_A ((N_TOTALC + RPB - 1) / RPB)        // 1172
#define NB_S ((N_USERC + RPB - 1) / RPB)         // 782
#define IPB 12288                                // items per partition block
#define PBLK_A ((NNZ_AC + IPB - 1) / IPB)        // 163
#define PBLK_S ((NNZ_SC + IPB - 1) / IPB)        // 82

#define LOSS_BLOCKS (BATCHC / 4)                 // 1024

// ---------------- bucket histogram: LDS pre-aggregation, then flush ----------------
__global__ __launch_bounds__(256) void hist_bucket(const int* __restrict__ a_rows, const int* __restrict__ s_rows,
                                                   int* __restrict__ aCnt, int* __restrict__ sCnt) {
    __shared__ int h[NB_A];
    int blk = blockIdx.x;
    const int* rows; int n; int nb; int* gout; int base;
    if (blk < PBLK_A) { rows = a_rows; n = NNZ_AC; nb = NB_A; gout = aCnt; base = blk * IPB; }
    else { rows = s_rows; n = NNZ_SC; nb = NB_S; gout = sCnt; base = (blk - PBLK_A) * IPB; }
    for (int i = threadIdx.x; i < nb; i += 256) h[i] = 0;
    __syncthreads();
    for (int k = 0; k < IPB; k += 256) {
        int idx = base + k + threadIdx.x;
        if (idx < n) atomicAdd(&h[rows[idx] >> 7], 1);
    }
    __syncthreads();
    for (int i = threadIdx.x; i < nb; i += 256) {
        int c = h[i];
        if (c) atomicAdd(&gout[i], c);
    }
}

// ---------------- exclusive scan of bucket counts -> cursor bases (2 blocks) ----------------
__global__ __launch_bounds__(256) void scan_buckets(const int* __restrict__ aCnt, const int* __restrict__ sCnt,
                                                    int* __restrict__ aCur, int* __restrict__ sCur) {
    __shared__ int lds[256];
    const int* cnt; int* cur; int nb;
    if (blockIdx.x == 0) { cnt = aCnt; cur = aCur; nb = NB_A; }
    else { cnt = sCnt; cur = sCur; nb = NB_S; }
    int tid = threadIdx.x;
    int v[5]; int s = 0;
#pragma unroll
    for (int k = 0; k < 5; ++k) {
        int i = tid * 5 + k;
        v[k] = s;
        s += (i < nb) ? cnt[i] : 0;
    }
    lds[tid] = s;
    __syncthreads();
    for (int off = 1; off < 256; off <<= 1) {
        int t = (tid >= off) ? lds[tid - off] : 0;
        __syncthreads();
        lds[tid] += t;
        __syncthreads();
    }
    int base = (tid > 0) ? lds[tid - 1] : 0;
#pragma unroll
    for (int k = 0; k < 5; ++k) {
        int i = tid * 5 + k;
        if (i < nb) cur[i] = base + v[k];
    }
}

// ---------------- partition: block-local counting sort into bucket regions ----------------
// pack.y = col | (row_in_bucket << 18)   (col < 262144, rl < 128)
__global__ __launch_bounds__(256) void partition_fused(
    const float* __restrict__ a_vals, const int* __restrict__ a_rows, const int* __restrict__ a_cols,
    const float* __restrict__ s_vals, const int* __restrict__ s_rows, const int* __restrict__ s_cols,
    int* __restrict__ aCur, int* __restrict__ sCur,
    int2* __restrict__ aPack, int2* __restrict__ sPack) {
    __shared__ int h[NB_A];
    __shared__ int cur[NB_A];
    int blk = blockIdx.x;
    const float* vals; const int* rows; const int* cols; int n; int nb; int* gcur; int2* pack; int base;
    if (blk < PBLK_A) { vals = a_vals; rows = a_rows; cols = a_cols; n = NNZ_AC; nb = NB_A; gcur = aCur; pack = aPack; base = blk * IPB; }
    else { vals = s_vals; rows = s_rows; cols = s_cols; n = NNZ_SC; nb = NB_S; gcur = sCur; pack = sPack; base = (blk - PBLK_A) * IPB; }
    int tid = threadIdx.x;
    for (int i = tid; i < nb; i += 256) h[i] = 0;
    __syncthreads();
    for (int k = 0; k < IPB; k += 256) {
        int idx = base + k + tid;
        if (idx < n) atomicAdd(&h[rows[idx] >> 7], 1);
    }
    __syncthreads();
    for (int i = tid; i < nb; i += 256) {
        int c = h[i];
        cur[i] = c ? atomicAdd(&gcur[i], c) : 0;
    }
    __syncthreads();
    for (int k = 0; k < IPB; k += 256) {
        int idx = base + k + tid;
        if (idx < n) {
            int r = rows[idx];
            int b = r >> 7;
            int pos = atomicAdd(&cur[b], 1);
            pack[pos] = make_int2(__float_as_int(vals[idx]), cols[idx] | ((r & 127) << 18));
        }
    }
}

// ---------------- finalize: per-bucket counting sort -> row-grouped entries + rowptr ----------------
__global__ __launch_bounds__(256) void csr_finalize(const int* __restrict__ aEnd, const int* __restrict__ sEnd,
                                                    const int2* __restrict__ aRaw, const int2* __restrict__ sRaw,
                                                    int2* __restrict__ aOut, int2* __restrict__ sOut,
                                                    int* __restrict__ aRp, int* __restrict__ sRp) {
    __shared__ int cnt_[RPB];
    __shared__ int scn[RPB];
    __shared__ int cursor[RPB];
    int blk = blockIdx.x;
    const int* ends; const int2* raw; int2* outp; int* rp; int nb; int nrows; int b;
    if (blk < NB_A) { ends = aEnd; raw = aRaw; outp = aOut; rp = aRp; nb = NB_A; nrows = N_TOTALC; b = blk; }
    else { ends = sEnd; raw = sRaw; outp = sOut; rp = sRp; nb = NB_S; nrows = N_USERC; b = blk - NB_A; }
    int s = b ? ends[b - 1] : 0;
    int e = ends[b];
    int n = e - s;
    int tid = threadIdx.x;
    if (tid < RPB) cnt_[tid] = 0;
    __syncthreads();
    for (int i = tid; i < n; i += 256)
        atomicAdd(&cnt_[(raw[s + i].y >> 18) & 127], 1);
    __syncthreads();
    if (tid < RPB) scn[tid] = cnt_[tid];
    __syncthreads();
    for (int off = 1; off < RPB; off <<= 1) {
        int t = (tid < RPB && tid >= off) ? scn[tid - off] : 0;
        __syncthreads();
        if (tid < RPB) scn[tid] += t;
        __syncthreads();
    }
    if (tid < RPB) {
        int ex = scn[tid] - cnt_[tid];      // exclusive
        cursor[tid] = ex;
        int row = (b << 7) + tid;
        if (row < nrows) rp[row] = s + ex;
    }
    if (b == nb - 1 && tid == 0) rp[nrows] = e;
    __syncthreads();
    for (int i = tid; i < n; i += 256) {
        int2 en = raw[s + i];
        int r = (en.y >> 18) & 127;
        int pos = atomicAdd(&cursor[r], 1);
        outp[s + pos] = make_int2(en.x, en.y & 0x3FFFF);
    }
}

// ---------------- CSR SpMM (packed): one wave per row, lane = feature dim ----------------
__global__ __launch_bounds__(256) void spmm_csr(const int* __restrict__ rowptr,
                                                const int2* __restrict__ pack,
                                                const float* __restrict__ x,
                                                float* __restrict__ y, int nrows) {
    int w = (blockIdx.x * blockDim.x + threadIdx.x) >> 6;
    int lane = threadIdx.x & 63;
    if (w >= nrows) return;
    int s = rowptr[w], e = rowptr[w + 1];
    float a0 = 0.f, a1 = 0.f, a2 = 0.f, a3 = 0.f;
    int j = s;
    for (; j + 4 <= e; j += 4) {
        int2 e0 = pack[j], e1 = pack[j + 1], e2 = pack[j + 2], e3 = pack[j + 3];
        a0 += __int_as_float(e0.x) * x[(size_t)e0.y * 64 + lane];
        a1 += __int_as_float(e1.x) * x[(size_t)e1.y * 64 + lane];
        a2 += __int_as_float(e2.x) * x[(size_t)e2.y * 64 + lane];
        a3 += __int_as_float(e3.x) * x[(size_t)e3.y * 64 + lane];
    }
    for (; j < e; ++j) {
        int2 e0 = pack[j];
        a0 += __int_as_float(e0.x) * x[(size_t)e0.y * 64 + lane];
    }
    y[(size_t)w * 64 + lane] = a0 + a1 + a2 + a3;
}

// first A-layer: reads the virtual concat [user_emb; item_emb] directly
__global__ __launch_bounds__(256) void spmm_csr_concat(const int* __restrict__ rowptr,
                                                       const int2* __restrict__ pack,
                                                       const float* __restrict__ xu,
                                                       const float* __restrict__ xi,
                                                       float* __restrict__ y, int nrows) {
    int w = (blockIdx.x * blockDim.x + threadIdx.x) >> 6;
    int lane = threadIdx.x & 63;
    if (w >= nrows) return;
    int s = rowptr[w], e = rowptr[w + 1];
    float a0 = 0.f, a1 = 0.f, a2 = 0.f, a3 = 0.f;
    int j = s;
#define GATHER(c) ((c) < N_USERC ? xu[(size_t)(c) * 64 + lane] : xi[(size_t)((c) - N_USERC) * 64 + lane])
    for (; j + 4 <= e; j += 4) {
        int2 e0 = pack[j], e1 = pack[j + 1], e2 = pack[j + 2], e3 = pack[j + 3];
        a0 += __int_as_float(e0.x) * GATHER(e0.y);
        a1 += __int_as_float(e1.x) * GATHER(e1.y);
        a2 += __int_as_float(e2.x) * GATHER(e2.y);
        a3 += __int_as_float(e3.x) * GATHER(e3.y);
    }
    for (; j < e; ++j) {
        int2 e0 = pack[j];
        a0 += __int_as_float(e0.x) * GATHER(e0.y);
    }
#undef GATHER
    y[(size_t)w * 64 + lane] = a0 + a1 + a2 + a3;
}

// ---------------- collapsed encoder ----------------
__global__ __launch_bounds__(256) void mc_kernel(const float* __restrict__ w0, const float* __restrict__ b0,
                                                 const float* __restrict__ w2, const float* __restrict__ b2,
                                                 float* __restrict__ Mrm, float* __restrict__ cvec) {
    int idx = blockIdx.x * 256 + threadIdx.x;
    if (idx < 4096) {
        int j = idx >> 6, d = idx & 63;
        float acc = 0.f;
        for (int k = 0; k < 256; ++k) acc += w2[j * 256 + k] * w0[k * 64 + d];
        Mrm[idx] = acc;
    } else if (idx < 4160) {
        int i = idx - 4096;
        float acc = b2[i];
        for (int k = 0; k < 256; ++k) acc += w2[i * 256 + k] * b0[k];
        cvec[i] = acc;
    }
}

// enc(f) = f @ Mrm^T + cvec ; one wave per row; fused tail+head
__global__ __launch_bounds__(256) void enc2_fused(const float* __restrict__ emb,
                                                  const int* __restrict__ tail_idx, const int* __restrict__ head_idx,
                                                  const float* __restrict__ Mrm, const float* __restrict__ cvec,
                                                  float* __restrict__ tail_e, float* __restrict__ top_e) {
    __shared__ float fsh[4][64];
    int wv = threadIdx.x >> 6, lane = threadIdx.x & 63;
    int r = blockIdx.x * 4 + wv;
    int item;
    float* outp;
    if (r < N_TAILC) { item = tail_idx[r]; outp = tail_e + (size_t)r * 64; }
    else if (r < N_TAILC + N_HEADC) { item = head_idx[r - N_TAILC]; outp = top_e + (size_t)(r - N_TAILC) * 64; }
    else { item = -1; outp = nullptr; }
    if (item >= 0) fsh[wv][lane] = emb[(size_t)item * 64 + lane];
    __syncthreads();
    if (item < 0) return;
    float acc = cvec[lane];
#pragma unroll
    for (int d4 = 0; d4 < 64; d4 += 4) {
        float4 m4 = *(const float4*)&Mrm[lane * 64 + d4];
        float4 f4 = *(const float4*)&fsh[wv][d4];
        acc += m4.x * f4.x + m4.y * f4.y + m4.z * f4.z + m4.w * f4.w;
    }
    outp[lane] = acc;
}

// ---------------- score GEMM: C[m x 4000] = A[m x 64] @ B[4000 x 64]^T ----------------
__global__ __launch_bounds__(256) void score_gemm(const float* __restrict__ A,
                                                  const float* __restrict__ B,
                                                  float* __restrict__ C, int M) {
    __shared__ float As[32][132];
    __shared__ float Bs[32][132];
    int tid = threadIdx.x;
    int tx = tid & 15, ty = tid >> 4;
    int rowbase = blockIdx.y * 128;
    int colbase = blockIdx.x * 128;
    float acc[8][8];
#pragma unroll
    for (int i = 0; i < 8; ++i)
#pragma unroll
        for (int j = 0; j < 8; ++j) acc[i][j] = 0.f;

    for (int k0 = 0; k0 < 64; k0 += 32) {
        __syncthreads();
#pragma unroll
        for (int i = 0; i < 4; ++i) {
            int f = tid + i * 256;
            int r = f >> 3;
            int kq = (f & 7) << 2;
            int grow = rowbase + r;
            float4 av = (grow < M) ? *(const float4*)&A[(size_t)grow * 64 + k0 + kq]
                                   : make_float4(0.f, 0.f, 0.f, 0.f);
            As[kq + 0][r] = av.x; As[kq + 1][r] = av.y; As[kq + 2][r] = av.z; As[kq + 3][r] = av.w;
            int gcol = colbase + r;
            float4 bv = (gcol < N_HEADC) ? *(const float4*)&B[(size_t)gcol * 64 + k0 + kq]
                                         : make_float4(0.f, 0.f, 0.f, 0.f);
            Bs[kq + 0][r] = bv.x; Bs[kq + 1][r] = bv.y; Bs[kq + 2][r] = bv.z; Bs[kq + 3][r] = bv.w;
        }
        __syncthreads();
#pragma unroll
        for (int k = 0; k < 32; ++k) {
            float a[8], b[8];
#pragma unroll
            for (int i = 0; i < 8; ++i) a[i] = As[k][ty + 16 * i];
#pragma unroll
            for (int j = 0; j < 8; ++j) b[j] = Bs[k][tx + 16 * j];
#pragma unroll
            for (int i = 0; i < 8; ++i)
#pragma unroll
                for (int j = 0; j < 8; ++j) acc[i][j] += a[i] * b[j];
        }
    }
#pragma unroll
    for (int i = 0; i < 8; ++i) {
        int r = rowbase + ty + 16 * i;
        if (r < M) {
#pragma unroll
            for (int j = 0; j < 8; ++j) {
                int c = colbase + tx + 16 * j;
                if (c < N_HEADC) C[(size_t)r * N_HEADC + c] = acc[i][j];
            }
        }
    }
}

// ---------------- per-row top-k on materialized scores ----------------
__global__ __launch_bounds__(256) void topk_rows(const float* __restrict__ scores, int nrows, int row0,
                                                 const int* __restrict__ head_idx,
                                                 int* __restrict__ ig_cols, float* __restrict__ ig_vals) {
    int w = (blockIdx.x * blockDim.x + threadIdx.x) >> 6;
    int lane = threadIdx.x & 63;
    if (w >= nrows) return;
    const float* srow = scores + (size_t)w * N_HEADC;
    float v[TOPKC];
    int id[TOPKC];
#pragma unroll
    for (int k = 0; k < TOPKC; ++k) { v[k] = -1e30f; id[k] = -1; }
    for (int it = 0; it < 16; ++it) {
        int f4 = lane + it * 64;
        if (f4 < 1000) {
            float4 s4 = ((const float4*)srow)[f4];
            int cb = f4 * 4;
            float vv[4] = { s4.x, s4.y, s4.z, s4.w };
#pragma unroll
            for (int q = 0; q < 4; ++q) {
                float sc = vv[q];
                if (sc > v[TOPKC - 1]) {
                    float cv = sc; int ci = cb + q;
#pragma unroll
                    for (int k = 0; k < TOPKC; ++k) {
                        if (cv > v[k]) { float t = v[k]; int ti = id[k]; v[k] = cv; id[k] = ci; cv = t; ci = ti; }
                    }
                }
            }
        }
    }
    int ptr = 0;
    float ssum = 0.f;
    float outv = 0.f;
    int outid = -1;
#pragma unroll
    for (int r = 0; r < TOPKC; ++r) {
        float cv = (ptr < TOPKC) ? v[ptr] : -1e30f;
        int ci = (ptr < TOPKC) ? id[ptr] : -1;
        int wl = lane;
#pragma unroll
        for (int m = 1; m < 64; m <<= 1) {
            float ov = __shfl_xor(cv, m, 64);
            int oi = __shfl_xor(ci, m, 64);
            int ol = __shfl_xor(wl, m, 64);
            if (ov > cv || (ov == cv && ol < wl)) { cv = ov; ci = oi; wl = ol; }
        }
        if (wl == lane) ptr++;
        ssum += 1.f / (1.f + expf(-cv));
        if (lane == r) { outv = cv; outid = ci; }
    }
    if (lane < TOPKC) {
        float s = 1.f / (1.f + expf(-outv));
        float wgt = s / (ssum + 1.f);
        int grow = row0 + w;
        ig_vals[grow * TOPKC + lane] = wgt;
        ig_cols[grow * TOPKC + lane] = head_idx[outid];
    }
}

// ---------------- item_enh accumulation ----------------
__global__ __launch_bounds__(256) void ig_spmm_kernel(const int* __restrict__ tail_idx,
                                                      const int* __restrict__ ig_cols,
                                                      const float* __restrict__ ig_vals,
                                                      const float* __restrict__ items,
                                                      float* __restrict__ enh) {
    int e = (blockIdx.x * blockDim.x + threadIdx.x) >> 6;
    int lane = threadIdx.x & 63;
    if (e >= N_TAILC * TOPKC) return;
    int row = tail_idx[e / TOPKC];
    int col = ig_cols[e];
    float w = ig_vals[e];
    atomicAdd(&enh[(size_t)row * 64 + lane], w * items[(size_t)col * 64 + lane]);
}

// ---------------- loss: one wave per sample, per-block partial outputs (NO global atomics) ----------------
__global__ __launch_bounds__(256) void loss_kernel(const float* __restrict__ u0, const float* __restrict__ u1,
                                                   const float* __restrict__ u2, const float* __restrict__ items,
                                                   const float* __restrict__ enh, const float* __restrict__ deg,
                                                   const float* __restrict__ user_emb, const float* __restrict__ item_emb,
                                                   const int* __restrict__ bu, const int* __restrict__ bp,
                                                   const int* __restrict__ bn, float* __restrict__ part) {
    __shared__ float lsum[4], rsum[4];
    int w = (blockIdx.x * blockDim.x + threadIdx.x) >> 6;
    int wv = threadIdx.x >> 6;
    int lane = threadIdx.x & 63;
    int uu = bu[w], pp = bp[w];
    float ue = (u0[uu * 64 + lane] + u1[uu * 64 + lane] + u2[uu * 64 + lane]) * (1.f / 3.f);
    float swp = CONVF / (CONVF + expf(deg[pp] * (1.f / CONVF)));
    float pe = items[pp * 64 + lane] + swp * enh[pp * 64 + lane];
    float ps = ue * pe;
    float ns = 0.f;
    float u0e = user_emb[uu * 64 + lane];
    float p0e = item_emb[pp * 64 + lane];
    float reg = u0e * u0e + p0e * p0e;
#pragma unroll
    for (int k = 0; k < N_NEGC; ++k) {
        int nn = bn[w * N_NEGC + k];
        float swn = CONVF / (CONVF + expf(deg[nn] * (1.f / CONVF)));
        float nv = items[nn * 64 + lane] + swn * enh[nn * 64 + lane];
        ns += ue * nv;
        float n0 = item_emb[nn * 64 + lane];
        reg += n0 * n0;
    }
#pragma unroll
    for (int m = 32; m >= 1; m >>= 1) {
        ps += __shfl_xor(ps, m, 64);
        ns += __shfl_xor(ns, m, 64);
        reg += __shfl_xor(reg, m, 64);
    }
    if (lane == 0) {
        float x = ns * (1.f / N_NEGC) - ps;
        float sp = (x > 0.f) ? (x + log1pf(expf(-x))) : log1pf(expf(x));
        lsum[wv] = sp;
        rsum[wv] = reg;
    }
    __syncthreads();
    if (threadIdx.x == 0) {
        part[blockIdx.x] = lsum[0] + lsum[1] + lsum[2] + lsum[3];
        part[LOSS_BLOCKS + blockIdx.x] = rsum[0] + rsum[1] + rsum[2] + rsum[3];
    }
}

// single-block final reduce: out[0]=loss, out[1]=reg
__global__ __launch_bounds__(256) void loss_reduce(const float* __restrict__ part, float* __restrict__ out) {
    __shared__ float l[256], r[256];
    int tid = threadIdx.x;
    float a = 0.f, b = 0.f;
    for (int i = tid; i < LOSS_BLOCKS; i += 256) {
        a += part[i];
        b += part[LOSS_BLOCKS + i];
    }
    l[tid] = a; r[tid] = b;
    __syncthreads();
    for (int off = 128; off >= 1; off >>= 1) {
        if (tid < off) { l[tid] += l[tid + off]; r[tid] += r[tid + off]; }
        __syncthreads();
    }
    if (tid == 0) {
        out[0] = l[0] * (1.f / BATCHC);
        out[1] = 0.5f * r[0] * (1.f / BATCHC);
    }
}

extern "C" void kernel_launch(void* const* d_in, const int* in_sizes, int n_in,
                              void* d_out, int out_size, void* d_ws, size_t ws_size,
                              hipStream_t stream) {
    const float* user_emb = (const float*)d_in[0];
    const float* item_emb = (const float*)d_in[1];
    const float* w0 = (const float*)d_in[2];
    const float* b0 = (const float*)d_in[3];
    const float* w2 = (const float*)d_in[4];
    const float* b2 = (const float*)d_in[5];
    const float* a_vals = (const float*)d_in[6];
    const float* s_vals = (const float*)d_in[7];
    const float* item_degree = (const float*)d_in[8];
    const int* a_rows = (const int*)d_in[9];
    const int* a_cols = (const int*)d_in[10];
    const int* s_rows = (const int*)d_in[11];
    const int* s_cols = (const int*)d_in[12];
    const int* tail_idx = (const int*)d_in[13];
    const int* head_idx = (const int*)d_in[14];
    const int* batch_user = (const int*)d_in[15];
    const int* batch_pos = (const int*)d_in[16];
    const int* batch_neg = (const int*)d_in[17];
    float* out = (float*)d_out;

    // ---- workspace carve ----
    char* p = (char*)d_ws;
    auto carve = [&](size_t bytes) -> void* {
        void* r = (void*)p;
        p += (bytes + 255) & ~size_t(255);
        return r;
    };
    float* embA = (float*)carve((size_t)N_TOTALC * 64 * 4);
    float* embB = (float*)carve((size_t)N_TOTALC * 64 * 4);
    float* u1 = (float*)carve((size_t)N_USERC * 64 * 4);
    float* u2 = (float*)carve((size_t)N_USERC * 64 * 4);
    float* enh = (float*)carve((size_t)N_ITEMC * 64 * 4);
    float* tail_e = (float*)carve((size_t)N_TAILC * 64 * 4);
    float* top_e = (float*)carve((size_t)N_HEADC * 64 * 4);
    int2* aSort = (int2*)carve((size_t)NNZ_AC * 8);       // final row-grouped entries
    int2* sSort = (int2*)carve((size_t)NNZ_SC * 8);
    int* a_rowptr = (int*)carve((size_t)(N_TOTALC + 1) * 4);
    int* s_rowptr = (int*)carve((size_t)(N_USERC + 1) * 4);
    int* aCnt = (int*)carve((size_t)NB_A * 4);
    int* sCnt = (int*)carve((size_t)NB_S * 4);
    int* aCur = (int*)carve((size_t)NB_A * 4);
    int* sCur = (int*)carve((size_t)NB_S * 4);
    int* ig_cols_buf = (int*)carve((size_t)N_TAILC * TOPKC * 4);
    float* ig_vals_buf = (float*)carve((size_t)N_TAILC * TOPKC * 4);
    float* Mrm = (float*)carve(64 * 64 * 4);
    float* cvec = (float*)carve(64 * 4);
    float* loss_part = (float*)carve((size_t)LOSS_BLOCKS * 2 * 4);
    float* scores = (float*)carve((size_t)CHUNK_ROWS * N_HEADC * 4);   // 40MB
    // raw (bucket-ordered) pack buffers alias the scores region: dead before score phase
    int2* aPackRaw = (int2*)scores;
    int2* sPackRaw = aPackRaw + NNZ_AC;   // 16MB + 8MB = 24MB < 40MB

    // ---- bucketed CSR build (A + S) ----
    hipMemsetAsync(aCnt, 0, (size_t)NB_A * 4, stream);
    hipMemsetAsync(sCnt, 0, (size_t)NB_S * 4, stream);
    hist_bucket<<<PBLK_A + PBLK_S, 256, 0, stream>>>(a_rows, s_rows, aCnt, sCnt);
    scan_buckets<<<2, 256, 0, stream>>>(aCnt, sCnt, aCur, sCur);
    partition_fused<<<PBLK_A + PBLK_S, 256, 0, stream>>>(a_vals, a_rows, a_cols,
                                                         s_vals, s_rows, s_cols,
                                                         aCur, sCur, aPackRaw, sPackRaw);
    // aCur/sCur now hold bucket END offsets
    csr_finalize<<<NB_A + NB_S, 256, 0, stream>>>(aCur, sCur, aPackRaw, sPackRaw,
                                                  aSort, sSort, a_rowptr, s_rowptr);

    // ---- collapsed encoder (tail + head fused) ----
    mc_kernel<<<17, 256, 0, stream>>>(w0, b0, w2, b2, Mrm, cvec);
    enc2_fused<<<(N_TAILC + N_HEADC + 3) / 4, 256, 0, stream>>>(item_emb, tail_idx, head_idx, Mrm, cvec, tail_e, top_e);

    // ---- chunked scores GEMM + top-k (aPackRaw dead from here) ----
    for (int row0 = 0; row0 < N_TAILC; row0 += CHUNK_ROWS) {
        int m = N_TAILC - row0;
        if (m > CHUNK_ROWS) m = CHUNK_ROWS;
        int rb = (m + 127) / 128;
        score_gemm<<<dim3((N_HEADC + 127) / 128, rb), 256, 0, stream>>>(tail_e + (size_t)row0 * 64, top_e, scores, m);
        topk_rows<<<(m + 3) / 4, 256, 0, stream>>>(scores, m, row0, head_idx, ig_cols_buf, ig_vals_buf);
    }

    // ---- 3 A-layers (first reads inputs directly, then ping-pong) ----
    {
        int blocks = (N_TOTALC + 3) / 4;
        spmm_csr_concat<<<blocks, 256, 0, stream>>>(a_rowptr, aSort, user_emb, item_emb, embB, N_TOTALC);
        spmm_csr<<<blocks, 256, 0, stream>>>(a_rowptr, aSort, embB, embA, N_TOTALC);
        spmm_csr<<<blocks, 256, 0, stream>>>(a_rowptr, aSort, embA, embB, N_TOTALC);
    }
    const float* u0 = embB;
    const float* items = embB + (size_t)N_USERC * 64;

    // ---- 2 S-layers on users ----
    {
        int blocks = (N_USERC + 3) / 4;
        spmm_csr<<<blocks, 256, 0, stream>>>(s_rowptr, sSort, u0, u1, N_USERC);
        spmm_csr<<<blocks, 256, 0, stream>>>(s_rowptr, sSort, u1, u2, N_USERC);
    }

    // ---- item enhancement ----
    hipMemsetAsync(enh, 0, (size_t)N_ITEMC * 64 * 4, stream);
    ig_spmm_kernel<<<(N_TAILC * TOPKC) / 4, 256, 0, stream>>>(tail_idx, ig_cols_buf, ig_vals_buf, items, enh);

    // ---- loss + reg: per-block partials then single-block reduce ----
    loss_kernel<<<LOSS_BLOCKS, 256, 0, stream>>>(u0, u1, u2, items, enh, item_degree,
                                                 user_emb, item_emb, batch_user, batch_pos, batch_neg, loss_part);
    loss_reduce<<<1, 256, 0, stream>>>(loss_part, out);
}

// Round 7
// 1116.836 us; speedup vs baseline: 3.4402x; 1.0273x over previous
//
#include <hip/hip_runtime.h>

#define N_USERC 100000
#define N_ITEMC 50000
#define N_TOTALC 150000
#define DC 64
#define NNZ_AC 2000000
#define NNZ_SC 1000000
#define N_TAILC 10000
#define N_HEADC 4000
#define TOPKC 10
#define BATCHC 4096
#define N_NEGC 4
#define CONVF 40.0f
#define CHUNK_ROWS 2500

#define RPB 128                                  // rows per bucket
#define NB_A ((N_TOTALC + RPB - 1) / RPB)        // 1172
#define NB_S ((N_USERC + RPB - 1) / RPB)         // 782
#define IPB 12288                                // items per partition block
#define PBLK_A ((NNZ_AC + IPB - 1) / IPB)        // 163
#define PBLK_S ((NNZ_SC + IPB - 1) / IPB)        // 82

#define LOSS_BLOCKS (BATCHC / 4)                 // 1024

// ---------------- bucket histogram: LDS pre-aggregation, then flush ----------------
__global__ __launch_bounds__(256) void hist_bucket(const int* __restrict__ a_rows, const int* __restrict__ s_rows,
                                                   int* __restrict__ aCnt, int* __restrict__ sCnt) {
    __shared__ int h[NB_A];
    int blk = blockIdx.x;
    const int* rows; int n; int nb; int* gout; int base;
    if (blk < PBLK_A) { rows = a_rows; n = NNZ_AC; nb = NB_A; gout = aCnt; base = blk * IPB; }
    else { rows = s_rows; n = NNZ_SC; nb = NB_S; gout = sCnt; base = (blk - PBLK_A) * IPB; }
    for (int i = threadIdx.x; i < nb; i += 256) h[i] = 0;
    __syncthreads();
    for (int k = 0; k < IPB; k += 256) {
        int idx = base + k + threadIdx.x;
        if (idx < n) atomicAdd(&h[rows[idx] >> 7], 1);
    }
    __syncthreads();
    for (int i = threadIdx.x; i < nb; i += 256) {
        int c = h[i];
        if (c) atomicAdd(&gout[i], c);
    }
}

// ---------------- exclusive scan of bucket counts -> cursor bases (2 blocks) ----------------
__global__ __launch_bounds__(256) void scan_buckets(const int* __restrict__ aCnt, const int* __restrict__ sCnt,
                                                    int* __restrict__ aCur, int* __restrict__ sCur) {
    __shared__ int lds[256];
    const int* cnt; int* cur; int nb;
    if (blockIdx.x == 0) { cnt = aCnt; cur = aCur; nb = NB_A; }
    else { cnt = sCnt; cur = sCur; nb = NB_S; }
    int tid = threadIdx.x;
    int v[5]; int s = 0;
#pragma unroll
    for (int k = 0; k < 5; ++k) {
        int i = tid * 5 + k;
        v[k] = s;
        s += (i < nb) ? cnt[i] : 0;
    }
    lds[tid] = s;
    __syncthreads();
    for (int off = 1; off < 256; off <<= 1) {
        int t = (tid >= off) ? lds[tid - off] : 0;
        __syncthreads();
        lds[tid] += t;
        __syncthreads();
    }
    int base = (tid > 0) ? lds[tid - 1] : 0;
#pragma unroll
    for (int k = 0; k < 5; ++k) {
        int i = tid * 5 + k;
        if (i < nb) cur[i] = base + v[k];
    }
}

// ---------------- partition: block-local counting sort into bucket regions ----------------
// pack.y = col | (row_in_bucket << 18)   (col < 262144, rl < 128)
__global__ __launch_bounds__(256) void partition_fused(
    const float* __restrict__ a_vals, const int* __restrict__ a_rows, const int* __restrict__ a_cols,
    const float* __restrict__ s_vals, const int* __restrict__ s_rows, const int* __restrict__ s_cols,
    int* __restrict__ aCur, int* __restrict__ sCur,
    int2* __restrict__ aPack, int2* __restrict__ sPack) {
    __shared__ int h[NB_A];
    __shared__ int cur[NB_A];
    int blk = blockIdx.x;
    const float* vals; const int* rows; const int* cols; int n; int nb; int* gcur; int2* pack; int base;
    if (blk < PBLK_A) { vals = a_vals; rows = a_rows; cols = a_cols; n = NNZ_AC; nb = NB_A; gcur = aCur; pack = aPack; base = blk * IPB; }
    else { vals = s_vals; rows = s_rows; cols = s_cols; n = NNZ_SC; nb = NB_S; gcur = sCur; pack = sPack; base = (blk - PBLK_A) * IPB; }
    int tid = threadIdx.x;
    for (int i = tid; i < nb; i += 256) h[i] = 0;
    __syncthreads();
    for (int k = 0; k < IPB; k += 256) {
        int idx = base + k + tid;
        if (idx < n) atomicAdd(&h[rows[idx] >> 7], 1);
    }
    __syncthreads();
    for (int i = tid; i < nb; i += 256) {
        int c = h[i];
        cur[i] = c ? atomicAdd(&gcur[i], c) : 0;
    }
    __syncthreads();
    for (int k = 0; k < IPB; k += 256) {
        int idx = base + k + tid;
        if (idx < n) {
            int r = rows[idx];
            int b = r >> 7;
            int pos = atomicAdd(&cur[b], 1);
            pack[pos] = make_int2(__float_as_int(vals[idx]), cols[idx] | ((r & 127) << 18));
        }
    }
}

// ---------------- finalize: per-bucket counting sort -> row-grouped entries + rowptr ----------------
__global__ __launch_bounds__(256) void csr_finalize(const int* __restrict__ aEnd, const int* __restrict__ sEnd,
                                                    const int2* __restrict__ aRaw, const int2* __restrict__ sRaw,
                                                    int2* __restrict__ aOut, int2* __restrict__ sOut,
                                                    int* __restrict__ aRp, int* __restrict__ sRp) {
    __shared__ int cnt_[RPB];
    __shared__ int scn[RPB];
    __shared__ int cursor[RPB];
    int blk = blockIdx.x;
    const int* ends; const int2* raw; int2* outp; int* rp; int nb; int nrows; int b;
    if (blk < NB_A) { ends = aEnd; raw = aRaw; outp = aOut; rp = aRp; nb = NB_A; nrows = N_TOTALC; b = blk; }
    else { ends = sEnd; raw = sRaw; outp = sOut; rp = sRp; nb = NB_S; nrows = N_USERC; b = blk - NB_A; }
    int s = b ? ends[b - 1] : 0;
    int e = ends[b];
    int n = e - s;
    int tid = threadIdx.x;
    if (tid < RPB) cnt_[tid] = 0;
    __syncthreads();
    for (int i = tid; i < n; i += 256)
        atomicAdd(&cnt_[(raw[s + i].y >> 18) & 127], 1);
    __syncthreads();
    if (tid < RPB) scn[tid] = cnt_[tid];
    __syncthreads();
    for (int off = 1; off < RPB; off <<= 1) {
        int t = (tid < RPB && tid >= off) ? scn[tid - off] : 0;
        __syncthreads();
        if (tid < RPB) scn[tid] += t;
        __syncthreads();
    }
    if (tid < RPB) {
        int ex = scn[tid] - cnt_[tid];      // exclusive
        cursor[tid] = ex;
        int row = (b << 7) + tid;
        if (row < nrows) rp[row] = s + ex;
    }
    if (b == nb - 1 && tid == 0) rp[nrows] = e;
    __syncthreads();
    for (int i = tid; i < n; i += 256) {
        int2 en = raw[s + i];
        int r = (en.y >> 18) & 127;
        int pos = atomicAdd(&cursor[r], 1);
        outp[s + pos] = make_int2(en.x, en.y & 0x3FFFF);
    }
}

// ---------------- CSR SpMM (packed): one wave per row, 8-deep gather pipeline ----------------
__global__ __launch_bounds__(256) void spmm_csr(const int* __restrict__ rowptr,
                                                const int2* __restrict__ pack,
                                                const float* __restrict__ x,
                                                float* __restrict__ y, int nrows) {
    int w = (blockIdx.x * blockDim.x + threadIdx.x) >> 6;
    int lane = threadIdx.x & 63;
    if (w >= nrows) return;
    int s = rowptr[w], e = rowptr[w + 1];
    float a0 = 0.f, a1 = 0.f, a2 = 0.f, a3 = 0.f;
    int j = s;
    for (; j + 8 <= e; j += 8) {
        int2 e0 = pack[j], e1 = pack[j + 1], e2 = pack[j + 2], e3 = pack[j + 3];
        int2 e4 = pack[j + 4], e5 = pack[j + 5], e6 = pack[j + 6], e7 = pack[j + 7];
        float g0 = x[(size_t)e0.y * 64 + lane];
        float g1 = x[(size_t)e1.y * 64 + lane];
        float g2 = x[(size_t)e2.y * 64 + lane];
        float g3 = x[(size_t)e3.y * 64 + lane];
        float g4 = x[(size_t)e4.y * 64 + lane];
        float g5 = x[(size_t)e5.y * 64 + lane];
        float g6 = x[(size_t)e6.y * 64 + lane];
        float g7 = x[(size_t)e7.y * 64 + lane];
        a0 += __int_as_float(e0.x) * g0;
        a1 += __int_as_float(e1.x) * g1;
        a2 += __int_as_float(e2.x) * g2;
        a3 += __int_as_float(e3.x) * g3;
        a0 += __int_as_float(e4.x) * g4;
        a1 += __int_as_float(e5.x) * g5;
        a2 += __int_as_float(e6.x) * g6;
        a3 += __int_as_float(e7.x) * g7;
    }
    if (j + 4 <= e) {
        int2 e0 = pack[j], e1 = pack[j + 1], e2 = pack[j + 2], e3 = pack[j + 3];
        float g0 = x[(size_t)e0.y * 64 + lane];
        float g1 = x[(size_t)e1.y * 64 + lane];
        float g2 = x[(size_t)e2.y * 64 + lane];
        float g3 = x[(size_t)e3.y * 64 + lane];
        a0 += __int_as_float(e0.x) * g0;
        a1 += __int_as_float(e1.x) * g1;
        a2 += __int_as_float(e2.x) * g2;
        a3 += __int_as_float(e3.x) * g3;
        j += 4;
    }
    for (; j < e; ++j) {
        int2 e0 = pack[j];
        a0 += __int_as_float(e0.x) * x[(size_t)e0.y * 64 + lane];
    }
    y[(size_t)w * 64 + lane] = (a0 + a1) + (a2 + a3);
}

// first A-layer: reads the virtual concat [user_emb; item_emb] directly
__global__ __launch_bounds__(256) void spmm_csr_concat(const int* __restrict__ rowptr,
                                                       const int2* __restrict__ pack,
                                                       const float* __restrict__ xu,
                                                       const float* __restrict__ xi,
                                                       float* __restrict__ y, int nrows) {
    int w = (blockIdx.x * blockDim.x + threadIdx.x) >> 6;
    int lane = threadIdx.x & 63;
    if (w >= nrows) return;
    int s = rowptr[w], e = rowptr[w + 1];
    float a0 = 0.f, a1 = 0.f, a2 = 0.f, a3 = 0.f;
    int j = s;
#define GATHER(c) ((c) < N_USERC ? xu[(size_t)(c) * 64 + lane] : xi[(size_t)((c) - N_USERC) * 64 + lane])
    for (; j + 8 <= e; j += 8) {
        int2 e0 = pack[j], e1 = pack[j + 1], e2 = pack[j + 2], e3 = pack[j + 3];
        int2 e4 = pack[j + 4], e5 = pack[j + 5], e6 = pack[j + 6], e7 = pack[j + 7];
        float g0 = GATHER(e0.y);
        float g1 = GATHER(e1.y);
        float g2 = GATHER(e2.y);
        float g3 = GATHER(e3.y);
        float g4 = GATHER(e4.y);
        float g5 = GATHER(e5.y);
        float g6 = GATHER(e6.y);
        float g7 = GATHER(e7.y);
        a0 += __int_as_float(e0.x) * g0;
        a1 += __int_as_float(e1.x) * g1;
        a2 += __int_as_float(e2.x) * g2;
        a3 += __int_as_float(e3.x) * g3;
        a0 += __int_as_float(e4.x) * g4;
        a1 += __int_as_float(e5.x) * g5;
        a2 += __int_as_float(e6.x) * g6;
        a3 += __int_as_float(e7.x) * g7;
    }
    if (j + 4 <= e) {
        int2 e0 = pack[j], e1 = pack[j + 1], e2 = pack[j + 2], e3 = pack[j + 3];
        float g0 = GATHER(e0.y);
        float g1 = GATHER(e1.y);
        float g2 = GATHER(e2.y);
        float g3 = GATHER(e3.y);
        a0 += __int_as_float(e0.x) * g0;
        a1 += __int_as_float(e1.x) * g1;
        a2 += __int_as_float(e2.x) * g2;
        a3 += __int_as_float(e3.x) * g3;
        j += 4;
    }
    for (; j < e; ++j) {
        int2 e0 = pack[j];
        a0 += __int_as_float(e0.x) * GATHER(e0.y);
    }
#undef GATHER
    y[(size_t)w * 64 + lane] = (a0 + a1) + (a2 + a3);
}

// ---------------- collapsed encoder ----------------
__global__ __launch_bounds__(256) void mc_kernel(const float* __restrict__ w0, const float* __restrict__ b0,
                                                 const float* __restrict__ w2, const float* __restrict__ b2,
                                                 float* __restrict__ Mrm, float* __restrict__ cvec) {
    int idx = blockIdx.x * 256 + threadIdx.x;
    if (idx < 4096) {
        int j = idx >> 6, d = idx & 63;
        float acc = 0.f;
        for (int k = 0; k < 256; ++k) acc += w2[j * 256 + k] * w0[k * 64 + d];
        Mrm[idx] = acc;
    } else if (idx < 4160) {
        int i = idx - 4096;
        float acc = b2[i];
        for (int k = 0; k < 256; ++k) acc += w2[i * 256 + k] * b0[k];
        cvec[i] = acc;
    }
}

// enc(f) = f @ Mrm^T + cvec ; one wave per row; fused tail+head
__global__ __launch_bounds__(256) void enc2_fused(const float* __restrict__ emb,
                                                  const int* __restrict__ tail_idx, const int* __restrict__ head_idx,
                                                  const float* __restrict__ Mrm, const float* __restrict__ cvec,
                                                  float* __restrict__ tail_e, float* __restrict__ top_e) {
    __shared__ float fsh[4][64];
    int wv = threadIdx.x >> 6, lane = threadIdx.x & 63;
    int r = blockIdx.x * 4 + wv;
    int item;
    float* outp;
    if (r < N_TAILC) { item = tail_idx[r]; outp = tail_e + (size_t)r * 64; }
    else if (r < N_TAILC + N_HEADC) { item = head_idx[r - N_TAILC]; outp = top_e + (size_t)(r - N_TAILC) * 64; }
    else { item = -1; outp = nullptr; }
    if (item >= 0) fsh[wv][lane] = emb[(size_t)item * 64 + lane];
    __syncthreads();
    if (item < 0) return;
    float acc = cvec[lane];
#pragma unroll
    for (int d4 = 0; d4 < 64; d4 += 4) {
        float4 m4 = *(const float4*)&Mrm[lane * 64 + d4];
        float4 f4 = *(const float4*)&fsh[wv][d4];
        acc += m4.x * f4.x + m4.y * f4.y + m4.z * f4.z + m4.w * f4.w;
    }
    outp[lane] = acc;
}

// ---------------- score GEMM: C[m x 4000] = A[m x 64] @ B[4000 x 64]^T ----------------
__global__ __launch_bounds__(256) void score_gemm(const float* __restrict__ A,
                                                  const float* __restrict__ B,
                                                  float* __restrict__ C, int M) {
    __shared__ float As[32][132];
    __shared__ float Bs[32][132];
    int tid = threadIdx.x;
    int tx = tid & 15, ty = tid >> 4;
    int rowbase = blockIdx.y * 128;
    int colbase = blockIdx.x * 128;
    float acc[8][8];
#pragma unroll
    for (int i = 0; i < 8; ++i)
#pragma unroll
        for (int j = 0; j < 8; ++j) acc[i][j] = 0.f;

    for (int k0 = 0; k0 < 64; k0 += 32) {
        __syncthreads();
#pragma unroll
        for (int i = 0; i < 4; ++i) {
            int f = tid + i * 256;
            int r = f >> 3;
            int kq = (f & 7) << 2;
            int grow = rowbase + r;
            float4 av = (grow < M) ? *(const float4*)&A[(size_t)grow * 64 + k0 + kq]
                                   : make_float4(0.f, 0.f, 0.f, 0.f);
            As[kq + 0][r] = av.x; As[kq + 1][r] = av.y; As[kq + 2][r] = av.z; As[kq + 3][r] = av.w;
            int gcol = colbase + r;
            float4 bv = (gcol < N_HEADC) ? *(const float4*)&B[(size_t)gcol * 64 + k0 + kq]
                                         : make_float4(0.f, 0.f, 0.f, 0.f);
            Bs[kq + 0][r] = bv.x; Bs[kq + 1][r] = bv.y; Bs[kq + 2][r] = bv.z; Bs[kq + 3][r] = bv.w;
        }
        __syncthreads();
#pragma unroll
        for (int k = 0; k < 32; ++k) {
            float a[8], b[8];
#pragma unroll
            for (int i = 0; i < 8; ++i) a[i] = As[k][ty + 16 * i];
#pragma unroll
            for (int j = 0; j < 8; ++j) b[j] = Bs[k][tx + 16 * j];
#pragma unroll
            for (int i = 0; i < 8; ++i)
#pragma unroll
                for (int j = 0; j < 8; ++j) acc[i][j] += a[i] * b[j];
        }
    }
#pragma unroll
    for (int i = 0; i < 8; ++i) {
        int r = rowbase + ty + 16 * i;
        if (r < M) {
#pragma unroll
            for (int j = 0; j < 8; ++j) {
                int c = colbase + tx + 16 * j;
                if (c < N_HEADC) C[(size_t)r * N_HEADC + c] = acc[i][j];
            }
        }
    }
}

// ---------------- per-row top-k on materialized scores ----------------
__global__ __launch_bounds__(256) void topk_rows(const float* __restrict__ scores, int nrows, int row0,
                                                 const int* __restrict__ head_idx,
                                                 int* __restrict__ ig_cols, float* __restrict__ ig_vals) {
    int w = (blockIdx.x * blockDim.x + threadIdx.x) >> 6;
    int lane = threadIdx.x & 63;
    if (w >= nrows) return;
    const float* srow = scores + (size_t)w * N_HEADC;
    float v[TOPKC];
    int id[TOPKC];
#pragma unroll
    for (int k = 0; k < TOPKC; ++k) { v[k] = -1e30f; id[k] = -1; }
    for (int it = 0; it < 16; ++it) {
        int f4 = lane + it * 64;
        if (f4 < 1000) {
            float4 s4 = ((const float4*)srow)[f4];
            int cb = f4 * 4;
            float vv[4] = { s4.x, s4.y, s4.z, s4.w };
#pragma unroll
            for (int q = 0; q < 4; ++q) {
                float sc = vv[q];
                if (sc > v[TOPKC - 1]) {
                    float cv = sc; int ci = cb + q;
#pragma unroll
                    for (int k = 0; k < TOPKC; ++k) {
                        if (cv > v[k]) { float t = v[k]; int ti = id[k]; v[k] = cv; id[k] = ci; cv = t; ci = ti; }
                    }
                }
            }
        }
    }
    int ptr = 0;
    float ssum = 0.f;
    float outv = 0.f;
    int outid = -1;
#pragma unroll
    for (int r = 0; r < TOPKC; ++r) {
        float cv = (ptr < TOPKC) ? v[ptr] : -1e30f;
        int ci = (ptr < TOPKC) ? id[ptr] : -1;
        int wl = lane;
#pragma unroll
        for (int m = 1; m < 64; m <<= 1) {
            float ov = __shfl_xor(cv, m, 64);
            int oi = __shfl_xor(ci, m, 64);
            int ol = __shfl_xor(wl, m, 64);
            if (ov > cv || (ov == cv && ol < wl)) { cv = ov; ci = oi; wl = ol; }
        }
        if (wl == lane) ptr++;
        ssum += 1.f / (1.f + expf(-cv));
        if (lane == r) { outv = cv; outid = ci; }
    }
    if (lane < TOPKC) {
        float s = 1.f / (1.f + expf(-outv));
        float wgt = s / (ssum + 1.f);
        int grow = row0 + w;
        ig_vals[grow * TOPKC + lane] = wgt;
        ig_cols[grow * TOPKC + lane] = head_idx[outid];
    }
}

// ---------------- item_enh accumulation ----------------
__global__ __launch_bounds__(256) void ig_spmm_kernel(const int* __restrict__ tail_idx,
                                                      const int* __restrict__ ig_cols,
                                                      const float* __restrict__ ig_vals,
                                                      const float* __restrict__ items,
                                                      float* __restrict__ enh) {
    int e = (blockIdx.x * blockDim.x + threadIdx.x) >> 6;
    int lane = threadIdx.x & 63;
    if (e >= N_TAILC * TOPKC) return;
    int row = tail_idx[e / TOPKC];
    int col = ig_cols[e];
    float w = ig_vals[e];
    atomicAdd(&enh[(size_t)row * 64 + lane], w * items[(size_t)col * 64 + lane]);
}

// ---------------- loss: one wave per sample, per-block partial outputs (NO global atomics) ----------------
__global__ __launch_bounds__(256) void loss_kernel(const float* __restrict__ u0, const float* __restrict__ u1,
                                                   const float* __restrict__ u2, const float* __restrict__ items,
                                                   const float* __restrict__ enh, const float* __restrict__ deg,
                                                   const float* __restrict__ user_emb, const float* __restrict__ item_emb,
                                                   const int* __restrict__ bu, const int* __restrict__ bp,
                                                   const int* __restrict__ bn, float* __restrict__ part) {
    __shared__ float lsum[4], rsum[4];
    int w = (blockIdx.x * blockDim.x + threadIdx.x) >> 6;
    int wv = threadIdx.x >> 6;
    int lane = threadIdx.x & 63;
    int uu = bu[w], pp = bp[w];
    float ue = (u0[uu * 64 + lane] + u1[uu * 64 + lane] + u2[uu * 64 + lane]) * (1.f / 3.f);
    float swp = CONVF / (CONVF + expf(deg[pp] * (1.f / CONVF)));
    float pe = items[pp * 64 + lane] + swp * enh[pp * 64 + lane];
    float ps = ue * pe;
    float ns = 0.f;
    float u0e = user_emb[uu * 64 + lane];
    float p0e = item_emb[pp * 64 + lane];
    float reg = u0e * u0e + p0e * p0e;
#pragma unroll
    for (int k = 0; k < N_NEGC; ++k) {
        int nn = bn[w * N_NEGC + k];
        float swn = CONVF / (CONVF + expf(deg[nn] * (1.f / CONVF)));
        float nv = items[nn * 64 + lane] + swn * enh[nn * 64 + lane];
        ns += ue * nv;
        float n0 = item_emb[nn * 64 + lane];
        reg += n0 * n0;
    }
#pragma unroll
    for (int m = 32; m >= 1; m >>= 1) {
        ps += __shfl_xor(ps, m, 64);
        ns += __shfl_xor(ns, m, 64);
        reg += __shfl_xor(reg, m, 64);
    }
    if (lane == 0) {
        float x = ns * (1.f / N_NEGC) - ps;
        float sp = (x > 0.f) ? (x + log1pf(expf(-x))) : log1pf(expf(x));
        lsum[wv] = sp;
        rsum[wv] = reg;
    }
    __syncthreads();
    if (threadIdx.x == 0) {
        part[blockIdx.x] = lsum[0] + lsum[1] + lsum[2] + lsum[3];
        part[LOSS_BLOCKS + blockIdx.x] = rsum[0] + rsum[1] + rsum[2] + rsum[3];
    }
}

// single-block final reduce: out[0]=loss, out[1]=reg
__global__ __launch_bounds__(256) void loss_reduce(const float* __restrict__ part, float* __restrict__ out) {
    __shared__ float l[256], r[256];
    int tid = threadIdx.x;
    float a = 0.f, b = 0.f;
    for (int i = tid; i < LOSS_BLOCKS; i += 256) {
        a += part[i];
        b += part[LOSS_BLOCKS + i];
    }
    l[tid] = a; r[tid] = b;
    __syncthreads();
    for (int off = 128; off >= 1; off >>= 1) {
        if (tid < off) { l[tid] += l[tid + off]; r[tid] += r[tid + off]; }
        __syncthreads();
    }
    if (tid == 0) {
        out[0] = l[0] * (1.f / BATCHC);
        out[1] = 0.5f * r[0] * (1.f / BATCHC);
    }
}

extern "C" void kernel_launch(void* const* d_in, const int* in_sizes, int n_in,
                              void* d_out, int out_size, void* d_ws, size_t ws_size,
                              hipStream_t stream) {
    const float* user_emb = (const float*)d_in[0];
    const float* item_emb = (const float*)d_in[1];
    const float* w0 = (const float*)d_in[2];
    const float* b0 = (const float*)d_in[3];
    const float* w2 = (const float*)d_in[4];
    const float* b2 = (const float*)d_in[5];
    const float* a_vals = (const float*)d_in[6];
    const float* s_vals = (const float*)d_in[7];
    const float* item_degree = (const float*)d_in[8];
    const int* a_rows = (const int*)d_in[9];
    const int* a_cols = (const int*)d_in[10];
    const int* s_rows = (const int*)d_in[11];
    const int* s_cols = (const int*)d_in[12];
    const int* tail_idx = (const int*)d_in[13];
    const int* head_idx = (const int*)d_in[14];
    const int* batch_user = (const int*)d_in[15];
    const int* batch_pos = (const int*)d_in[16];
    const int* batch_neg = (const int*)d_in[17];
    float* out = (float*)d_out;

    // ---- workspace carve ----
    char* p = (char*)d_ws;
    auto carve = [&](size_t bytes) -> void* {
        void* r = (void*)p;
        p += (bytes + 255) & ~size_t(255);
        return r;
    };
    float* embA = (float*)carve((size_t)N_TOTALC * 64 * 4);
    float* embB = (float*)carve((size_t)N_TOTALC * 64 * 4);
    float* u1 = (float*)carve((size_t)N_USERC * 64 * 4);
    float* u2 = (float*)carve((size_t)N_USERC * 64 * 4);
    float* enh = (float*)carve((size_t)N_ITEMC * 64 * 4);
    float* tail_e = (float*)carve((size_t)N_TAILC * 64 * 4);
    float* top_e = (float*)carve((size_t)N_HEADC * 64 * 4);
    int2* aSort = (int2*)carve((size_t)NNZ_AC * 8);       // final row-grouped entries
    int2* sSort = (int2*)carve((size_t)NNZ_SC * 8);
    int* a_rowptr = (int*)carve((size_t)(N_TOTALC + 1) * 4);
    int* s_rowptr = (int*)carve((size_t)(N_USERC + 1) * 4);
    int* aCnt = (int*)carve((size_t)NB_A * 4);
    int* sCnt = (int*)carve((size_t)NB_S * 4);
    int* aCur = (int*)carve((size_t)NB_A * 4);
    int* sCur = (int*)carve((size_t)NB_S * 4);
    int* ig_cols_buf = (int*)carve((size_t)N_TAILC * TOPKC * 4);
    float* ig_vals_buf = (float*)carve((size_t)N_TAILC * TOPKC * 4);
    float* Mrm = (float*)carve(64 * 64 * 4);
    float* cvec = (float*)carve(64 * 4);
    float* loss_part = (float*)carve((size_t)LOSS_BLOCKS * 2 * 4);
    float* scores = (float*)carve((size_t)CHUNK_ROWS * N_HEADC * 4);   // 40MB
    // raw (bucket-ordered) pack buffers alias the scores region: dead before score phase
    int2* aPackRaw = (int2*)scores;
    int2* sPackRaw = aPackRaw + NNZ_AC;   // 16MB + 8MB = 24MB < 40MB

    // ---- bucketed CSR build (A + S) ----
    hipMemsetAsync(aCnt, 0, (size_t)NB_A * 4, stream);
    hipMemsetAsync(sCnt, 0, (size_t)NB_S * 4, stream);
    hist_bucket<<<PBLK_A + PBLK_S, 256, 0, stream>>>(a_rows, s_rows, aCnt, sCnt);
    scan_buckets<<<2, 256, 0, stream>>>(aCnt, sCnt, aCur, sCur);
    partition_fused<<<PBLK_A + PBLK_S, 256, 0, stream>>>(a_vals, a_rows, a_cols,
                                                         s_vals, s_rows, s_cols,
                                                         aCur, sCur, aPackRaw, sPackRaw);
    // aCur/sCur now hold bucket END offsets
    csr_finalize<<<NB_A + NB_S, 256, 0, stream>>>(aCur, sCur, aPackRaw, sPackRaw,
                                                  aSort, sSort, a_rowptr, s_rowptr);

    // ---- collapsed encoder (tail + head fused) ----
    mc_kernel<<<17, 256, 0, stream>>>(w0, b0, w2, b2, Mrm, cvec);
    enc2_fused<<<(N_TAILC + N_HEADC + 3) / 4, 256, 0, stream>>>(item_emb, tail_idx, head_idx, Mrm, cvec, tail_e, top_e);

    // ---- chunked scores GEMM + top-k (aPackRaw dead from here) ----
    for (int row0 = 0; row0 < N_TAILC; row0 += CHUNK_ROWS) {
        int m = N_TAILC - row0;
        if (m > CHUNK_ROWS) m = CHUNK_ROWS;
        int rb = (m + 127) / 128;
        score_gemm<<<dim3((N_HEADC + 127) / 128, rb), 256, 0, stream>>>(tail_e + (size_t)row0 * 64, top_e, scores, m);
        topk_rows<<<(m + 3) / 4, 256, 0, stream>>>(scores, m, row0, head_idx, ig_cols_buf, ig_vals_buf);
    }

    // ---- 3 A-layers (first reads inputs directly, then ping-pong) ----
    {
        int blocks = (N_TOTALC + 3) / 4;
        spmm_csr_concat<<<blocks, 256, 0, stream>>>(a_rowptr, aSort, user_emb, item_emb, embB, N_TOTALC);
        spmm_csr<<<blocks, 256, 0, stream>>>(a_rowptr, aSort, embB, embA, N_TOTALC);
        spmm_csr<<<blocks, 256, 0, stream>>>(a_rowptr, aSort, embA, embB, N_TOTALC);
    }
    const float* u0 = embB;
    const float* items = embB + (size_t)N_USERC * 64;

    // ---- 2 S-layers on users ----
    {
        int blocks = (N_USERC + 3) / 4;
        spmm_csr<<<blocks, 256, 0, stream>>>(s_rowptr, sSort, u0, u1, N_USERC);
        spmm_csr<<<blocks, 256, 0, stream>>>(s_rowptr, sSort, u1, u2, N_USERC);
    }

    // ---- item enhancement ----
    hipMemsetAsync(enh, 0, (size_t)N_ITEMC * 64 * 4, stream);
    ig_spmm_kernel<<<(N_TAILC * TOPKC) / 4, 256, 0, stream>>>(tail_idx, ig_cols_buf, ig_vals_buf, items, enh);

    // ---- loss + reg: per-block partials then single-block reduce ----
    loss_kernel<<<LOSS_BLOCKS, 256, 0, stream>>>(u0, u1, u2, items, enh, item_degree,
                                                 user_emb, item_emb, batch_user, batch_pos, batch_neg, loss_part);
    loss_reduce<<<1, 256, 0, stream>>>(loss_part, out);
}

// Round 8
// 1069.327 us; speedup vs baseline: 3.5930x; 1.0444x over previous
//
#include <hip/hip_runtime.h>
#include <hip/hip_bf16.h>

#define N_USERC 100000
#define N_ITEMC 50000
#define N_TOTALC 150000
#define DC 64
#define NNZ_AC 2000000
#define NNZ_SC 1000000
#define N_TAILC 10000
#define N_HEADC 4000
#define TOPKC 10
#define BATCHC 4096
#define N_NEGC 4
#define CONVF 40.0f
#define CHUNK_ROWS 2500

#define RPB 128                                  // rows per bucket
#define NB_A ((N_TOTALC + RPB - 1) / RPB)        // 1172
#define NB_S ((N_USERC + RPB - 1) / RPB)         // 782
#define IPB 6144                                 // items per partition block
#define PBLK_A ((NNZ_AC + IPB - 1) / IPB)        // 326
#define PBLK_S ((NNZ_SC + IPB - 1) / IPB)        // 163

#define LOSS_BLOCKS (BATCHC / 4)                 // 1024

__device__ __forceinline__ unsigned short F2B(float f) {
    __hip_bfloat16 b = __float2bfloat16(f);
    return *(unsigned short*)&b;
}
__device__ __forceinline__ float B2F(unsigned short h) {
    return __uint_as_float(((unsigned)h) << 16);
}

// ---------------- bucket histogram: LDS pre-aggregation, then flush ----------------
__global__ __launch_bounds__(256) void hist_bucket(const int* __restrict__ a_rows, const int* __restrict__ s_rows,
                                                   int* __restrict__ aCnt, int* __restrict__ sCnt) {
    __shared__ int h[NB_A];
    int blk = blockIdx.x;
    const int* rows; int n; int nb; int* gout; int base;
    if (blk < PBLK_A) { rows = a_rows; n = NNZ_AC; nb = NB_A; gout = aCnt; base = blk * IPB; }
    else { rows = s_rows; n = NNZ_SC; nb = NB_S; gout = sCnt; base = (blk - PBLK_A) * IPB; }
    for (int i = threadIdx.x; i < nb; i += 256) h[i] = 0;
    __syncthreads();
    for (int k = 0; k < IPB; k += 256) {
        int idx = base + k + threadIdx.x;
        if (idx < n) atomicAdd(&h[rows[idx] >> 7], 1);
    }
    __syncthreads();
    for (int i = threadIdx.x; i < nb; i += 256) {
        int c = h[i];
        if (c) atomicAdd(&gout[i], c);
    }
}

// ---------------- exclusive scan of bucket counts -> cursor bases (2 blocks) ----------------
__global__ __launch_bounds__(256) void scan_buckets(const int* __restrict__ aCnt, const int* __restrict__ sCnt,
                                                    int* __restrict__ aCur, int* __restrict__ sCur) {
    __shared__ int lds[256];
    const int* cnt; int* cur; int nb;
    if (blockIdx.x == 0) { cnt = aCnt; cur = aCur; nb = NB_A; }
    else { cnt = sCnt; cur = sCur; nb = NB_S; }
    int tid = threadIdx.x;
    int v[5]; int s = 0;
#pragma unroll
    for (int k = 0; k < 5; ++k) {
        int i = tid * 5 + k;
        v[k] = s;
        s += (i < nb) ? cnt[i] : 0;
    }
    lds[tid] = s;
    __syncthreads();
    for (int off = 1; off < 256; off <<= 1) {
        int t = (tid >= off) ? lds[tid - off] : 0;
        __syncthreads();
        lds[tid] += t;
        __syncthreads();
    }
    int base = (tid > 0) ? lds[tid - 1] : 0;
#pragma unroll
    for (int k = 0; k < 5; ++k) {
        int i = tid * 5 + k;
        if (i < nb) cur[i] = base + v[k];
    }
}

// ---------------- partition: block-local counting sort into bucket regions ----------------
// pack.y = col | (row_in_bucket << 18)   (col < 262144, rl < 128)
__global__ __launch_bounds__(256) void partition_fused(
    const float* __restrict__ a_vals, const int* __restrict__ a_rows, const int* __restrict__ a_cols,
    const float* __restrict__ s_vals, const int* __restrict__ s_rows, const int* __restrict__ s_cols,
    int* __restrict__ aCur, int* __restrict__ sCur,
    int2* __restrict__ aPack, int2* __restrict__ sPack) {
    __shared__ int h[NB_A];
    __shared__ int cur[NB_A];
    int blk = blockIdx.x;
    const float* vals; const int* rows; const int* cols; int n; int nb; int* gcur; int2* pack; int base;
    if (blk < PBLK_A) { vals = a_vals; rows = a_rows; cols = a_cols; n = NNZ_AC; nb = NB_A; gcur = aCur; pack = aPack; base = blk * IPB; }
    else { vals = s_vals; rows = s_rows; cols = s_cols; n = NNZ_SC; nb = NB_S; gcur = sCur; pack = sPack; base = (blk - PBLK_A) * IPB; }
    int tid = threadIdx.x;
    for (int i = tid; i < nb; i += 256) h[i] = 0;
    __syncthreads();
    for (int k = 0; k < IPB; k += 256) {
        int idx = base + k + tid;
        if (idx < n) atomicAdd(&h[rows[idx] >> 7], 1);
    }
    __syncthreads();
    for (int i = tid; i < nb; i += 256) {
        int c = h[i];
        cur[i] = c ? atomicAdd(&gcur[i], c) : 0;
    }
    __syncthreads();
    for (int k = 0; k < IPB; k += 256) {
        int idx = base + k + tid;
        if (idx < n) {
            int r = rows[idx];
            int b = r >> 7;
            int pos = atomicAdd(&cur[b], 1);
            pack[pos] = make_int2(__float_as_int(vals[idx]), cols[idx] | ((r & 127) << 18));
        }
    }
}

// ---------------- finalize: per-bucket counting sort -> row-grouped entries + rowptr ----------------
__global__ __launch_bounds__(256) void csr_finalize(const int* __restrict__ aEnd, const int* __restrict__ sEnd,
                                                    const int2* __restrict__ aRaw, const int2* __restrict__ sRaw,
                                                    int2* __restrict__ aOut, int2* __restrict__ sOut,
                                                    int* __restrict__ aRp, int* __restrict__ sRp) {
    __shared__ int cnt_[RPB];
    __shared__ int scn[RPB];
    __shared__ int cursor[RPB];
    int blk = blockIdx.x;
    const int* ends; const int2* raw; int2* outp; int* rp; int nb; int nrows; int b;
    if (blk < NB_A) { ends = aEnd; raw = aRaw; outp = aOut; rp = aRp; nb = NB_A; nrows = N_TOTALC; b = blk; }
    else { ends = sEnd; raw = sRaw; outp = sOut; rp = sRp; nb = NB_S; nrows = N_USERC; b = blk - NB_A; }
    int s = b ? ends[b - 1] : 0;
    int e = ends[b];
    int n = e - s;
    int tid = threadIdx.x;
    if (tid < RPB) cnt_[tid] = 0;
    __syncthreads();
    for (int i = tid; i < n; i += 256)
        atomicAdd(&cnt_[(raw[s + i].y >> 18) & 127], 1);
    __syncthreads();
    if (tid < RPB) scn[tid] = cnt_[tid];
    __syncthreads();
    for (int off = 1; off < RPB; off <<= 1) {
        int t = (tid < RPB && tid >= off) ? scn[tid - off] : 0;
        __syncthreads();
        if (tid < RPB) scn[tid] += t;
        __syncthreads();
    }
    if (tid < RPB) {
        int ex = scn[tid] - cnt_[tid];      // exclusive
        cursor[tid] = ex;
        int row = (b << 7) + tid;
        if (row < nrows) rp[row] = s + ex;
    }
    if (b == nb - 1 && tid == 0) rp[nrows] = e;
    __syncthreads();
    for (int i = tid; i < n; i += 256) {
        int2 en = raw[s + i];
        int r = (en.y >> 18) & 127;
        int pos = atomicAdd(&cursor[r], 1);
        outp[s + pos] = make_int2(en.x, en.y & 0x3FFFF);
    }
}

// ---------------- concat + fp32->bf16 convert: embH = bf16(concat(user_emb, item_emb)) ----------------
__global__ __launch_bounds__(256) void to_bf16_concat(const float* __restrict__ xu, const float* __restrict__ xi,
                                                      unsigned short* __restrict__ out) {
    size_t i4 = (size_t)blockIdx.x * 256 + threadIdx.x;
    const size_t NU4 = (size_t)N_USERC * 16;     // float4 count in user part
    const size_t NT4 = (size_t)N_TOTALC * 16;
    if (i4 >= NT4) return;
    float4 v = (i4 < NU4) ? ((const float4*)xu)[i4] : ((const float4*)xi)[i4 - NU4];
    ushort4 h;
    h.x = F2B(v.x); h.y = F2B(v.y); h.z = F2B(v.z); h.w = F2B(v.w);
    ((ushort4*)out)[i4] = h;
}

// ---------------- CSR SpMM, bf16 gather operand: one wave per row, 8-deep pipeline ----------------
// writes fp32 y and bf16 mirror yh
__global__ __launch_bounds__(256) void spmm_h(const int* __restrict__ rowptr,
                                              const int2* __restrict__ pack,
                                              const unsigned short* __restrict__ xh,
                                              float* __restrict__ y,
                                              unsigned short* __restrict__ yh, int nrows) {
    int w = (blockIdx.x * blockDim.x + threadIdx.x) >> 6;
    int lane = threadIdx.x & 63;
    if (w >= nrows) return;
    int s = rowptr[w], e = rowptr[w + 1];
    float a0 = 0.f, a1 = 0.f, a2 = 0.f, a3 = 0.f;
    int j = s;
    for (; j + 8 <= e; j += 8) {
        int2 e0 = pack[j], e1 = pack[j + 1], e2 = pack[j + 2], e3 = pack[j + 3];
        int2 e4 = pack[j + 4], e5 = pack[j + 5], e6 = pack[j + 6], e7 = pack[j + 7];
        float g0 = B2F(xh[(size_t)e0.y * 64 + lane]);
        float g1 = B2F(xh[(size_t)e1.y * 64 + lane]);
        float g2 = B2F(xh[(size_t)e2.y * 64 + lane]);
        float g3 = B2F(xh[(size_t)e3.y * 64 + lane]);
        float g4 = B2F(xh[(size_t)e4.y * 64 + lane]);
        float g5 = B2F(xh[(size_t)e5.y * 64 + lane]);
        float g6 = B2F(xh[(size_t)e6.y * 64 + lane]);
        float g7 = B2F(xh[(size_t)e7.y * 64 + lane]);
        a0 += __int_as_float(e0.x) * g0;
        a1 += __int_as_float(e1.x) * g1;
        a2 += __int_as_float(e2.x) * g2;
        a3 += __int_as_float(e3.x) * g3;
        a0 += __int_as_float(e4.x) * g4;
        a1 += __int_as_float(e5.x) * g5;
        a2 += __int_as_float(e6.x) * g6;
        a3 += __int_as_float(e7.x) * g7;
    }
    if (j + 4 <= e) {
        int2 e0 = pack[j], e1 = pack[j + 1], e2 = pack[j + 2], e3 = pack[j + 3];
        float g0 = B2F(xh[(size_t)e0.y * 64 + lane]);
        float g1 = B2F(xh[(size_t)e1.y * 64 + lane]);
        float g2 = B2F(xh[(size_t)e2.y * 64 + lane]);
        float g3 = B2F(xh[(size_t)e3.y * 64 + lane]);
        a0 += __int_as_float(e0.x) * g0;
        a1 += __int_as_float(e1.x) * g1;
        a2 += __int_as_float(e2.x) * g2;
        a3 += __int_as_float(e3.x) * g3;
        j += 4;
    }
    for (; j < e; ++j) {
        int2 e0 = pack[j];
        a0 += __int_as_float(e0.x) * B2F(xh[(size_t)e0.y * 64 + lane]);
    }
    float r = (a0 + a1) + (a2 + a3);
    y[(size_t)w * 64 + lane] = r;
    yh[(size_t)w * 64 + lane] = F2B(r);
}

// ---------------- collapsed encoder ----------------
__global__ __launch_bounds__(256) void mc_kernel(const float* __restrict__ w0, const float* __restrict__ b0,
                                                 const float* __restrict__ w2, const float* __restrict__ b2,
                                                 float* __restrict__ Mrm, float* __restrict__ cvec) {
    int idx = blockIdx.x * 256 + threadIdx.x;
    if (idx < 4096) {
        int j = idx >> 6, d = idx & 63;
        float acc = 0.f;
        for (int k = 0; k < 256; ++k) acc += w2[j * 256 + k] * w0[k * 64 + d];
        Mrm[idx] = acc;
    } else if (idx < 4160) {
        int i = idx - 4096;
        float acc = b2[i];
        for (int k = 0; k < 256; ++k) acc += w2[i * 256 + k] * b0[k];
        cvec[i] = acc;
    }
}

// enc(f) = f @ Mrm^T + cvec ; one wave per row; fused tail+head
__global__ __launch_bounds__(256) void enc2_fused(const float* __restrict__ emb,
                                                  const int* __restrict__ tail_idx, const int* __restrict__ head_idx,
                                                  const float* __restrict__ Mrm, const float* __restrict__ cvec,
                                                  float* __restrict__ tail_e, float* __restrict__ top_e) {
    __shared__ float fsh[4][64];
    int wv = threadIdx.x >> 6, lane = threadIdx.x & 63;
    int r = blockIdx.x * 4 + wv;
    int item;
    float* outp;
    if (r < N_TAILC) { item = tail_idx[r]; outp = tail_e + (size_t)r * 64; }
    else if (r < N_TAILC + N_HEADC) { item = head_idx[r - N_TAILC]; outp = top_e + (size_t)(r - N_TAILC) * 64; }
    else { item = -1; outp = nullptr; }
    if (item >= 0) fsh[wv][lane] = emb[(size_t)item * 64 + lane];
    __syncthreads();
    if (item < 0) return;
    float acc = cvec[lane];
#pragma unroll
    for (int d4 = 0; d4 < 64; d4 += 4) {
        float4 m4 = *(const float4*)&Mrm[lane * 64 + d4];
        float4 f4 = *(const float4*)&fsh[wv][d4];
        acc += m4.x * f4.x + m4.y * f4.y + m4.z * f4.z + m4.w * f4.w;
    }
    outp[lane] = acc;
}

// ---------------- score GEMM: C[m x 4000] = A[m x 64] @ B[4000 x 64]^T ----------------
__global__ __launch_bounds__(256) void score_gemm(const float* __restrict__ A,
                                                  const float* __restrict__ B,
                                                  float* __restrict__ C, int M) {
    __shared__ float As[32][132];
    __shared__ float Bs[32][132];
    int tid = threadIdx.x;
    int tx = tid & 15, ty = tid >> 4;
    int rowbase = blockIdx.y * 128;
    int colbase = blockIdx.x * 128;
    float acc[8][8];
#pragma unroll
    for (int i = 0; i < 8; ++i)
#pragma unroll
        for (int j = 0; j < 8; ++j) acc[i][j] = 0.f;

    for (int k0 = 0; k0 < 64; k0 += 32) {
        __syncthreads();
#pragma unroll
        for (int i = 0; i < 4; ++i) {
            int f = tid + i * 256;
            int r = f >> 3;
            int kq = (f & 7) << 2;
            int grow = rowbase + r;
            float4 av = (grow < M) ? *(const float4*)&A[(size_t)grow * 64 + k0 + kq]
                                   : make_float4(0.f, 0.f, 0.f, 0.f);
            As[kq + 0][r] = av.x; As[kq + 1][r] = av.y; As[kq + 2][r] = av.z; As[kq + 3][r] = av.w;
            int gcol = colbase + r;
            float4 bv = (gcol < N_HEADC) ? *(const float4*)&B[(size_t)gcol * 64 + k0 + kq]
                                         : make_float4(0.f, 0.f, 0.f, 0.f);
            Bs[kq + 0][r] = bv.x; Bs[kq + 1][r] = bv.y; Bs[kq + 2][r] = bv.z; Bs[kq + 3][r] = bv.w;
        }
        __syncthreads();
#pragma unroll
        for (int k = 0; k < 32; ++k) {
            float a[8], b[8];
#pragma unroll
            for (int i = 0; i < 8; ++i) a[i] = As[k][ty + 16 * i];
#pragma unroll
            for (int j = 0; j < 8; ++j) b[j] = Bs[k][tx + 16 * j];
#pragma unroll
            for (int i = 0; i < 8; ++i)
#pragma unroll
                for (int j = 0; j < 8; ++j) acc[i][j] += a[i] * b[j];
        }
    }
#pragma unroll
    for (int i = 0; i < 8; ++i) {
        int r = rowbase + ty + 16 * i;
        if (r < M) {
#pragma unroll
            for (int j = 0; j < 8; ++j) {
                int c = colbase + tx + 16 * j;
                if (c < N_HEADC) C[(size_t)r * N_HEADC + c] = acc[i][j];
            }
        }
    }
}

// ---------------- per-row top-k on materialized scores ----------------
__global__ __launch_bounds__(256) void topk_rows(const float* __restrict__ scores, int nrows, int row0,
                                                 const int* __restrict__ head_idx,
                                                 int* __restrict__ ig_cols, float* __restrict__ ig_vals) {
    int w = (blockIdx.x * blockDim.x + threadIdx.x) >> 6;
    int lane = threadIdx.x & 63;
    if (w >= nrows) return;
    const float* srow = scores + (size_t)w * N_HEADC;
    float v[TOPKC];
    int id[TOPKC];
#pragma unroll
    for (int k = 0; k < TOPKC; ++k) { v[k] = -1e30f; id[k] = -1; }
    for (int it = 0; it < 16; ++it) {
        int f4 = lane + it * 64;
        if (f4 < 1000) {
            float4 s4 = ((const float4*)srow)[f4];
            int cb = f4 * 4;
            float vv[4] = { s4.x, s4.y, s4.z, s4.w };
#pragma unroll
            for (int q = 0; q < 4; ++q) {
                float sc = vv[q];
                if (sc > v[TOPKC - 1]) {
                    float cv = sc; int ci = cb + q;
#pragma unroll
                    for (int k = 0; k < TOPKC; ++k) {
                        if (cv > v[k]) { float t = v[k]; int ti = id[k]; v[k] = cv; id[k] = ci; cv = t; ci = ti; }
                    }
                }
            }
        }
    }
    int ptr = 0;
    float ssum = 0.f;
    float outv = 0.f;
    int outid = -1;
#pragma unroll
    for (int r = 0; r < TOPKC; ++r) {
        float cv = (ptr < TOPKC) ? v[ptr] : -1e30f;
        int ci = (ptr < TOPKC) ? id[ptr] : -1;
        int wl = lane;
#pragma unroll
        for (int m = 1; m < 64; m <<= 1) {
            float ov = __shfl_xor(cv, m, 64);
            int oi = __shfl_xor(ci, m, 64);
            int ol = __shfl_xor(wl, m, 64);
            if (ov > cv || (ov == cv && ol < wl)) { cv = ov; ci = oi; wl = ol; }
        }
        if (wl == lane) ptr++;
        ssum += 1.f / (1.f + expf(-cv));
        if (lane == r) { outv = cv; outid = ci; }
    }
    if (lane < TOPKC) {
        float s = 1.f / (1.f + expf(-outv));
        float wgt = s / (ssum + 1.f);
        int grow = row0 + w;
        ig_vals[grow * TOPKC + lane] = wgt;
        ig_cols[grow * TOPKC + lane] = head_idx[outid];
    }
}

// ---------------- item_enh accumulation ----------------
__global__ __launch_bounds__(256) void ig_spmm_kernel(const int* __restrict__ tail_idx,
                                                      const int* __restrict__ ig_cols,
                                                      const float* __restrict__ ig_vals,
                                                      const float* __restrict__ items,
                                                      float* __restrict__ enh) {
    int e = (blockIdx.x * blockDim.x + threadIdx.x) >> 6;
    int lane = threadIdx.x & 63;
    if (e >= N_TAILC * TOPKC) return;
    int row = tail_idx[e / TOPKC];
    int col = ig_cols[e];
    float w = ig_vals[e];
    atomicAdd(&enh[(size_t)row * 64 + lane], w * items[(size_t)col * 64 + lane]);
}

// ---------------- loss: one wave per sample, per-block partial outputs (NO global atomics) ----------------
__global__ __launch_bounds__(256) void loss_kernel(const float* __restrict__ u0, const float* __restrict__ u1,
                                                   const float* __restrict__ u2, const float* __restrict__ items,
                                                   const float* __restrict__ enh, const float* __restrict__ deg,
                                                   const float* __restrict__ user_emb, const float* __restrict__ item_emb,
                                                   const int* __restrict__ bu, const int* __restrict__ bp,
                                                   const int* __restrict__ bn, float* __restrict__ part) {
    __shared__ float lsum[4], rsum[4];
    int w = (blockIdx.x * blockDim.x + threadIdx.x) >> 6;
    int wv = threadIdx.x >> 6;
    int lane = threadIdx.x & 63;
    int uu = bu[w], pp = bp[w];
    float ue = (u0[uu * 64 + lane] + u1[uu * 64 + lane] + u2[uu * 64 + lane]) * (1.f / 3.f);
    float swp = CONVF / (CONVF + expf(deg[pp] * (1.f / CONVF)));
    float pe = items[pp * 64 + lane] + swp * enh[pp * 64 + lane];
    float ps = ue * pe;
    float ns = 0.f;
    float u0e = user_emb[uu * 64 + lane];
    float p0e = item_emb[pp * 64 + lane];
    float reg = u0e * u0e + p0e * p0e;
#pragma unroll
    for (int k = 0; k < N_NEGC; ++k) {
        int nn = bn[w * N_NEGC + k];
        float swn = CONVF / (CONVF + expf(deg[nn] * (1.f / CONVF)));
        float nv = items[nn * 64 + lane] + swn * enh[nn * 64 + lane];
        ns += ue * nv;
        float n0 = item_emb[nn * 64 + lane];
        reg += n0 * n0;
    }
#pragma unroll
    for (int m = 32; m >= 1; m >>= 1) {
        ps += __shfl_xor(ps, m, 64);
        ns += __shfl_xor(ns, m, 64);
        reg += __shfl_xor(reg, m, 64);
    }
    if (lane == 0) {
        float x = ns * (1.f / N_NEGC) - ps;
        float sp = (x > 0.f) ? (x + log1pf(expf(-x))) : log1pf(expf(x));
        lsum[wv] = sp;
        rsum[wv] = reg;
    }
    __syncthreads();
    if (threadIdx.x == 0) {
        part[blockIdx.x] = lsum[0] + lsum[1] + lsum[2] + lsum[3];
        part[LOSS_BLOCKS + blockIdx.x] = rsum[0] + rsum[1] + rsum[2] + rsum[3];
    }
}

// single-block final reduce: out[0]=loss, out[1]=reg
__global__ __launch_bounds__(256) void loss_reduce(const float* __restrict__ part, float* __restrict__ out) {
    __shared__ float l[256], r[256];
    int tid = threadIdx.x;
    float a = 0.f, b = 0.f;
    for (int i = tid; i < LOSS_BLOCKS; i += 256) {
        a += part[i];
        b += part[LOSS_BLOCKS + i];
    }
    l[tid] = a; r[tid] = b;
    __syncthreads();
    for (int off = 128; off >= 1; off >>= 1) {
        if (tid < off) { l[tid] += l[tid + off]; r[tid] += r[tid + off]; }
        __syncthreads();
    }
    if (tid == 0) {
        out[0] = l[0] * (1.f / BATCHC);
        out[1] = 0.5f * r[0] * (1.f / BATCHC);
    }
}

extern "C" void kernel_launch(void* const* d_in, const int* in_sizes, int n_in,
                              void* d_out, int out_size, void* d_ws, size_t ws_size,
                              hipStream_t stream) {
    const float* user_emb = (const float*)d_in[0];
    const float* item_emb = (const float*)d_in[1];
    const float* w0 = (const float*)d_in[2];
    const float* b0 = (const float*)d_in[3];
    const float* w2 = (const float*)d_in[4];
    const float* b2 = (const float*)d_in[5];
    const float* a_vals = (const float*)d_in[6];
    const float* s_vals = (const float*)d_in[7];
    const float* item_degree = (const float*)d_in[8];
    const int* a_rows = (const int*)d_in[9];
    const int* a_cols = (const int*)d_in[10];
    const int* s_rows = (const int*)d_in[11];
    const int* s_cols = (const int*)d_in[12];
    const int* tail_idx = (const int*)d_in[13];
    const int* head_idx = (const int*)d_in[14];
    const int* batch_user = (const int*)d_in[15];
    const int* batch_pos = (const int*)d_in[16];
    const int* batch_neg = (const int*)d_in[17];
    float* out = (float*)d_out;

    // ---- workspace carve ----
    char* p = (char*)d_ws;
    auto carve = [&](size_t bytes) -> void* {
        void* r = (void*)p;
        p += (bytes + 255) & ~size_t(255);
        return r;
    };
    float* embA = (float*)carve((size_t)N_TOTALC * 64 * 4);
    float* embB = (float*)carve((size_t)N_TOTALC * 64 * 4);
    float* u1 = (float*)carve((size_t)N_USERC * 64 * 4);
    float* u2 = (float*)carve((size_t)N_USERC * 64 * 4);
    float* enh = (float*)carve((size_t)N_ITEMC * 64 * 4);
    float* tail_e = (float*)carve((size_t)N_TAILC * 64 * 4);
    float* top_e = (float*)carve((size_t)N_HEADC * 64 * 4);
    int2* aSort = (int2*)carve((size_t)NNZ_AC * 8);       // final row-grouped entries
    int2* sSort = (int2*)carve((size_t)NNZ_SC * 8);
    int* a_rowptr = (int*)carve((size_t)(N_TOTALC + 1) * 4);
    int* s_rowptr = (int*)carve((size_t)(N_USERC + 1) * 4);
    int* aCnt = (int*)carve((size_t)NB_A * 4);
    int* sCnt = (int*)carve((size_t)NB_S * 4);
    int* aCur = (int*)carve((size_t)NB_A * 4);
    int* sCur = (int*)carve((size_t)NB_S * 4);
    int* ig_cols_buf = (int*)carve((size_t)N_TAILC * TOPKC * 4);
    float* ig_vals_buf = (float*)carve((size_t)N_TAILC * TOPKC * 4);
    float* Mrm = (float*)carve(64 * 64 * 4);
    float* cvec = (float*)carve(64 * 4);
    float* loss_part = (float*)carve((size_t)LOSS_BLOCKS * 2 * 4);
    unsigned short* embH0 = (unsigned short*)carve((size_t)N_TOTALC * 64 * 2);   // bf16 concat input
    unsigned short* embH1 = (unsigned short*)carve((size_t)N_TOTALC * 64 * 2);   // bf16 mirrors (ping)
    float* scores = (float*)carve((size_t)CHUNK_ROWS * N_HEADC * 4);   // 40MB
    // aliases within the scores region (dead across phases):
    int2* aPackRaw = (int2*)scores;                          // build phase only
    int2* sPackRaw = aPackRaw + NNZ_AC;                      // 16+8=24MB < 40MB
    unsigned short* embH2 = (unsigned short*)scores;         // L2 out / L3 in (19.2MB), after score phase
    unsigned short* uh1 = embH0;                             // S1 bf16 out (embH0 dead after L1)
    unsigned short* uh2 = embH1;                             // S2 bf16 out (embH1 dead after S1... see order)

    // ---- bucketed CSR build (A + S) ----
    hipMemsetAsync(aCnt, 0, (size_t)NB_A * 4, stream);
    hipMemsetAsync(sCnt, 0, (size_t)NB_S * 4, stream);
    hist_bucket<<<PBLK_A + PBLK_S, 256, 0, stream>>>(a_rows, s_rows, aCnt, sCnt);
    scan_buckets<<<2, 256, 0, stream>>>(aCnt, sCnt, aCur, sCur);
    partition_fused<<<PBLK_A + PBLK_S, 256, 0, stream>>>(a_vals, a_rows, a_cols,
                                                         s_vals, s_rows, s_cols,
                                                         aCur, sCur, aPackRaw, sPackRaw);
    // aCur/sCur now hold bucket END offsets
    csr_finalize<<<NB_A + NB_S, 256, 0, stream>>>(aCur, sCur, aPackRaw, sPackRaw,
                                                  aSort, sSort, a_rowptr, s_rowptr);

    // ---- collapsed encoder (tail + head fused) ----
    mc_kernel<<<17, 256, 0, stream>>>(w0, b0, w2, b2, Mrm, cvec);
    enc2_fused<<<(N_TAILC + N_HEADC + 3) / 4, 256, 0, stream>>>(item_emb, tail_idx, head_idx, Mrm, cvec, tail_e, top_e);

    // ---- bf16 concat input table ----
    to_bf16_concat<<<((N_TOTALC * 16) + 255) / 256, 256, 0, stream>>>(user_emb, item_emb, embH0);

    // ---- chunked scores GEMM + top-k (aPackRaw dead from here) ----
    for (int row0 = 0; row0 < N_TAILC; row0 += CHUNK_ROWS) {
        int m = N_TAILC - row0;
        if (m > CHUNK_ROWS) m = CHUNK_ROWS;
        int rb = (m + 127) / 128;
        score_gemm<<<dim3((N_HEADC + 127) / 128, rb), 256, 0, stream>>>(tail_e + (size_t)row0 * 64, top_e, scores, m);
        topk_rows<<<(m + 3) / 4, 256, 0, stream>>>(scores, m, row0, head_idx, ig_cols_buf, ig_vals_buf);
    }

    // ---- 3 A-layers, bf16 gathers (scores region dead from here -> embH2 alias live) ----
    {
        int blocks = (N_TOTALC + 3) / 4;
        spmm_h<<<blocks, 256, 0, stream>>>(a_rowptr, aSort, embH0, embA, embH1, N_TOTALC);  // L1
        spmm_h<<<blocks, 256, 0, stream>>>(a_rowptr, aSort, embH1, embA, embH2, N_TOTALC);  // L2 (fp32 out dead)
        spmm_h<<<blocks, 256, 0, stream>>>(a_rowptr, aSort, embH2, embB, embH1, N_TOTALC);  // L3 -> final fp32 in embB
    }
    const float* u0 = embB;
    const float* items = embB + (size_t)N_USERC * 64;

    // ---- 2 S-layers on users, bf16 gathers ----
    {
        int blocks = (N_USERC + 3) / 4;
        spmm_h<<<blocks, 256, 0, stream>>>(s_rowptr, sSort, embH1, u1, uh1, N_USERC);  // S1 (gathers users rows of L3)
        spmm_h<<<blocks, 256, 0, stream>>>(s_rowptr, sSort, uh1, u2, uh2, N_USERC);    // S2 (bf16 out unused)
    }

    // ---- item enhancement ----
    hipMemsetAsync(enh, 0, (size_t)N_ITEMC * 64 * 4, stream);
    ig_spmm_kernel<<<(N_TAILC * TOPKC) / 4, 256, 0, stream>>>(tail_idx, ig_cols_buf, ig_vals_buf, items, enh);

    // ---- loss + reg: per-block partials then single-block reduce ----
    loss_kernel<<<LOSS_BLOCKS, 256, 0, stream>>>(u0, u1, u2, items, enh, item_degree,
                                                 user_emb, item_emb, batch_user, batch_pos, batch_neg, loss_part);
    loss_reduce<<<1, 256, 0, stream>>>(loss_part, out);
}

// Round 9
// 1068.015 us; speedup vs baseline: 3.5974x; 1.0012x over previous
//
#include <hip/hip_runtime.h>
#include <hip/hip_bf16.h>

#define N_USERC 100000
#define N_ITEMC 50000
#define N_TOTALC 150000
#define DC 64
#define NNZ_AC 2000000
#define NNZ_SC 1000000
#define N_TAILC 10000
#define N_HEADC 4000
#define TOPKC 10
#define BATCHC 4096
#define N_NEGC 4
#define CONVF 40.0f
#define CHUNK_ROWS 2500

#define RPB 128                                  // rows per bucket
#define NB_A ((N_TOTALC + RPB - 1) / RPB)        // 1172
#define NB_S ((N_USERC + RPB - 1) / RPB)         // 782
#define IPB 6144                                 // items per partition block
#define PBLK_A ((NNZ_AC + IPB - 1) / IPB)        // 326
#define PBLK_S ((NNZ_SC + IPB - 1) / IPB)        // 163

#define LOSS_BLOCKS (BATCHC / 4)                 // 1024

__device__ __forceinline__ unsigned short F2B(float f) {
    __hip_bfloat16 b = __float2bfloat16(f);
    return *(unsigned short*)&b;
}
__device__ __forceinline__ float B2F(unsigned short h) {
    return __uint_as_float(((unsigned)h) << 16);
}

// ---------------- bucket histogram: LDS pre-aggregation, then flush ----------------
__global__ __launch_bounds__(256) void hist_bucket(const int* __restrict__ a_rows, const int* __restrict__ s_rows,
                                                   int* __restrict__ aCnt, int* __restrict__ sCnt) {
    __shared__ int h[NB_A];
    int blk = blockIdx.x;
    const int* rows; int n; int nb; int* gout; int base;
    if (blk < PBLK_A) { rows = a_rows; n = NNZ_AC; nb = NB_A; gout = aCnt; base = blk * IPB; }
    else { rows = s_rows; n = NNZ_SC; nb = NB_S; gout = sCnt; base = (blk - PBLK_A) * IPB; }
    for (int i = threadIdx.x; i < nb; i += 256) h[i] = 0;
    __syncthreads();
    for (int k = 0; k < IPB; k += 256) {
        int idx = base + k + threadIdx.x;
        if (idx < n) atomicAdd(&h[rows[idx] >> 7], 1);
    }
    __syncthreads();
    for (int i = threadIdx.x; i < nb; i += 256) {
        int c = h[i];
        if (c) atomicAdd(&gout[i], c);
    }
}

// ---------------- exclusive scan of bucket counts -> cursor bases (2 blocks) ----------------
__global__ __launch_bounds__(256) void scan_buckets(const int* __restrict__ aCnt, const int* __restrict__ sCnt,
                                                    int* __restrict__ aCur, int* __restrict__ sCur) {
    __shared__ int lds[256];
    const int* cnt; int* cur; int nb;
    if (blockIdx.x == 0) { cnt = aCnt; cur = aCur; nb = NB_A; }
    else { cnt = sCnt; cur = sCur; nb = NB_S; }
    int tid = threadIdx.x;
    int v[5]; int s = 0;
#pragma unroll
    for (int k = 0; k < 5; ++k) {
        int i = tid * 5 + k;
        v[k] = s;
        s += (i < nb) ? cnt[i] : 0;
    }
    lds[tid] = s;
    __syncthreads();
    for (int off = 1; off < 256; off <<= 1) {
        int t = (tid >= off) ? lds[tid - off] : 0;
        __syncthreads();
        lds[tid] += t;
        __syncthreads();
    }
    int base = (tid > 0) ? lds[tid - 1] : 0;
#pragma unroll
    for (int k = 0; k < 5; ++k) {
        int i = tid * 5 + k;
        if (i < nb) cur[i] = base + v[k];
    }
}

// ---------------- partition: block-local counting sort into bucket regions ----------------
// pack.y = col | (row_in_bucket << 18)   (col < 262144, rl < 128)
__global__ __launch_bounds__(256) void partition_fused(
    const float* __restrict__ a_vals, const int* __restrict__ a_rows, const int* __restrict__ a_cols,
    const float* __restrict__ s_vals, const int* __restrict__ s_rows, const int* __restrict__ s_cols,
    int* __restrict__ aCur, int* __restrict__ sCur,
    int2* __restrict__ aPack, int2* __restrict__ sPack) {
    __shared__ int h[NB_A];
    __shared__ int cur[NB_A];
    int blk = blockIdx.x;
    const float* vals; const int* rows; const int* cols; int n; int nb; int* gcur; int2* pack; int base;
    if (blk < PBLK_A) { vals = a_vals; rows = a_rows; cols = a_cols; n = NNZ_AC; nb = NB_A; gcur = aCur; pack = aPack; base = blk * IPB; }
    else { vals = s_vals; rows = s_rows; cols = s_cols; n = NNZ_SC; nb = NB_S; gcur = sCur; pack = sPack; base = (blk - PBLK_A) * IPB; }
    int tid = threadIdx.x;
    for (int i = tid; i < nb; i += 256) h[i] = 0;
    __syncthreads();
    for (int k = 0; k < IPB; k += 256) {
        int idx = base + k + tid;
        if (idx < n) atomicAdd(&h[rows[idx] >> 7], 1);
    }
    __syncthreads();
    for (int i = tid; i < nb; i += 256) {
        int c = h[i];
        cur[i] = c ? atomicAdd(&gcur[i], c) : 0;
    }
    __syncthreads();
    for (int k = 0; k < IPB; k += 256) {
        int idx = base + k + tid;
        if (idx < n) {
            int r = rows[idx];
            int b = r >> 7;
            int pos = atomicAdd(&cur[b], 1);
            pack[pos] = make_int2(__float_as_int(vals[idx]), cols[idx] | ((r & 127) << 18));
        }
    }
}

// ---------------- finalize: per-bucket counting sort -> row-grouped entries + rowptr ----------------
__global__ __launch_bounds__(256) void csr_finalize(const int* __restrict__ aEnd, const int* __restrict__ sEnd,
                                                    const int2* __restrict__ aRaw, const int2* __restrict__ sRaw,
                                                    int2* __restrict__ aOut, int2* __restrict__ sOut,
                                                    int* __restrict__ aRp, int* __restrict__ sRp) {
    __shared__ int cnt_[RPB];
    __shared__ int scn[RPB];
    __shared__ int cursor[RPB];
    int blk = blockIdx.x;
    const int* ends; const int2* raw; int2* outp; int* rp; int nb; int nrows; int b;
    if (blk < NB_A) { ends = aEnd; raw = aRaw; outp = aOut; rp = aRp; nb = NB_A; nrows = N_TOTALC; b = blk; }
    else { ends = sEnd; raw = sRaw; outp = sOut; rp = sRp; nb = NB_S; nrows = N_USERC; b = blk - NB_A; }
    int s = b ? ends[b - 1] : 0;
    int e = ends[b];
    int n = e - s;
    int tid = threadIdx.x;
    if (tid < RPB) cnt_[tid] = 0;
    __syncthreads();
    for (int i = tid; i < n; i += 256)
        atomicAdd(&cnt_[(raw[s + i].y >> 18) & 127], 1);
    __syncthreads();
    if (tid < RPB) scn[tid] = cnt_[tid];
    __syncthreads();
    for (int off = 1; off < RPB; off <<= 1) {
        int t = (tid < RPB && tid >= off) ? scn[tid - off] : 0;
        __syncthreads();
        if (tid < RPB) scn[tid] += t;
        __syncthreads();
    }
    if (tid < RPB) {
        int ex = scn[tid] - cnt_[tid];      // exclusive
        cursor[tid] = ex;
        int row = (b << 7) + tid;
        if (row < nrows) rp[row] = s + ex;
    }
    if (b == nb - 1 && tid == 0) rp[nrows] = e;
    __syncthreads();
    for (int i = tid; i < n; i += 256) {
        int2 en = raw[s + i];
        int r = (en.y >> 18) & 127;
        int pos = atomicAdd(&cursor[r], 1);
        outp[s + pos] = make_int2(en.x, en.y & 0x3FFFF);
    }
}

// ---------------- concat + fp32->bf16 convert: embH = bf16(concat(user_emb, item_emb)) ----------------
__global__ __launch_bounds__(256) void to_bf16_concat(const float* __restrict__ xu, const float* __restrict__ xi,
                                                      unsigned short* __restrict__ out) {
    size_t i4 = (size_t)blockIdx.x * 256 + threadIdx.x;
    const size_t NU4 = (size_t)N_USERC * 16;     // float4 count in user part
    const size_t NT4 = (size_t)N_TOTALC * 16;
    if (i4 >= NT4) return;
    float4 v = (i4 < NU4) ? ((const float4*)xu)[i4] : ((const float4*)xi)[i4 - NU4];
    ushort4 h;
    h.x = F2B(v.x); h.y = F2B(v.y); h.z = F2B(v.z); h.w = F2B(v.w);
    ((ushort4*)out)[i4] = h;
}

// ---------------- CSR SpMM, bf16 gather operand: one wave per row, 8-deep pipeline ----------------
// writes fp32 y and bf16 mirror yh
__global__ __launch_bounds__(256) void spmm_h(const int* __restrict__ rowptr,
                                              const int2* __restrict__ pack,
                                              const unsigned short* __restrict__ xh,
                                              float* __restrict__ y,
                                              unsigned short* __restrict__ yh, int nrows) {
    int w = (blockIdx.x * blockDim.x + threadIdx.x) >> 6;
    int lane = threadIdx.x & 63;
    if (w >= nrows) return;
    int s = rowptr[w], e = rowptr[w + 1];
    float a0 = 0.f, a1 = 0.f, a2 = 0.f, a3 = 0.f;
    int j = s;
    for (; j + 8 <= e; j += 8) {
        int2 e0 = pack[j], e1 = pack[j + 1], e2 = pack[j + 2], e3 = pack[j + 3];
        int2 e4 = pack[j + 4], e5 = pack[j + 5], e6 = pack[j + 6], e7 = pack[j + 7];
        float g0 = B2F(xh[(size_t)e0.y * 64 + lane]);
        float g1 = B2F(xh[(size_t)e1.y * 64 + lane]);
        float g2 = B2F(xh[(size_t)e2.y * 64 + lane]);
        float g3 = B2F(xh[(size_t)e3.y * 64 + lane]);
        float g4 = B2F(xh[(size_t)e4.y * 64 + lane]);
        float g5 = B2F(xh[(size_t)e5.y * 64 + lane]);
        float g6 = B2F(xh[(size_t)e6.y * 64 + lane]);
        float g7 = B2F(xh[(size_t)e7.y * 64 + lane]);
        a0 += __int_as_float(e0.x) * g0;
        a1 += __int_as_float(e1.x) * g1;
        a2 += __int_as_float(e2.x) * g2;
        a3 += __int_as_float(e3.x) * g3;
        a0 += __int_as_float(e4.x) * g4;
        a1 += __int_as_float(e5.x) * g5;
        a2 += __int_as_float(e6.x) * g6;
        a3 += __int_as_float(e7.x) * g7;
    }
    if (j + 4 <= e) {
        int2 e0 = pack[j], e1 = pack[j + 1], e2 = pack[j + 2], e3 = pack[j + 3];
        float g0 = B2F(xh[(size_t)e0.y * 64 + lane]);
        float g1 = B2F(xh[(size_t)e1.y * 64 + lane]);
        float g2 = B2F(xh[(size_t)e2.y * 64 + lane]);
        float g3 = B2F(xh[(size_t)e3.y * 64 + lane]);
        a0 += __int_as_float(e0.x) * g0;
        a1 += __int_as_float(e1.x) * g1;
        a2 += __int_as_float(e2.x) * g2;
        a3 += __int_as_float(e3.x) * g3;
        j += 4;
    }
    for (; j < e; ++j) {
        int2 e0 = pack[j];
        a0 += __int_as_float(e0.x) * B2F(xh[(size_t)e0.y * 64 + lane]);
    }
    float r = (a0 + a1) + (a2 + a3);
    y[(size_t)w * 64 + lane] = r;
    yh[(size_t)w * 64 + lane] = F2B(r);
}

// ---------------- collapsed encoder ----------------
__global__ __launch_bounds__(256) void mc_kernel(const float* __restrict__ w0, const float* __restrict__ b0,
                                                 const float* __restrict__ w2, const float* __restrict__ b2,
                                                 float* __restrict__ Mrm, float* __restrict__ cvec) {
    int idx = blockIdx.x * 256 + threadIdx.x;
    if (idx < 4096) {
        int j = idx >> 6, d = idx & 63;
        float acc = 0.f;
        for (int k = 0; k < 256; ++k) acc += w2[j * 256 + k] * w0[k * 64 + d];
        Mrm[idx] = acc;
    } else if (idx < 4160) {
        int i = idx - 4096;
        float acc = b2[i];
        for (int k = 0; k < 256; ++k) acc += w2[i * 256 + k] * b0[k];
        cvec[i] = acc;
    }
}

// enc(f) = f @ Mrm^T + cvec ; one wave per row; fused tail+head
__global__ __launch_bounds__(256) void enc2_fused(const float* __restrict__ emb,
                                                  const int* __restrict__ tail_idx, const int* __restrict__ head_idx,
                                                  const float* __restrict__ Mrm, const float* __restrict__ cvec,
                                                  float* __restrict__ tail_e, float* __restrict__ top_e) {
    __shared__ float fsh[4][64];
    int wv = threadIdx.x >> 6, lane = threadIdx.x & 63;
    int r = blockIdx.x * 4 + wv;
    int item;
    float* outp;
    if (r < N_TAILC) { item = tail_idx[r]; outp = tail_e + (size_t)r * 64; }
    else if (r < N_TAILC + N_HEADC) { item = head_idx[r - N_TAILC]; outp = top_e + (size_t)(r - N_TAILC) * 64; }
    else { item = -1; outp = nullptr; }
    if (item >= 0) fsh[wv][lane] = emb[(size_t)item * 64 + lane];
    __syncthreads();
    if (item < 0) return;
    float acc = cvec[lane];
#pragma unroll
    for (int d4 = 0; d4 < 64; d4 += 4) {
        float4 m4 = *(const float4*)&Mrm[lane * 64 + d4];
        float4 f4 = *(const float4*)&fsh[wv][d4];
        acc += m4.x * f4.x + m4.y * f4.y + m4.z * f4.z + m4.w * f4.w;
    }
    outp[lane] = acc;
}

// ---------------- score GEMM: C[m x 4000] = A[m x 64] @ B[4000 x 64]^T ----------------
__global__ __launch_bounds__(256) void score_gemm(const float* __restrict__ A,
                                                  const float* __restrict__ B,
                                                  float* __restrict__ C, int M) {
    __shared__ float As[32][132];
    __shared__ float Bs[32][132];
    int tid = threadIdx.x;
    int tx = tid & 15, ty = tid >> 4;
    int rowbase = blockIdx.y * 128;
    int colbase = blockIdx.x * 128;
    float acc[8][8];
#pragma unroll
    for (int i = 0; i < 8; ++i)
#pragma unroll
        for (int j = 0; j < 8; ++j) acc[i][j] = 0.f;

    for (int k0 = 0; k0 < 64; k0 += 32) {
        __syncthreads();
#pragma unroll
        for (int i = 0; i < 4; ++i) {
            int f = tid + i * 256;
            int r = f >> 3;
            int kq = (f & 7) << 2;
            int grow = rowbase + r;
            float4 av = (grow < M) ? *(const float4*)&A[(size_t)grow * 64 + k0 + kq]
                                   : make_float4(0.f, 0.f, 0.f, 0.f);
            As[kq + 0][r] = av.x; As[kq + 1][r] = av.y; As[kq + 2][r] = av.z; As[kq + 3][r] = av.w;
            int gcol = colbase + r;
            float4 bv = (gcol < N_HEADC) ? *(const float4*)&B[(size_t)gcol * 64 + k0 + kq]
                                         : make_float4(0.f, 0.f, 0.f, 0.f);
            Bs[kq + 0][r] = bv.x; Bs[kq + 1][r] = bv.y; Bs[kq + 2][r] = bv.z; Bs[kq + 3][r] = bv.w;
        }
        __syncthreads();
#pragma unroll
        for (int k = 0; k < 32; ++k) {
            float a[8], b[8];
#pragma unroll
            for (int i = 0; i < 8; ++i) a[i] = As[k][ty + 16 * i];
#pragma unroll
            for (int j = 0; j < 8; ++j) b[j] = Bs[k][tx + 16 * j];
#pragma unroll
            for (int i = 0; i < 8; ++i)
#pragma unroll
                for (int j = 0; j < 8; ++j) acc[i][j] += a[i] * b[j];
        }
    }
#pragma unroll
    for (int i = 0; i < 8; ++i) {
        int r = rowbase + ty + 16 * i;
        if (r < M) {
#pragma unroll
            for (int j = 0; j < 8; ++j) {
                int c = colbase + tx + 16 * j;
                if (c < N_HEADC) C[(size_t)r * N_HEADC + c] = acc[i][j];
            }
        }
    }
}

// ---------------- per-row top-k on materialized scores (constant-index registers only) ----------------
__global__ __launch_bounds__(256) void topk_rows(const float* __restrict__ scores, int nrows, int row0,
                                                 const int* __restrict__ head_idx,
                                                 int* __restrict__ ig_cols, float* __restrict__ ig_vals) {
    int w = (blockIdx.x * blockDim.x + threadIdx.x) >> 6;
    int lane = threadIdx.x & 63;
    if (w >= nrows) return;
    const float* srow = scores + (size_t)w * N_HEADC;
    float v[TOPKC];
    int id[TOPKC];
#pragma unroll
    for (int k = 0; k < TOPKC; ++k) { v[k] = -1e30f; id[k] = -1; }
    // scan: per-lane top-10 (all indices compile-time constant)
    for (int it = 0; it < 16; ++it) {
        int f4 = lane + it * 64;
        if (f4 < 1000) {
            float4 s4 = ((const float4*)srow)[f4];
            int cb = f4 * 4;
            float vv[4] = { s4.x, s4.y, s4.z, s4.w };
#pragma unroll
            for (int q = 0; q < 4; ++q) {
                float sc = vv[q];
                if (sc > v[TOPKC - 1]) {
                    float cv = sc; int ci = cb + q;
#pragma unroll
                    for (int k = 0; k < TOPKC; ++k) {
                        if (cv > v[k]) { float t = v[k]; int ti = id[k]; v[k] = cv; id[k] = ci; cv = t; ci = ti; }
                    }
                }
            }
        }
    }
    // extraction: head is always v[0]; winner lane shifts its list down (constant indices)
    float ssum = 0.f;
    float outv = 0.f;
    int outid = -1;
#pragma unroll
    for (int r = 0; r < TOPKC; ++r) {
        float cv = v[0];
        int ci = id[0];
        int wl = lane;
#pragma unroll
        for (int m = 1; m < 64; m <<= 1) {
            float ov = __shfl_xor(cv, m, 64);
            int oi = __shfl_xor(ci, m, 64);
            int ol = __shfl_xor(wl, m, 64);
            if (ov > cv || (ov == cv && ol < wl)) { cv = ov; ci = oi; wl = ol; }
        }
        if (wl == lane) {
#pragma unroll
            for (int k = 0; k < TOPKC - 1; ++k) { v[k] = v[k + 1]; id[k] = id[k + 1]; }
            v[TOPKC - 1] = -1e30f;
            id[TOPKC - 1] = -1;
        }
        ssum += 1.f / (1.f + expf(-cv));
        if (lane == r) { outv = cv; outid = ci; }
    }
    if (lane < TOPKC) {
        float s = 1.f / (1.f + expf(-outv));
        float wgt = s / (ssum + 1.f);
        int grow = row0 + w;
        ig_vals[grow * TOPKC + lane] = wgt;
        ig_cols[grow * TOPKC + lane] = head_idx[outid];
    }
}

// ---------------- item_enh accumulation ----------------
__global__ __launch_bounds__(256) void ig_spmm_kernel(const int* __restrict__ tail_idx,
                                                      const int* __restrict__ ig_cols,
                                                      const float* __restrict__ ig_vals,
                                                      const float* __restrict__ items,
                                                      float* __restrict__ enh) {
    int e = (blockIdx.x * blockDim.x + threadIdx.x) >> 6;
    int lane = threadIdx.x & 63;
    if (e >= N_TAILC * TOPKC) return;
    int row = tail_idx[e / TOPKC];
    int col = ig_cols[e];
    float w = ig_vals[e];
    atomicAdd(&enh[(size_t)row * 64 + lane], w * items[(size_t)col * 64 + lane]);
}

// ---------------- loss: one wave per sample, per-block partial outputs (NO global atomics) ----------------
__global__ __launch_bounds__(256) void loss_kernel(const float* __restrict__ u0, const float* __restrict__ u1,
                                                   const float* __restrict__ u2, const float* __restrict__ items,
                                                   const float* __restrict__ enh, const float* __restrict__ deg,
                                                   const float* __restrict__ user_emb, const float* __restrict__ item_emb,
                                                   const int* __restrict__ bu, const int* __restrict__ bp,
                                                   const int* __restrict__ bn, float* __restrict__ part) {
    __shared__ float lsum[4], rsum[4];
    int w = (blockIdx.x * blockDim.x + threadIdx.x) >> 6;
    int wv = threadIdx.x >> 6;
    int lane = threadIdx.x & 63;
    int uu = bu[w], pp = bp[w];
    float ue = (u0[uu * 64 + lane] + u1[uu * 64 + lane] + u2[uu * 64 + lane]) * (1.f / 3.f);
    float swp = CONVF / (CONVF + expf(deg[pp] * (1.f / CONVF)));
    float pe = items[pp * 64 + lane] + swp * enh[pp * 64 + lane];
    float ps = ue * pe;
    float ns = 0.f;
    float u0e = user_emb[uu * 64 + lane];
    float p0e = item_emb[pp * 64 + lane];
    float reg = u0e * u0e + p0e * p0e;
#pragma unroll
    for (int k = 0; k < N_NEGC; ++k) {
        int nn = bn[w * N_NEGC + k];
        float swn = CONVF / (CONVF + expf(deg[nn] * (1.f / CONVF)));
        float nv = items[nn * 64 + lane] + swn * enh[nn * 64 + lane];
        ns += ue * nv;
        float n0 = item_emb[nn * 64 + lane];
        reg += n0 * n0;
    }
#pragma unroll
    for (int m = 32; m >= 1; m >>= 1) {
        ps += __shfl_xor(ps, m, 64);
        ns += __shfl_xor(ns, m, 64);
        reg += __shfl_xor(reg, m, 64);
    }
    if (lane == 0) {
        float x = ns * (1.f / N_NEGC) - ps;
        float sp = (x > 0.f) ? (x + log1pf(expf(-x))) : log1pf(expf(x));
        lsum[wv] = sp;
        rsum[wv] = reg;
    }
    __syncthreads();
    if (threadIdx.x == 0) {
        part[blockIdx.x] = lsum[0] + lsum[1] + lsum[2] + lsum[3];
        part[LOSS_BLOCKS + blockIdx.x] = rsum[0] + rsum[1] + rsum[2] + rsum[3];
    }
}

// single-block final reduce: out[0]=loss, out[1]=reg
__global__ __launch_bounds__(256) void loss_reduce(const float* __restrict__ part, float* __restrict__ out) {
    __shared__ float l[256], r[256];
    int tid = threadIdx.x;
    float a = 0.f, b = 0.f;
    for (int i = tid; i < LOSS_BLOCKS; i += 256) {
        a += part[i];
        b += part[LOSS_BLOCKS + i];
    }
    l[tid] = a; r[tid] = b;
    __syncthreads();
    for (int off = 128; off >= 1; off >>= 1) {
        if (tid < off) { l[tid] += l[tid + off]; r[tid] += r[tid + off]; }
        __syncthreads();
    }
    if (tid == 0) {
        out[0] = l[0] * (1.f / BATCHC);
        out[1] = 0.5f * r[0] * (1.f / BATCHC);
    }
}

extern "C" void kernel_launch(void* const* d_in, const int* in_sizes, int n_in,
                              void* d_out, int out_size, void* d_ws, size_t ws_size,
                              hipStream_t stream) {
    const float* user_emb = (const float*)d_in[0];
    const float* item_emb = (const float*)d_in[1];
    const float* w0 = (const float*)d_in[2];
    const float* b0 = (const float*)d_in[3];
    const float* w2 = (const float*)d_in[4];
    const float* b2 = (const float*)d_in[5];
    const float* a_vals = (const float*)d_in[6];
    const float* s_vals = (const float*)d_in[7];
    const float* item_degree = (const float*)d_in[8];
    const int* a_rows = (const int*)d_in[9];
    const int* a_cols = (const int*)d_in[10];
    const int* s_rows = (const int*)d_in[11];
    const int* s_cols = (const int*)d_in[12];
    const int* tail_idx = (const int*)d_in[13];
    const int* head_idx = (const int*)d_in[14];
    const int* batch_user = (const int*)d_in[15];
    const int* batch_pos = (const int*)d_in[16];
    const int* batch_neg = (const int*)d_in[17];
    float* out = (float*)d_out;

    // ---- workspace carve ----
    char* p = (char*)d_ws;
    auto carve = [&](size_t bytes) -> void* {
        void* r = (void*)p;
        p += (bytes + 255) & ~size_t(255);
        return r;
    };
    float* embA = (float*)carve((size_t)N_TOTALC * 64 * 4);
    float* embB = (float*)carve((size_t)N_TOTALC * 64 * 4);
    float* u1 = (float*)carve((size_t)N_USERC * 64 * 4);
    float* u2 = (float*)carve((size_t)N_USERC * 64 * 4);
    float* enh = (float*)carve((size_t)N_ITEMC * 64 * 4);
    float* tail_e = (float*)carve((size_t)N_TAILC * 64 * 4);
    float* top_e = (float*)carve((size_t)N_HEADC * 64 * 4);
    int2* aSort = (int2*)carve((size_t)NNZ_AC * 8);       // final row-grouped entries
    int2* sSort = (int2*)carve((size_t)NNZ_SC * 8);
    int* a_rowptr = (int*)carve((size_t)(N_TOTALC + 1) * 4);
    int* s_rowptr = (int*)carve((size_t)(N_USERC + 1) * 4);
    int* aCnt = (int*)carve((size_t)NB_A * 4);
    int* sCnt = (int*)carve((size_t)NB_S * 4);
    int* aCur = (int*)carve((size_t)NB_A * 4);
    int* sCur = (int*)carve((size_t)NB_S * 4);
    int* ig_cols_buf = (int*)carve((size_t)N_TAILC * TOPKC * 4);
    float* ig_vals_buf = (float*)carve((size_t)N_TAILC * TOPKC * 4);
    float* Mrm = (float*)carve(64 * 64 * 4);
    float* cvec = (float*)carve(64 * 4);
    float* loss_part = (float*)carve((size_t)LOSS_BLOCKS * 2 * 4);
    unsigned short* embH0 = (unsigned short*)carve((size_t)N_TOTALC * 64 * 2);   // bf16 concat input
    unsigned short* embH1 = (unsigned short*)carve((size_t)N_TOTALC * 64 * 2);   // bf16 mirrors (ping)
    float* scores = (float*)carve((size_t)CHUNK_ROWS * N_HEADC * 4);   // 40MB
    // aliases within the scores region (dead across phases):
    int2* aPackRaw = (int2*)scores;                          // build phase only
    int2* sPackRaw = aPackRaw + NNZ_AC;                      // 16+8=24MB < 40MB
    unsigned short* embH2 = (unsigned short*)scores;         // L2 out / L3 in (19.2MB), after score phase
    unsigned short* uh1 = embH0;                             // S1 bf16 out (embH0 dead after L1)
    unsigned short* uh2 = embH1;                             // S2 bf16 out (unused downstream)

    // ---- bucketed CSR build (A + S) ----
    hipMemsetAsync(aCnt, 0, (size_t)NB_A * 4, stream);
    hipMemsetAsync(sCnt, 0, (size_t)NB_S * 4, stream);
    hist_bucket<<<PBLK_A + PBLK_S, 256, 0, stream>>>(a_rows, s_rows, aCnt, sCnt);
    scan_buckets<<<2, 256, 0, stream>>>(aCnt, sCnt, aCur, sCur);
    partition_fused<<<PBLK_A + PBLK_S, 256, 0, stream>>>(a_vals, a_rows, a_cols,
                                                         s_vals, s_rows, s_cols,
                                                         aCur, sCur, aPackRaw, sPackRaw);
    // aCur/sCur now hold bucket END offsets
    csr_finalize<<<NB_A + NB_S, 256, 0, stream>>>(aCur, sCur, aPackRaw, sPackRaw,
                                                  aSort, sSort, a_rowptr, s_rowptr);

    // ---- collapsed encoder (tail + head fused) ----
    mc_kernel<<<17, 256, 0, stream>>>(w0, b0, w2, b2, Mrm, cvec);
    enc2_fused<<<(N_TAILC + N_HEADC + 3) / 4, 256, 0, stream>>>(item_emb, tail_idx, head_idx, Mrm, cvec, tail_e, top_e);

    // ---- bf16 concat input table ----
    to_bf16_concat<<<((N_TOTALC * 16) + 255) / 256, 256, 0, stream>>>(user_emb, item_emb, embH0);

    // ---- chunked scores GEMM + top-k (aPackRaw dead from here) ----
    for (int row0 = 0; row0 < N_TAILC; row0 += CHUNK_ROWS) {
        int m = N_TAILC - row0;
        if (m > CHUNK_ROWS) m = CHUNK_ROWS;
        int rb = (m + 127) / 128;
        score_gemm<<<dim3((N_HEADC + 127) / 128, rb), 256, 0, stream>>>(tail_e + (size_t)row0 * 64, top_e, scores, m);
        topk_rows<<<(m + 3) / 4, 256, 0, stream>>>(scores, m, row0, head_idx, ig_cols_buf, ig_vals_buf);
    }

    // ---- 3 A-layers, bf16 gathers (scores region dead from here -> embH2 alias live) ----
    {
        int blocks = (N_TOTALC + 3) / 4;
        spmm_h<<<blocks, 256, 0, stream>>>(a_rowptr, aSort, embH0, embA, embH1, N_TOTALC);  // L1
        spmm_h<<<blocks, 256, 0, stream>>>(a_rowptr, aSort, embH1, embA, embH2, N_TOTALC);  // L2 (fp32 out dead)
        spmm_h<<<blocks, 256, 0, stream>>>(a_rowptr, aSort, embH2, embB, embH1, N_TOTALC);  // L3 -> final fp32 in embB
    }
    const float* u0 = embB;
    const float* items = embB + (size_t)N_USERC * 64;

    // ---- 2 S-layers on users, bf16 gathers ----
    {
        int blocks = (N_USERC + 3) / 4;
        spmm_h<<<blocks, 256, 0, stream>>>(s_rowptr, sSort, embH1, u1, uh1, N_USERC);  // S1 (gathers users rows of L3)
        spmm_h<<<blocks, 256, 0, stream>>>(s_rowptr, sSort, uh1, u2, uh2, N_USERC);    // S2 (bf16 out unused)
    }

    // ---- item enhancement ----
    hipMemsetAsync(enh, 0, (size_t)N_ITEMC * 64 * 4, stream);
    ig_spmm_kernel<<<(N_TAILC * TOPKC) / 4, 256, 0, stream>>>(tail_idx, ig_cols_buf, ig_vals_buf, items, enh);

    // ---- loss + reg: per-block partials then single-block reduce ----
    loss_kernel<<<LOSS_BLOCKS, 256, 0, stream>>>(u0, u1, u2, items, enh, item_degree,
                                                 user_emb, item_emb, batch_user, batch_pos, batch_neg, loss_part);
    loss_reduce<<<1, 256, 0, stream>>>(loss_part, out);
}

// Round 10
// 848.811 us; speedup vs baseline: 4.5265x; 1.2582x over previous
//
#include <hip/hip_runtime.h>
#include <hip/hip_bf16.h>

#define N_USERC 100000
#define N_ITEMC 50000
#define N_TOTALC 150000
#define DC 64
#define NNZ_AC 2000000
#define NNZ_SC 1000000
#define N_TAILC 10000
#define N_HEADC 4000
#define TOPKC 10
#define BATCHC 4096
#define N_NEGC 4
#define CONVF 40.0f
#define CHUNK_ROWS 2500

#define RPB 128                                  // rows per bucket
#define NB_A ((N_TOTALC + RPB - 1) / RPB)        // 1172
#define NB_S ((N_USERC + RPB - 1) / RPB)         // 782
#define IPB 6144                                 // items per partition block
#define PBLK_A ((NNZ_AC + IPB - 1) / IPB)        // 326
#define PBLK_S ((NNZ_SC + IPB - 1) / IPB)        // 163

#define LOSS_BLOCKS (BATCHC / 4)                 // 1024

__device__ __forceinline__ unsigned short F2B(float f) {
    __hip_bfloat16 b = __float2bfloat16(f);
    return *(unsigned short*)&b;
}
__device__ __forceinline__ float B2F(unsigned short h) {
    return __uint_as_float(((unsigned)h) << 16);
}

// ---------------- bucket histogram: LDS pre-aggregation, then flush ----------------
__global__ __launch_bounds__(256) void hist_bucket(const int* __restrict__ a_rows, const int* __restrict__ s_rows,
                                                   int* __restrict__ aCnt, int* __restrict__ sCnt) {
    __shared__ int h[NB_A];
    int blk = blockIdx.x;
    const int* rows; int n; int nb; int* gout; int base;
    if (blk < PBLK_A) { rows = a_rows; n = NNZ_AC; nb = NB_A; gout = aCnt; base = blk * IPB; }
    else { rows = s_rows; n = NNZ_SC; nb = NB_S; gout = sCnt; base = (blk - PBLK_A) * IPB; }
    for (int i = threadIdx.x; i < nb; i += 256) h[i] = 0;
    __syncthreads();
    for (int k = 0; k < IPB; k += 256) {
        int idx = base + k + threadIdx.x;
        if (idx < n) atomicAdd(&h[rows[idx] >> 7], 1);
    }
    __syncthreads();
    for (int i = threadIdx.x; i < nb; i += 256) {
        int c = h[i];
        if (c) atomicAdd(&gout[i], c);
    }
}

// ---------------- exclusive scan of bucket counts -> cursor bases (2 blocks) ----------------
__global__ __launch_bounds__(256) void scan_buckets(const int* __restrict__ aCnt, const int* __restrict__ sCnt,
                                                    int* __restrict__ aCur, int* __restrict__ sCur) {
    __shared__ int lds[256];
    const int* cnt; int* cur; int nb;
    if (blockIdx.x == 0) { cnt = aCnt; cur = aCur; nb = NB_A; }
    else { cnt = sCnt; cur = sCur; nb = NB_S; }
    int tid = threadIdx.x;
    int v[5]; int s = 0;
#pragma unroll
    for (int k = 0; k < 5; ++k) {
        int i = tid * 5 + k;
        v[k] = s;
        s += (i < nb) ? cnt[i] : 0;
    }
    lds[tid] = s;
    __syncthreads();
    for (int off = 1; off < 256; off <<= 1) {
        int t = (tid >= off) ? lds[tid - off] : 0;
        __syncthreads();
        lds[tid] += t;
        __syncthreads();
    }
    int base = (tid > 0) ? lds[tid - 1] : 0;
#pragma unroll
    for (int k = 0; k < 5; ++k) {
        int i = tid * 5 + k;
        if (i < nb) cur[i] = base + v[k];
    }
}

// ---------------- partition: block-local counting sort into bucket regions ----------------
// pack.y = col | (row_in_bucket << 18)   (col < 262144, rl < 128)
__global__ __launch_bounds__(256) void partition_fused(
    const float* __restrict__ a_vals, const int* __restrict__ a_rows, const int* __restrict__ a_cols,
    const float* __restrict__ s_vals, const int* __restrict__ s_rows, const int* __restrict__ s_cols,
    int* __restrict__ aCur, int* __restrict__ sCur,
    int2* __restrict__ aPack, int2* __restrict__ sPack) {
    __shared__ int h[NB_A];
    __shared__ int cur[NB_A];
    int blk = blockIdx.x;
    const float* vals; const int* rows; const int* cols; int n; int nb; int* gcur; int2* pack; int base;
    if (blk < PBLK_A) { vals = a_vals; rows = a_rows; cols = a_cols; n = NNZ_AC; nb = NB_A; gcur = aCur; pack = aPack; base = blk * IPB; }
    else { vals = s_vals; rows = s_rows; cols = s_cols; n = NNZ_SC; nb = NB_S; gcur = sCur; pack = sPack; base = (blk - PBLK_A) * IPB; }
    int tid = threadIdx.x;
    for (int i = tid; i < nb; i += 256) h[i] = 0;
    __syncthreads();
    for (int k = 0; k < IPB; k += 256) {
        int idx = base + k + tid;
        if (idx < n) atomicAdd(&h[rows[idx] >> 7], 1);
    }
    __syncthreads();
    for (int i = tid; i < nb; i += 256) {
        int c = h[i];
        cur[i] = c ? atomicAdd(&gcur[i], c) : 0;
    }
    __syncthreads();
    for (int k = 0; k < IPB; k += 256) {
        int idx = base + k + tid;
        if (idx < n) {
            int r = rows[idx];
            int b = r >> 7;
            int pos = atomicAdd(&cur[b], 1);
            pack[pos] = make_int2(__float_as_int(vals[idx]), cols[idx] | ((r & 127) << 18));
        }
    }
}

// ---------------- finalize: per-bucket counting sort -> row-grouped entries + rowptr ----------------
__global__ __launch_bounds__(256) void csr_finalize(const int* __restrict__ aEnd, const int* __restrict__ sEnd,
                                                    const int2* __restrict__ aRaw, const int2* __restrict__ sRaw,
                                                    int2* __restrict__ aOut, int2* __restrict__ sOut,
                                                    int* __restrict__ aRp, int* __restrict__ sRp) {
    __shared__ int cnt_[RPB];
    __shared__ int scn[RPB];
    __shared__ int cursor[RPB];
    int blk = blockIdx.x;
    const int* ends; const int2* raw; int2* outp; int* rp; int nb; int nrows; int b;
    if (blk < NB_A) { ends = aEnd; raw = aRaw; outp = aOut; rp = aRp; nb = NB_A; nrows = N_TOTALC; b = blk; }
    else { ends = sEnd; raw = sRaw; outp = sOut; rp = sRp; nb = NB_S; nrows = N_USERC; b = blk - NB_A; }
    int s = b ? ends[b - 1] : 0;
    int e = ends[b];
    int n = e - s;
    int tid = threadIdx.x;
    if (tid < RPB) cnt_[tid] = 0;
    __syncthreads();
    for (int i = tid; i < n; i += 256)
        atomicAdd(&cnt_[(raw[s + i].y >> 18) & 127], 1);
    __syncthreads();
    if (tid < RPB) scn[tid] = cnt_[tid];
    __syncthreads();
    for (int off = 1; off < RPB; off <<= 1) {
        int t = (tid < RPB && tid >= off) ? scn[tid - off] : 0;
        __syncthreads();
        if (tid < RPB) scn[tid] += t;
        __syncthreads();
    }
    if (tid < RPB) {
        int ex = scn[tid] - cnt_[tid];      // exclusive
        cursor[tid] = ex;
        int row = (b << 7) + tid;
        if (row < nrows) rp[row] = s + ex;
    }
    if (b == nb - 1 && tid == 0) rp[nrows] = e;
    __syncthreads();
    for (int i = tid; i < n; i += 256) {
        int2 en = raw[s + i];
        int r = (en.y >> 18) & 127;
        int pos = atomicAdd(&cursor[r], 1);
        outp[s + pos] = make_int2(en.x, en.y & 0x3FFFF);
    }
}

// ---------------- concat + fp32->bf16 convert: embH = bf16(concat(user_emb, item_emb)) ----------------
__global__ __launch_bounds__(256) void to_bf16_concat(const float* __restrict__ xu, const float* __restrict__ xi,
                                                      unsigned short* __restrict__ out) {
    size_t i4 = (size_t)blockIdx.x * 256 + threadIdx.x;
    const size_t NU4 = (size_t)N_USERC * 16;     // float4 count in user part
    const size_t NT4 = (size_t)N_TOTALC * 16;
    if (i4 >= NT4) return;
    float4 v = (i4 < NU4) ? ((const float4*)xu)[i4] : ((const float4*)xi)[i4 - NU4];
    ushort4 h;
    h.x = F2B(v.x); h.y = F2B(v.y); h.z = F2B(v.z); h.w = F2B(v.w);
    ((ushort4*)out)[i4] = h;
}

// ---------------- CSR SpMM, bf16 gather operand: one wave per row, 8-deep pipeline ----------------
// writes fp32 y and bf16 mirror yh
__global__ __launch_bounds__(256) void spmm_h(const int* __restrict__ rowptr,
                                              const int2* __restrict__ pack,
                                              const unsigned short* __restrict__ xh,
                                              float* __restrict__ y,
                                              unsigned short* __restrict__ yh, int nrows) {
    int w = (blockIdx.x * blockDim.x + threadIdx.x) >> 6;
    int lane = threadIdx.x & 63;
    if (w >= nrows) return;
    int s = rowptr[w], e = rowptr[w + 1];
    float a0 = 0.f, a1 = 0.f, a2 = 0.f, a3 = 0.f;
    int j = s;
    for (; j + 8 <= e; j += 8) {
        int2 e0 = pack[j], e1 = pack[j + 1], e2 = pack[j + 2], e3 = pack[j + 3];
        int2 e4 = pack[j + 4], e5 = pack[j + 5], e6 = pack[j + 6], e7 = pack[j + 7];
        float g0 = B2F(xh[(size_t)e0.y * 64 + lane]);
        float g1 = B2F(xh[(size_t)e1.y * 64 + lane]);
        float g2 = B2F(xh[(size_t)e2.y * 64 + lane]);
        float g3 = B2F(xh[(size_t)e3.y * 64 + lane]);
        float g4 = B2F(xh[(size_t)e4.y * 64 + lane]);
        float g5 = B2F(xh[(size_t)e5.y * 64 + lane]);
        float g6 = B2F(xh[(size_t)e6.y * 64 + lane]);
        float g7 = B2F(xh[(size_t)e7.y * 64 + lane]);
        a0 += __int_as_float(e0.x) * g0;
        a1 += __int_as_float(e1.x) * g1;
        a2 += __int_as_float(e2.x) * g2;
        a3 += __int_as_float(e3.x) * g3;
        a0 += __int_as_float(e4.x) * g4;
        a1 += __int_as_float(e5.x) * g5;
        a2 += __int_as_float(e6.x) * g6;
        a3 += __int_as_float(e7.x) * g7;
    }
    if (j + 4 <= e) {
        int2 e0 = pack[j], e1 = pack[j + 1], e2 = pack[j + 2], e3 = pack[j + 3];
        float g0 = B2F(xh[(size_t)e0.y * 64 + lane]);
        float g1 = B2F(xh[(size_t)e1.y * 64 + lane]);
        float g2 = B2F(xh[(size_t)e2.y * 64 + lane]);
        float g3 = B2F(xh[(size_t)e3.y * 64 + lane]);
        a0 += __int_as_float(e0.x) * g0;
        a1 += __int_as_float(e1.x) * g1;
        a2 += __int_as_float(e2.x) * g2;
        a3 += __int_as_float(e3.x) * g3;
        j += 4;
    }
    for (; j < e; ++j) {
        int2 e0 = pack[j];
        a0 += __int_as_float(e0.x) * B2F(xh[(size_t)e0.y * 64 + lane]);
    }
    float r = (a0 + a1) + (a2 + a3);
    y[(size_t)w * 64 + lane] = r;
    yh[(size_t)w * 64 + lane] = F2B(r);
}

// ---------------- collapsed encoder ----------------
__global__ __launch_bounds__(256) void mc_kernel(const float* __restrict__ w0, const float* __restrict__ b0,
                                                 const float* __restrict__ w2, const float* __restrict__ b2,
                                                 float* __restrict__ Mrm, float* __restrict__ cvec) {
    int idx = blockIdx.x * 256 + threadIdx.x;
    if (idx < 4096) {
        int j = idx >> 6, d = idx & 63;
        float acc = 0.f;
        for (int k = 0; k < 256; ++k) acc += w2[j * 256 + k] * w0[k * 64 + d];
        Mrm[idx] = acc;
    } else if (idx < 4160) {
        int i = idx - 4096;
        float acc = b2[i];
        for (int k = 0; k < 256; ++k) acc += w2[i * 256 + k] * b0[k];
        cvec[i] = acc;
    }
}

// enc(f) = f @ Mrm^T + cvec ; one wave per row; fused tail+head
__global__ __launch_bounds__(256) void enc2_fused(const float* __restrict__ emb,
                                                  const int* __restrict__ tail_idx, const int* __restrict__ head_idx,
                                                  const float* __restrict__ Mrm, const float* __restrict__ cvec,
                                                  float* __restrict__ tail_e, float* __restrict__ top_e) {
    __shared__ float fsh[4][64];
    int wv = threadIdx.x >> 6, lane = threadIdx.x & 63;
    int r = blockIdx.x * 4 + wv;
    int item;
    float* outp;
    if (r < N_TAILC) { item = tail_idx[r]; outp = tail_e + (size_t)r * 64; }
    else if (r < N_TAILC + N_HEADC) { item = head_idx[r - N_TAILC]; outp = top_e + (size_t)(r - N_TAILC) * 64; }
    else { item = -1; outp = nullptr; }
    if (item >= 0) fsh[wv][lane] = emb[(size_t)item * 64 + lane];
    __syncthreads();
    if (item < 0) return;
    float acc = cvec[lane];
#pragma unroll
    for (int d4 = 0; d4 < 64; d4 += 4) {
        float4 m4 = *(const float4*)&Mrm[lane * 64 + d4];
        float4 f4 = *(const float4*)&fsh[wv][d4];
        acc += m4.x * f4.x + m4.y * f4.y + m4.z * f4.z + m4.w * f4.w;
    }
    outp[lane] = acc;
}

// ---------------- score GEMM: C[m x 4000] = A[m x 64] @ B[4000 x 64]^T ----------------
__global__ __launch_bounds__(256) void score_gemm(const float* __restrict__ A,
                                                  const float* __restrict__ B,
                                                  float* __restrict__ C, int M) {
    __shared__ float As[32][132];
    __shared__ float Bs[32][132];
    int tid = threadIdx.x;
    int tx = tid & 15, ty = tid >> 4;
    int rowbase = blockIdx.y * 128;
    int colbase = blockIdx.x * 128;
    float acc[8][8];
#pragma unroll
    for (int i = 0; i < 8; ++i)
#pragma unroll
        for (int j = 0; j < 8; ++j) acc[i][j] = 0.f;

    for (int k0 = 0; k0 < 64; k0 += 32) {
        __syncthreads();
#pragma unroll
        for (int i = 0; i < 4; ++i) {
            int f = tid + i * 256;
            int r = f >> 3;
            int kq = (f & 7) << 2;
            int grow = rowbase + r;
            float4 av = (grow < M) ? *(const float4*)&A[(size_t)grow * 64 + k0 + kq]
                                   : make_float4(0.f, 0.f, 0.f, 0.f);
            As[kq + 0][r] = av.x; As[kq + 1][r] = av.y; As[kq + 2][r] = av.z; As[kq + 3][r] = av.w;
            int gcol = colbase + r;
            float4 bv = (gcol < N_HEADC) ? *(const float4*)&B[(size_t)gcol * 64 + k0 + kq]
                                         : make_float4(0.f, 0.f, 0.f, 0.f);
            Bs[kq + 0][r] = bv.x; Bs[kq + 1][r] = bv.y; Bs[kq + 2][r] = bv.z; Bs[kq + 3][r] = bv.w;
        }
        __syncthreads();
#pragma unroll
        for (int k = 0; k < 32; ++k) {
            float a[8], b[8];
#pragma unroll
            for (int i = 0; i < 8; ++i) a[i] = As[k][ty + 16 * i];
#pragma unroll
            for (int j = 0; j < 8; ++j) b[j] = Bs[k][tx + 16 * j];
#pragma unroll
            for (int i = 0; i < 8; ++i)
#pragma unroll
                for (int j = 0; j < 8; ++j) acc[i][j] += a[i] * b[j];
        }
    }
#pragma unroll
    for (int i = 0; i < 8; ++i) {
        int r = rowbase + ty + 16 * i;
        if (r < M) {
#pragma unroll
            for (int j = 0; j < 8; ++j) {
                int c = colbase + tx + 16 * j;
                if (c < N_HEADC) C[(size_t)r * N_HEADC + c] = acc[i][j];
            }
        }
    }
}

// ---------------- per-row top-k: NAMED SCALARS ONLY (no arrays -> forced register allocation) ----------------
#define BUB(vk, ik) { if (cv > vk) { float tf = vk; vk = cv; cv = tf; int ti = ik; ik = ci; ci = ti; } }
#define TINS(sc, idx) { float sc_ = (sc); if (sc_ > v9) { float cv = sc_; int ci = (idx); \
    BUB(v0, i0) BUB(v1, i1) BUB(v2, i2) BUB(v3, i3) BUB(v4, i4) \
    BUB(v5, i5) BUB(v6, i6) BUB(v7, i7) BUB(v8, i8) BUB(v9, i9) } }

__global__ __launch_bounds__(256) void topk_rows(const float* __restrict__ scores, int nrows, int row0,
                                                 const int* __restrict__ head_idx,
                                                 int* __restrict__ ig_cols, float* __restrict__ ig_vals) {
    int w = (blockIdx.x * blockDim.x + threadIdx.x) >> 6;
    int lane = threadIdx.x & 63;
    if (w >= nrows) return;
    const float* srow = scores + (size_t)w * N_HEADC;
    float v0 = -1e30f, v1 = -1e30f, v2 = -1e30f, v3 = -1e30f, v4 = -1e30f;
    float v5 = -1e30f, v6 = -1e30f, v7 = -1e30f, v8 = -1e30f, v9 = -1e30f;
    int i0 = -1, i1 = -1, i2 = -1, i3 = -1, i4 = -1;
    int i5 = -1, i6 = -1, i7 = -1, i8 = -1, i9 = -1;
    // scan: per-lane top-10 held in named scalars (v0 >= v1 >= ... >= v9)
    for (int it = 0; it < 16; ++it) {
        int f4 = lane + it * 64;
        if (f4 < 1000) {
            float4 s4 = ((const float4*)srow)[f4];
            int cb = f4 * 4;
            TINS(s4.x, cb + 0)
            TINS(s4.y, cb + 1)
            TINS(s4.z, cb + 2)
            TINS(s4.w, cb + 3)
        }
    }
    // extraction: wave-max butterfly; winner shifts its named list down
    float ssum = 0.f;
    float outv = 0.f;
    int outid = -1;
#pragma unroll
    for (int r = 0; r < TOPKC; ++r) {
        float cv = v0;
        int ci = i0;
        int wl = lane;
#pragma unroll
        for (int m = 1; m < 64; m <<= 1) {
            float ov = __shfl_xor(cv, m, 64);
            int oi = __shfl_xor(ci, m, 64);
            int ol = __shfl_xor(wl, m, 64);
            if (ov > cv || (ov == cv && ol < wl)) { cv = ov; ci = oi; wl = ol; }
        }
        if (wl == lane) {
            v0 = v1; i0 = i1; v1 = v2; i1 = i2; v2 = v3; i2 = i3;
            v3 = v4; i3 = i4; v4 = v5; i4 = i5; v5 = v6; i5 = i6;
            v6 = v7; i6 = i7; v7 = v8; i7 = i8; v8 = v9; i8 = i9;
            v9 = -1e30f; i9 = -1;
        }
        ssum += 1.f / (1.f + expf(-cv));
        if (lane == r) { outv = cv; outid = ci; }
    }
    if (lane < TOPKC) {
        float s = 1.f / (1.f + expf(-outv));
        float wgt = s / (ssum + 1.f);
        int grow = row0 + w;
        ig_vals[grow * TOPKC + lane] = wgt;
        ig_cols[grow * TOPKC + lane] = head_idx[outid];
    }
}

// ---------------- item_enh accumulation ----------------
__global__ __launch_bounds__(256) void ig_spmm_kernel(const int* __restrict__ tail_idx,
                                                      const int* __restrict__ ig_cols,
                                                      const float* __restrict__ ig_vals,
                                                      const float* __restrict__ items,
                                                      float* __restrict__ enh) {
    int e = (blockIdx.x * blockDim.x + threadIdx.x) >> 6;
    int lane = threadIdx.x & 63;
    if (e >= N_TAILC * TOPKC) return;
    int row = tail_idx[e / TOPKC];
    int col = ig_cols[e];
    float w = ig_vals[e];
    atomicAdd(&enh[(size_t)row * 64 + lane], w * items[(size_t)col * 64 + lane]);
}

// ---------------- loss: one wave per sample, per-block partial outputs (NO global atomics) ----------------
__global__ __launch_bounds__(256) void loss_kernel(const float* __restrict__ u0, const float* __restrict__ u1,
                                                   const float* __restrict__ u2, const float* __restrict__ items,
                                                   const float* __restrict__ enh, const float* __restrict__ deg,
                                                   const float* __restrict__ user_emb, const float* __restrict__ item_emb,
                                                   const int* __restrict__ bu, const int* __restrict__ bp,
                                                   const int* __restrict__ bn, float* __restrict__ part) {
    __shared__ float lsum[4], rsum[4];
    int w = (blockIdx.x * blockDim.x + threadIdx.x) >> 6;
    int wv = threadIdx.x >> 6;
    int lane = threadIdx.x & 63;
    int uu = bu[w], pp = bp[w];
    float ue = (u0[uu * 64 + lane] + u1[uu * 64 + lane] + u2[uu * 64 + lane]) * (1.f / 3.f);
    float swp = CONVF / (CONVF + expf(deg[pp] * (1.f / CONVF)));
    float pe = items[pp * 64 + lane] + swp * enh[pp * 64 + lane];
    float ps = ue * pe;
    float ns = 0.f;
    float u0e = user_emb[uu * 64 + lane];
    float p0e = item_emb[pp * 64 + lane];
    float reg = u0e * u0e + p0e * p0e;
#pragma unroll
    for (int k = 0; k < N_NEGC; ++k) {
        int nn = bn[w * N_NEGC + k];
        float swn = CONVF / (CONVF + expf(deg[nn] * (1.f / CONVF)));
        float nv = items[nn * 64 + lane] + swn * enh[nn * 64 + lane];
        ns += ue * nv;
        float n0 = item_emb[nn * 64 + lane];
        reg += n0 * n0;
    }
#pragma unroll
    for (int m = 32; m >= 1; m >>= 1) {
        ps += __shfl_xor(ps, m, 64);
        ns += __shfl_xor(ns, m, 64);
        reg += __shfl_xor(reg, m, 64);
    }
    if (lane == 0) {
        float x = ns * (1.f / N_NEGC) - ps;
        float sp = (x > 0.f) ? (x + log1pf(expf(-x))) : log1pf(expf(x));
        lsum[wv] = sp;
        rsum[wv] = reg;
    }
    __syncthreads();
    if (threadIdx.x == 0) {
        part[blockIdx.x] = lsum[0] + lsum[1] + lsum[2] + lsum[3];
        part[LOSS_BLOCKS + blockIdx.x] = rsum[0] + rsum[1] + rsum[2] + rsum[3];
    }
}

// single-block final reduce: out[0]=loss, out[1]=reg
__global__ __launch_bounds__(256) void loss_reduce(const float* __restrict__ part, float* __restrict__ out) {
    __shared__ float l[256], r[256];
    int tid = threadIdx.x;
    float a = 0.f, b = 0.f;
    for (int i = tid; i < LOSS_BLOCKS; i += 256) {
        a += part[i];
        b += part[LOSS_BLOCKS + i];
    }
    l[tid] = a; r[tid] = b;
    __syncthreads();
    for (int off = 128; off >= 1; off >>= 1) {
        if (tid < off) { l[tid] += l[tid + off]; r[tid] += r[tid + off]; }
        __syncthreads();
    }
    if (tid == 0) {
        out[0] = l[0] * (1.f / BATCHC);
        out[1] = 0.5f * r[0] * (1.f / BATCHC);
    }
}

extern "C" void kernel_launch(void* const* d_in, const int* in_sizes, int n_in,
                              void* d_out, int out_size, void* d_ws, size_t ws_size,
                              hipStream_t stream) {
    const float* user_emb = (const float*)d_in[0];
    const float* item_emb = (const float*)d_in[1];
    const float* w0 = (const float*)d_in[2];
    const float* b0 = (const float*)d_in[3];
    const float* w2 = (const float*)d_in[4];
    const float* b2 = (const float*)d_in[5];
    const float* a_vals = (const float*)d_in[6];
    const float* s_vals = (const float*)d_in[7];
    const float* item_degree = (const float*)d_in[8];
    const int* a_rows = (const int*)d_in[9];
    const int* a_cols = (const int*)d_in[10];
    const int* s_rows = (const int*)d_in[11];
    const int* s_cols = (const int*)d_in[12];
    const int* tail_idx = (const int*)d_in[13];
    const int* head_idx = (const int*)d_in[14];
    const int* batch_user = (const int*)d_in[15];
    const int* batch_pos = (const int*)d_in[16];
    const int* batch_neg = (const int*)d_in[17];
    float* out = (float*)d_out;

    // ---- workspace carve ----
    char* p = (char*)d_ws;
    auto carve = [&](size_t bytes) -> void* {
        void* r = (void*)p;
        p += (bytes + 255) & ~size_t(255);
        return r;
    };
    float* embA = (float*)carve((size_t)N_TOTALC * 64 * 4);
    float* embB = (float*)carve((size_t)N_TOTALC * 64 * 4);
    float* u1 = (float*)carve((size_t)N_USERC * 64 * 4);
    float* u2 = (float*)carve((size_t)N_USERC * 64 * 4);
    float* enh = (float*)carve((size_t)N_ITEMC * 64 * 4);
    float* tail_e = (float*)carve((size_t)N_TAILC * 64 * 4);
    float* top_e = (float*)carve((size_t)N_HEADC * 64 * 4);
    int2* aSort = (int2*)carve((size_t)NNZ_AC * 8);       // final row-grouped entries
    int2* sSort = (int2*)carve((size_t)NNZ_SC * 8);
    int* a_rowptr = (int*)carve((size_t)(N_TOTALC + 1) * 4);
    int* s_rowptr = (int*)carve((size_t)(N_USERC + 1) * 4);
    int* aCnt = (int*)carve((size_t)NB_A * 4);
    int* sCnt = (int*)carve((size_t)NB_S * 4);
    int* aCur = (int*)carve((size_t)NB_A * 4);
    int* sCur = (int*)carve((size_t)NB_S * 4);
    int* ig_cols_buf = (int*)carve((size_t)N_TAILC * TOPKC * 4);
    float* ig_vals_buf = (float*)carve((size_t)N_TAILC * TOPKC * 4);
    float* Mrm = (float*)carve(64 * 64 * 4);
    float* cvec = (float*)carve(64 * 4);
    float* loss_part = (float*)carve((size_t)LOSS_BLOCKS * 2 * 4);
    unsigned short* embH0 = (unsigned short*)carve((size_t)N_TOTALC * 64 * 2);   // bf16 concat input
    unsigned short* embH1 = (unsigned short*)carve((size_t)N_TOTALC * 64 * 2);   // bf16 mirrors (ping)
    float* scores = (float*)carve((size_t)CHUNK_ROWS * N_HEADC * 4);   // 40MB
    // aliases within the scores region (dead across phases):
    int2* aPackRaw = (int2*)scores;                          // build phase only
    int2* sPackRaw = aPackRaw + NNZ_AC;                      // 16+8=24MB < 40MB
    unsigned short* embH2 = (unsigned short*)scores;         // L2 out / L3 in (19.2MB), after score phase
    unsigned short* uh1 = embH0;                             // S1 bf16 out (embH0 dead after L1)
    unsigned short* uh2 = embH1;                             // S2 bf16 out (unused downstream)

    // ---- bucketed CSR build (A + S) ----
    hipMemsetAsync(aCnt, 0, (size_t)NB_A * 4, stream);
    hipMemsetAsync(sCnt, 0, (size_t)NB_S * 4, stream);
    hist_bucket<<<PBLK_A + PBLK_S, 256, 0, stream>>>(a_rows, s_rows, aCnt, sCnt);
    scan_buckets<<<2, 256, 0, stream>>>(aCnt, sCnt, aCur, sCur);
    partition_fused<<<PBLK_A + PBLK_S, 256, 0, stream>>>(a_vals, a_rows, a_cols,
                                                         s_vals, s_rows, s_cols,
                                                         aCur, sCur, aPackRaw, sPackRaw);
    // aCur/sCur now hold bucket END offsets
    csr_finalize<<<NB_A + NB_S, 256, 0, stream>>>(aCur, sCur, aPackRaw, sPackRaw,
                                                  aSort, sSort, a_rowptr, s_rowptr);

    // ---- collapsed encoder (tail + head fused) ----
    mc_kernel<<<17, 256, 0, stream>>>(w0, b0, w2, b2, Mrm, cvec);
    enc2_fused<<<(N_TAILC + N_HEADC + 3) / 4, 256, 0, stream>>>(item_emb, tail_idx, head_idx, Mrm, cvec, tail_e, top_e);

    // ---- bf16 concat input table ----
    to_bf16_concat<<<((N_TOTALC * 16) + 255) / 256, 256, 0, stream>>>(user_emb, item_emb, embH0);

    // ---- chunked scores GEMM + top-k (aPackRaw dead from here) ----
    for (int row0 = 0; row0 < N_TAILC; row0 += CHUNK_ROWS) {
        int m = N_TAILC - row0;
        if (m > CHUNK_ROWS) m = CHUNK_ROWS;
        int rb = (m + 127) / 128;
        score_gemm<<<dim3((N_HEADC + 127) / 128, rb), 256, 0, stream>>>(tail_e + (size_t)row0 * 64, top_e, scores, m);
        topk_rows<<<(m + 3) / 4, 256, 0, stream>>>(scores, m, row0, head_idx, ig_cols_buf, ig_vals_buf);
    }

    // ---- 3 A-layers, bf16 gathers (scores region dead from here -> embH2 alias live) ----
    {
        int blocks = (N_TOTALC + 3) / 4;
        spmm_h<<<blocks, 256, 0, stream>>>(a_rowptr, aSort, embH0, embA, embH1, N_TOTALC);  // L1
        spmm_h<<<blocks, 256, 0, stream>>>(a_rowptr, aSort, embH1, embA, embH2, N_TOTALC);  // L2 (fp32 out dead)
        spmm_h<<<blocks, 256, 0, stream>>>(a_rowptr, aSort, embH2, embB, embH1, N_TOTALC);  // L3 -> final fp32 in embB
    }
    const float* u0 = embB;
    const float* items = embB + (size_t)N_USERC * 64;

    // ---- 2 S-layers on users, bf16 gathers ----
    {
        int blocks = (N_USERC + 3) / 4;
        spmm_h<<<blocks, 256, 0, stream>>>(s_rowptr, sSort, embH1, u1, uh1, N_USERC);  // S1 (gathers users rows of L3)
        spmm_h<<<blocks, 256, 0, stream>>>(s_rowptr, sSort, uh1, u2, uh2, N_USERC);    // S2 (bf16 out unused)
    }

    // ---- item enhancement ----
    hipMemsetAsync(enh, 0, (size_t)N_ITEMC * 64 * 4, stream);
    ig_spmm_kernel<<<(N_TAILC * TOPKC) / 4, 256, 0, stream>>>(tail_idx, ig_cols_buf, ig_vals_buf, items, enh);

    // ---- loss + reg: per-block partials then single-block reduce ----
    loss_kernel<<<LOSS_BLOCKS, 256, 0, stream>>>(u0, u1, u2, items, enh, item_degree,
                                                 user_emb, item_emb, batch_user, batch_pos, batch_neg, loss_part);
    loss_reduce<<<1, 256, 0, stream>>>(loss_part, out);
}